// Round 1
// baseline (1289.126 us; speedup 1.0000x reference)
//
#include <hip/hip_runtime.h>
#include <math.h>

#define N_NODES 50000
#define N_EDGES 800000
#define D 128
#define GR 50
#define EPSV 1e-5f

__device__ __forceinline__ float lrelu(float v){ return v > 0.f ? v : 0.2f*v; }

// ---------------- CSR build (bucket edges by dst) ----------------
__global__ void k_count(const int* __restrict__ dst, int* __restrict__ deg){
  int e = blockIdx.x*256 + threadIdx.x;
  if (e < N_EDGES) atomicAdd(&deg[dst[e]], 1);
}

__global__ void k_scan1(const int* __restrict__ deg, int* __restrict__ bsum){
  __shared__ int s[256];
  int i = blockIdx.x*256 + threadIdx.x;
  int v = (i < N_NODES) ? deg[i] : 0;
  s[threadIdx.x] = v; __syncthreads();
  for (int off = 128; off > 0; off >>= 1){
    if (threadIdx.x < off) s[threadIdx.x] += s[threadIdx.x + off];
    __syncthreads();
  }
  if (threadIdx.x == 0) bsum[blockIdx.x] = s[0];
}

__global__ void k_scan2(int* bsum, int nb, int* rowStart){
  int run = 0;
  for (int b = 0; b < nb; ++b){ int t = bsum[b]; bsum[b] = run; run += t; }
  rowStart[N_NODES] = run;
}

__global__ void k_scan3(const int* __restrict__ deg, const int* __restrict__ bsum,
                        int* __restrict__ rowStart){
  __shared__ int s[256];
  int i = blockIdx.x*256 + threadIdx.x;
  int v = (i < N_NODES) ? deg[i] : 0;
  s[threadIdx.x] = v; __syncthreads();
  for (int off = 1; off < 256; off <<= 1){
    int xv = (threadIdx.x >= off) ? s[threadIdx.x - off] : 0;
    __syncthreads();
    s[threadIdx.x] += xv;
    __syncthreads();
  }
  if (i < N_NODES) rowStart[i] = bsum[blockIdx.x] + s[threadIdx.x] - v;
}

__global__ void k_fill(const int* __restrict__ src, const int* __restrict__ dst,
                       const int* __restrict__ rowStart, int* __restrict__ cursor,
                       int* __restrict__ srcList){
  int e = blockIdx.x*256 + threadIdx.x;
  if (e < N_EDGES){
    int d = dst[e];
    int pos = rowStart[d] + atomicAdd(&cursor[d], 1);
    srcList[pos] = src[e];
  }
}

// ---------------- fp32 GEMM: Y[n,128] = X[n,128] @ W[128,128] (+bias / +=) ----
// mode 0: Y = XW + bias ; mode 1: Y = XW ; mode 2: Y += XW
__global__ __launch_bounds__(256, 2) void k_gemm(const float* __restrict__ X,
    const float* __restrict__ W, const float* __restrict__ bias,
    float* __restrict__ Y, int n, int mode){
  __shared__ float Xs[128*128];
  int t = threadIdx.x;
  int rbase = blockIdx.x * 128;
  // stage X tile, XOR-swizzled by (row>>3)&3 so fragment reads are conflict-free
  #pragma unroll
  for (int i = 0; i < 16; ++i){
    int f = t + i*256;       // float4 slot id
    int r = f >> 5;          // 32 float4 per row
    int q = f & 31;
    float4 v = make_float4(0.f,0.f,0.f,0.f);
    int gr = rbase + r;
    if (gr < n) v = *(const float4*)(X + (size_t)gr*D + q*4);
    int phys = q ^ ((r >> 3) & 3);
    *(float4*)(Xs + r*128 + phys*4) = v;
  }
  __syncthreads();

  int rg = t >> 4;       // 16 row groups * 8 rows
  int cg = t & 15;       // 16 col groups * 8 cols
  int c0 = cg * 8;
  float acc[8][8];
  #pragma unroll
  for (int i = 0; i < 8; ++i)
    #pragma unroll
    for (int j = 0; j < 8; ++j) acc[i][j] = 0.f;

  #pragma unroll 2
  for (int kk = 0; kk < 128; kk += 4){
    float4 wA[4], wB[4];
    #pragma unroll
    for (int j = 0; j < 4; ++j){
      wA[j] = *(const float4*)(W + (kk + j)*D + c0);
      wB[j] = *(const float4*)(W + (kk + j)*D + c0 + 4);
    }
    int physq = (((kk >> 2) ^ (rg & 3)) << 2);
    #pragma unroll
    for (int i = 0; i < 8; ++i){
      float4 xv = *(const float4*)(Xs + (rg*8 + i)*128 + physq);
      float xj[4] = {xv.x, xv.y, xv.z, xv.w};
      #pragma unroll
      for (int j = 0; j < 4; ++j){
        float xs = xj[j];
        acc[i][0] += xs*wA[j].x; acc[i][1] += xs*wA[j].y;
        acc[i][2] += xs*wA[j].z; acc[i][3] += xs*wA[j].w;
        acc[i][4] += xs*wB[j].x; acc[i][5] += xs*wB[j].y;
        acc[i][6] += xs*wB[j].z; acc[i][7] += xs*wB[j].w;
      }
    }
  }

  float4 bv0 = make_float4(0.f,0.f,0.f,0.f), bv1 = bv0;
  if (mode == 0){
    bv0 = *(const float4*)(bias + c0);
    bv1 = *(const float4*)(bias + c0 + 4);
  }
  #pragma unroll
  for (int i = 0; i < 8; ++i){
    int r = rbase + rg*8 + i;
    if (r < n){
      float* yp = Y + (size_t)r*D + c0;
      float o[8] = {acc[i][0],acc[i][1],acc[i][2],acc[i][3],
                    acc[i][4],acc[i][5],acc[i][6],acc[i][7]};
      if (mode == 0){
        o[0]+=bv0.x; o[1]+=bv0.y; o[2]+=bv0.z; o[3]+=bv0.w;
        o[4]+=bv1.x; o[5]+=bv1.y; o[6]+=bv1.z; o[7]+=bv1.w;
      } else if (mode == 2){
        float4 y0 = *(const float4*)yp;
        float4 y1 = *(const float4*)(yp + 4);
        o[0]+=y0.x; o[1]+=y0.y; o[2]+=y0.z; o[3]+=y0.w;
        o[4]+=y1.x; o[5]+=y1.y; o[6]+=y1.z; o[7]+=y1.w;
      }
      *(float4*)yp       = make_float4(o[0],o[1],o[2],o[3]);
      *(float4*)(yp + 4) = make_float4(o[4],o[5],o[6],o[7]);
    }
  }
}

// ---------------- GAT attention scalars: es/ed [N,4] ----------------
__global__ void k_esed(const float* __restrict__ h, const float* __restrict__ as_,
                       const float* __restrict__ ad_, float* __restrict__ es,
                       float* __restrict__ ed){
  int idx = blockIdx.x*256 + threadIdx.x;
  if (idx >= N_NODES*4) return;
  int i = idx >> 2, hd = idx & 3;
  const float* hr = h + (size_t)i*D + hd*32;
  const float* ar = as_ + hd*32;
  const float* br = ad_ + hd*32;
  float s1 = 0.f, s2 = 0.f;
  #pragma unroll
  for (int j = 0; j < 32; j += 4){
    float4 hv = *(const float4*)(hr + j);
    float4 av = *(const float4*)(ar + j);
    float4 bv = *(const float4*)(br + j);
    s1 += hv.x*av.x + hv.y*av.y + hv.z*av.z + hv.w*av.w;
    s2 += hv.x*bv.x + hv.y*bv.y + hv.z*bv.z + hv.w*bv.w;
  }
  es[idx] = s1; ed[idx] = s2;
}

// ---------------- GAT aggregation: wave per node, online softmax ------------
__global__ __launch_bounds__(256) void k_gat(const float* __restrict__ h,
    const float* __restrict__ es, const float* __restrict__ edv,
    const int* __restrict__ rowStart, const int* __restrict__ srcList,
    const float* __restrict__ bias, float* __restrict__ out){
  int i = blockIdx.x*4 + (threadIdx.x >> 6);
  if (i >= N_NODES) return;
  int lane = threadIdx.x & 63;
  int h0 = lane >> 5, h1 = 2 + (lane >> 5);
  int c0 = lane, c1 = lane + 64;
  float ed0 = edv[i*4 + h0], ed1 = edv[i*4 + h1];
  // self loop initializes the online-softmax state
  float m0 = lrelu(es[i*4 + h0] + ed0);
  float m1 = lrelu(es[i*4 + h1] + ed1);
  float z0 = 1.f, z1 = 1.f;
  float acc0 = h[(size_t)i*D + c0];
  float acc1 = h[(size_t)i*D + c1];
  int ke = rowStart[i + 1];
  for (int k = rowStart[i]; k < ke; ++k){
    int s = srcList[k];
    float hv0 = h[(size_t)s*D + c0];
    float hv1 = h[(size_t)s*D + c1];
    float e0 = lrelu(es[s*4 + h0] + ed0);
    float e1 = lrelu(es[s*4 + h1] + ed1);
    float nm0 = fmaxf(m0, e0), nm1 = fmaxf(m1, e1);
    float sc0 = __expf(m0 - nm0), sc1 = __expf(m1 - nm1);
    float w0  = __expf(e0 - nm0), w1  = __expf(e1 - nm1);
    z0 = z0*sc0 + w0;           z1 = z1*sc1 + w1;
    acc0 = acc0*sc0 + hv0*w0;   acc1 = acc1*sc1 + hv1*w1;
    m0 = nm0; m1 = nm1;
  }
  out[(size_t)i*D + c0] = acc0/z0 + bias[c0];
  out[(size_t)i*D + c1] = acc1/z1 + bias[c1];
}

// ---------------- SAGE mean aggregation: wave per node ----------------
__global__ __launch_bounds__(256) void k_sage_mean(const float* __restrict__ h,
    const int* __restrict__ rowStart, const int* __restrict__ srcList,
    float* __restrict__ out){
  int i = blockIdx.x*4 + (threadIdx.x >> 6);
  if (i >= N_NODES) return;
  int lane = threadIdx.x & 63;
  int k0 = rowStart[i], k1 = rowStart[i + 1];
  float a0 = 0.f, a1 = 0.f;
  for (int k = k0; k < k1; ++k){
    int s = srcList[k];
    a0 += h[(size_t)s*D + lane];
    a1 += h[(size_t)s*D + lane + 64];
  }
  int dg = k1 - k0;
  float inv = 1.f / (float)(dg > 0 ? dg : 1);
  out[(size_t)i*D + lane]      = a0*inv;
  out[(size_t)i*D + lane + 64] = a1*inv;
}

// ---------------- BatchNorm stats (sum, sumsq per column) ----------------
__global__ __launch_bounds__(256) void k_bnstat(const float* __restrict__ x,
                                                float* __restrict__ sums){
  int col = threadIdx.x & 127;
  int ro  = threadIdx.x >> 7;
  float s = 0.f, s2 = 0.f;
  for (int r = blockIdx.x*2 + ro; r < N_NODES; r += gridDim.x*2){
    float v = x[(size_t)r*D + col];
    s += v; s2 += v*v;
  }
  __shared__ float rs[256], rq[256];
  rs[threadIdx.x] = s; rq[threadIdx.x] = s2;
  __syncthreads();
  if (threadIdx.x < 128){
    atomicAdd(&sums[col],       rs[threadIdx.x] + rs[threadIdx.x + 128]);
    atomicAdd(&sums[128 + col], rq[threadIdx.x] + rq[threadIdx.x + 128]);
  }
}

// ---------------- BN apply (+optional residual) + leaky relu ----------------
__global__ void k_bnapply(const float* __restrict__ x, const float* __restrict__ sums,
    const float* __restrict__ g, const float* __restrict__ b,
    const float* __restrict__ res, float* __restrict__ y){
  int f = blockIdx.x*256 + threadIdx.x;
  if (f >= N_NODES*32) return;
  int c = (f & 31) * 4;
  float4 v = *(const float4*)(x + (size_t)f*4);
  float vv[4] = {v.x, v.y, v.z, v.w};
  float rr[4] = {0.f, 0.f, 0.f, 0.f};
  if (res){
    float4 rv = *(const float4*)(res + (size_t)f*4);
    rr[0]=rv.x; rr[1]=rv.y; rr[2]=rv.z; rr[3]=rv.w;
  }
  float o[4];
  const float invn = 1.f / (float)N_NODES;
  #pragma unroll
  for (int j = 0; j < 4; ++j){
    int cc = c + j;
    float mu  = sums[cc] * invn;
    float var = sums[128 + cc] * invn - mu*mu;
    float rs  = rsqrtf(var + EPSV);
    o[j] = lrelu((vv[j] - mu)*rs*g[cc] + b[cc] + rr[j]);
  }
  *(float4*)(y + (size_t)f*4) = make_float4(o[0], o[1], o[2], o[3]);
}

// ---------------- global mean pool (batch sorted -> run-length) -------------
__global__ __launch_bounds__(256) void k_pool(const float* __restrict__ h,
    const int* __restrict__ batch, float* __restrict__ pooled,
    float* __restrict__ cnt){
  int col = threadIdx.x & 127;
  int ro  = threadIdx.x >> 7;
  int base = blockIdx.x * 128;
  int g_cur = -1; float acc = 0.f, cacc = 0.f;
  for (int ii = 0; ii < 64; ++ii){
    int r = base + ro + ii*2;
    if (r >= N_NODES) break;
    int g = batch[r];
    if (g != g_cur){
      if (g_cur >= 0){
        atomicAdd(&pooled[g_cur*D + col], acc);
        if (col == 0) atomicAdd(&cnt[g_cur], cacc);
      }
      acc = 0.f; cacc = 0.f; g_cur = g;
    }
    acc  += h[(size_t)r*D + col];
    cacc += 1.f;
  }
  if (g_cur >= 0){
    atomicAdd(&pooled[g_cur*D + col], acc);
    if (col == 0) atomicAdd(&cnt[g_cur], cacc);
  }
}

// ---------------- final FC on pooled ----------------
__global__ void k_fc(const float* __restrict__ pooled, const float* __restrict__ cnt,
    const float* __restrict__ W, const float* __restrict__ b, float* __restrict__ out){
  int idx = blockIdx.x*256 + threadIdx.x;
  if (idx >= GR*64) return;
  int g = idx >> 6, o = idx & 63;
  const float* p = pooled + g*D;
  float s = 0.f;
  for (int c2 = 0; c2 < D; ++c2) s += p[c2] * W[c2*64 + o];
  float inv = 1.f / fmaxf(cnt[g], 1.f);
  out[idx] = s*inv + b[o];
}

extern "C" void kernel_launch(void* const* d_in, const int* in_sizes, int n_in,
                              void* d_out, int out_size, void* d_ws, size_t ws_size,
                              hipStream_t stream){
  (void)in_sizes; (void)n_in; (void)out_size; (void)ws_size;
  const float* x       = (const float*)d_in[0];
  const int*   ei      = (const int*)  d_in[1];
  const int*   batch   = (const int*)  d_in[2];
  const float* gat1_W  = (const float*)d_in[3];
  const float* gat1_as = (const float*)d_in[4];
  const float* gat1_ad = (const float*)d_in[5];
  const float* gat1_b  = (const float*)d_in[6];
  const float* gat2_W  = (const float*)d_in[7];
  const float* gat2_as = (const float*)d_in[8];
  const float* gat2_ad = (const float*)d_in[9];
  const float* gat2_b  = (const float*)d_in[10];
  const float* s3_Wl   = (const float*)d_in[11];
  const float* s3_bl   = (const float*)d_in[12];
  const float* s3_Wr   = (const float*)d_in[13];
  const float* s4_Wl   = (const float*)d_in[14];
  const float* s4_bl   = (const float*)d_in[15];
  const float* s4_Wr   = (const float*)d_in[16];
  const float* s5_Wl   = (const float*)d_in[17];
  const float* s5_bl   = (const float*)d_in[18];
  const float* s5_Wr   = (const float*)d_in[19];
  const float* bn1_g = (const float*)d_in[20]; const float* bn1_b = (const float*)d_in[21];
  const float* bn2_g = (const float*)d_in[22]; const float* bn2_b = (const float*)d_in[23];
  const float* bn3_g = (const float*)d_in[24]; const float* bn3_b = (const float*)d_in[25];
  const float* bn4_g = (const float*)d_in[26]; const float* bn4_b = (const float*)d_in[27];
  const float* bn5_g = (const float*)d_in[28]; const float* bn5_b = (const float*)d_in[29];
  const float* res1_W = (const float*)d_in[30]; const float* res1_b = (const float*)d_in[31];
  const float* res2_W = (const float*)d_in[32]; const float* res2_b = (const float*)d_in[33];
  const float* fc_W   = (const float*)d_in[34]; const float* fc_b   = (const float*)d_in[35];
  float* out = (float*)d_out;

  char* ws = (char*)d_ws;
  size_t off = 0;
  auto alloc = [&](size_t bytes) -> void* {
    void* p = ws + off; off += (bytes + 255) & ~(size_t)255; return p;
  };
  int*   rowStart = (int*)  alloc((N_NODES + 1) * 4);
  int*   cursor   = (int*)  alloc((size_t)N_NODES * 4);   // doubles as deg
  int*   srcList  = (int*)  alloc((size_t)N_EDGES * 4);
  int*   bsum     = (int*)  alloc(256 * 4);
  float* bnsums   = (float*)alloc(256 * 4);
  float* pooled   = (float*)alloc(GR * D * 4);
  float* cnt      = (float*)alloc(64 * 4);
  float* es       = (float*)alloc((size_t)N_NODES * 4 * 4);
  float* edv      = (float*)alloc((size_t)N_NODES * 4 * 4);
  float* B1       = (float*)alloc((size_t)N_NODES * D * 4);
  float* B2       = (float*)alloc((size_t)N_NODES * D * 4);
  float* B3       = (float*)alloc((size_t)N_NODES * D * 4);

  const int* srcE = ei;
  const int* dstE = ei + N_EDGES;
  const int nb = (N_NODES + 255) / 256;
  const int egrid = (N_EDGES + 255) / 256;
  const int ggrid = (N_NODES + 127) / 128;   // gemm tiles
  const int agrid = (N_NODES + 3) / 4;       // wave-per-node kernels
  const int bgrid = (N_NODES*32 + 255) / 256;

  // CSR build
  hipMemsetAsync(cursor, 0, (size_t)N_NODES*4, stream);
  k_count<<<egrid, 256, 0, stream>>>(dstE, cursor);
  k_scan1<<<nb, 256, 0, stream>>>(cursor, bsum);
  k_scan2<<<1, 1, 0, stream>>>(bsum, nb, rowStart);
  k_scan3<<<nb, 256, 0, stream>>>(cursor, bsum, rowStart);
  hipMemsetAsync(cursor, 0, (size_t)N_NODES*4, stream);
  k_fill<<<egrid, 256, 0, stream>>>(srcE, dstE, rowStart, cursor, srcList);

  // ---- layer 1 (GAT) ----
  k_gemm<<<ggrid, 256, 0, stream>>>(x, res1_W, res1_b, B1, N_NODES, 0);
  k_gemm<<<ggrid, 256, 0, stream>>>(x, gat1_W, nullptr, B2, N_NODES, 1);
  k_esed<<<(N_NODES*4 + 255)/256, 256, 0, stream>>>(B2, gat1_as, gat1_ad, es, edv);
  k_gat<<<agrid, 256, 0, stream>>>(B2, es, edv, rowStart, srcList, gat1_b, B3);
  hipMemsetAsync(bnsums, 0, 256*4, stream);
  k_bnstat<<<256, 256, 0, stream>>>(B3, bnsums);
  k_bnapply<<<bgrid, 256, 0, stream>>>(B3, bnsums, bn1_g, bn1_b, B1, B2); // h1 -> B2

  // ---- layer 2 (GAT) ----
  k_gemm<<<ggrid, 256, 0, stream>>>(B2, res2_W, res2_b, B1, N_NODES, 0);
  k_gemm<<<ggrid, 256, 0, stream>>>(B2, gat2_W, nullptr, B3, N_NODES, 1);
  k_esed<<<(N_NODES*4 + 255)/256, 256, 0, stream>>>(B3, gat2_as, gat2_ad, es, edv);
  k_gat<<<agrid, 256, 0, stream>>>(B3, es, edv, rowStart, srcList, gat2_b, B2);
  hipMemsetAsync(bnsums, 0, 256*4, stream);
  k_bnstat<<<256, 256, 0, stream>>>(B2, bnsums);
  k_bnapply<<<bgrid, 256, 0, stream>>>(B2, bnsums, bn2_g, bn2_b, B1, B2); // h2 -> B2

  // ---- layer 3 (SAGE) ----
  k_sage_mean<<<agrid, 256, 0, stream>>>(B2, rowStart, srcList, B3);
  k_gemm<<<ggrid, 256, 0, stream>>>(B3, s3_Wl, s3_bl, B1, N_NODES, 0);
  k_gemm<<<ggrid, 256, 0, stream>>>(B2, s3_Wr, nullptr, B1, N_NODES, 2);
  hipMemsetAsync(bnsums, 0, 256*4, stream);
  k_bnstat<<<256, 256, 0, stream>>>(B1, bnsums);
  k_bnapply<<<bgrid, 256, 0, stream>>>(B1, bnsums, bn3_g, bn3_b, nullptr, B1); // h3 -> B1

  // ---- layer 4 (SAGE) ----
  k_sage_mean<<<agrid, 256, 0, stream>>>(B1, rowStart, srcList, B3);
  k_gemm<<<ggrid, 256, 0, stream>>>(B3, s4_Wl, s4_bl, B2, N_NODES, 0);
  k_gemm<<<ggrid, 256, 0, stream>>>(B1, s4_Wr, nullptr, B2, N_NODES, 2);
  hipMemsetAsync(bnsums, 0, 256*4, stream);
  k_bnstat<<<256, 256, 0, stream>>>(B2, bnsums);
  k_bnapply<<<bgrid, 256, 0, stream>>>(B2, bnsums, bn4_g, bn4_b, nullptr, B2); // h4 -> B2

  // ---- layer 5 (SAGE) ----
  k_sage_mean<<<agrid, 256, 0, stream>>>(B2, rowStart, srcList, B3);
  k_gemm<<<ggrid, 256, 0, stream>>>(B3, s5_Wl, s5_bl, B1, N_NODES, 0);
  k_gemm<<<ggrid, 256, 0, stream>>>(B2, s5_Wr, nullptr, B1, N_NODES, 2);
  hipMemsetAsync(bnsums, 0, 256*4, stream);
  k_bnstat<<<256, 256, 0, stream>>>(B1, bnsums);
  k_bnapply<<<bgrid, 256, 0, stream>>>(B1, bnsums, bn5_g, bn5_b, nullptr, B1); // h5 -> B1

  // ---- pool + fc ----
  hipMemsetAsync(pooled, 0, GR*D*4, stream);
  hipMemsetAsync(cnt, 0, 64*4, stream);
  k_pool<<<ggrid, 256, 0, stream>>>(B1, batch, pooled, cnt);
  k_fc<<<(GR*64 + 255)/256, 256, 0, stream>>>(pooled, cnt, fc_W, fc_b, out);
}

// Round 2
// 1035.402 us; speedup vs baseline: 1.2450x; 1.2450x over previous
//
#include <hip/hip_runtime.h>
#include <math.h>

#define N_NODES 50000
#define N_EDGES 800000
#define D 128
#define GR 50
#define EPSV 1e-5f

__device__ __forceinline__ float lrelu(float v){ return v > 0.f ? v : 0.2f*v; }

// ---------------- CSR build (bucket edges by dst) ----------------
__global__ void k_count(const int* __restrict__ dst, int* __restrict__ deg){
  int e = blockIdx.x*256 + threadIdx.x;
  if (e < N_EDGES) atomicAdd(&deg[dst[e]], 1);
}

__global__ void k_scan1(const int* __restrict__ deg, int* __restrict__ bsum){
  __shared__ int s[256];
  int i = blockIdx.x*256 + threadIdx.x;
  int v = (i < N_NODES) ? deg[i] : 0;
  s[threadIdx.x] = v; __syncthreads();
  for (int off = 128; off > 0; off >>= 1){
    if (threadIdx.x < off) s[threadIdx.x] += s[threadIdx.x + off];
    __syncthreads();
  }
  if (threadIdx.x == 0) bsum[blockIdx.x] = s[0];
}

__global__ void k_scan2(int* bsum, int nb, int* rowStart){
  int run = 0;
  for (int b = 0; b < nb; ++b){ int t = bsum[b]; bsum[b] = run; run += t; }
  rowStart[N_NODES] = run;
}

__global__ void k_scan3(const int* __restrict__ deg, const int* __restrict__ bsum,
                        int* __restrict__ rowStart){
  __shared__ int s[256];
  int i = blockIdx.x*256 + threadIdx.x;
  int v = (i < N_NODES) ? deg[i] : 0;
  s[threadIdx.x] = v; __syncthreads();
  for (int off = 1; off < 256; off <<= 1){
    int xv = (threadIdx.x >= off) ? s[threadIdx.x - off] : 0;
    __syncthreads();
    s[threadIdx.x] += xv;
    __syncthreads();
  }
  if (i < N_NODES) rowStart[i] = bsum[blockIdx.x] + s[threadIdx.x] - v;
}

__global__ void k_fill(const int* __restrict__ src, const int* __restrict__ dst,
                       const int* __restrict__ rowStart, int* __restrict__ cursor,
                       int* __restrict__ srcList){
  int e = blockIdx.x*256 + threadIdx.x;
  if (e < N_EDGES){
    int d = dst[e];
    int pos = rowStart[d] + atomicAdd(&cursor[d], 1);
    srcList[pos] = src[e];
  }
}

// ---------------- fp32 GEMM: Y = X@W + bias (residual projections) ----------
__global__ __launch_bounds__(256, 2) void k_gemm(const float* __restrict__ X,
    const float* __restrict__ W, const float* __restrict__ bias,
    float* __restrict__ Y, int n){
  __shared__ float Xs[128*128];
  int t = threadIdx.x;
  int rbase = blockIdx.x * 128;
  #pragma unroll
  for (int i = 0; i < 16; ++i){
    int f = t + i*256;
    int r = f >> 5;
    int q = f & 31;
    float4 v = make_float4(0.f,0.f,0.f,0.f);
    int gr = rbase + r;
    if (gr < n) v = *(const float4*)(X + (size_t)gr*D + q*4);
    int phys = q ^ ((r >> 3) & 3);
    *(float4*)(Xs + r*128 + phys*4) = v;
  }
  __syncthreads();

  int rg = t >> 4, cg = t & 15;
  int c0 = cg * 8;
  float acc[8][8];
  #pragma unroll
  for (int i = 0; i < 8; ++i)
    #pragma unroll
    for (int j = 0; j < 8; ++j) acc[i][j] = 0.f;

  #pragma unroll 2
  for (int kk = 0; kk < 128; kk += 4){
    float4 wA[4], wB[4];
    #pragma unroll
    for (int j = 0; j < 4; ++j){
      wA[j] = *(const float4*)(W + (kk + j)*D + c0);
      wB[j] = *(const float4*)(W + (kk + j)*D + c0 + 4);
    }
    int physq = (((kk >> 2) ^ (rg & 3)) << 2);
    #pragma unroll
    for (int i = 0; i < 8; ++i){
      float4 xv = *(const float4*)(Xs + (rg*8 + i)*128 + physq);
      float xj[4] = {xv.x, xv.y, xv.z, xv.w};
      #pragma unroll
      for (int j = 0; j < 4; ++j){
        float xs = xj[j];
        acc[i][0] += xs*wA[j].x; acc[i][1] += xs*wA[j].y;
        acc[i][2] += xs*wA[j].z; acc[i][3] += xs*wA[j].w;
        acc[i][4] += xs*wB[j].x; acc[i][5] += xs*wB[j].y;
        acc[i][6] += xs*wB[j].z; acc[i][7] += xs*wB[j].w;
      }
    }
  }

  float4 bv0 = *(const float4*)(bias + c0);
  float4 bv1 = *(const float4*)(bias + c0 + 4);
  #pragma unroll
  for (int i = 0; i < 8; ++i){
    int r = rbase + rg*8 + i;
    if (r < n){
      float* yp = Y + (size_t)r*D + c0;
      *(float4*)yp       = make_float4(acc[i][0]+bv0.x, acc[i][1]+bv0.y,
                                       acc[i][2]+bv0.z, acc[i][3]+bv0.w);
      *(float4*)(yp + 4) = make_float4(acc[i][4]+bv1.x, acc[i][5]+bv1.y,
                                       acc[i][6]+bv1.z, acc[i][7]+bv1.w);
    }
  }
}

// --------- GAT GEMM: Y = X@W (no bias) + fused es/ed attention scalars ------
__global__ __launch_bounds__(256, 2) void k_gemm_gat(const float* __restrict__ X,
    const float* __restrict__ W, const float* __restrict__ as_,
    const float* __restrict__ ad_, float* __restrict__ Y,
    float* __restrict__ es, float* __restrict__ ed, int n){
  __shared__ float Xs[128*128];
  int t = threadIdx.x;
  int rbase = blockIdx.x * 128;
  #pragma unroll
  for (int i = 0; i < 16; ++i){
    int f = t + i*256;
    int r = f >> 5;
    int q = f & 31;
    float4 v = make_float4(0.f,0.f,0.f,0.f);
    int gr = rbase + r;
    if (gr < n) v = *(const float4*)(X + (size_t)gr*D + q*4);
    int phys = q ^ ((r >> 3) & 3);
    *(float4*)(Xs + r*128 + phys*4) = v;
  }
  __syncthreads();

  int rg = t >> 4, cg = t & 15;
  int c0 = cg * 8;
  float acc[8][8];
  #pragma unroll
  for (int i = 0; i < 8; ++i)
    #pragma unroll
    for (int j = 0; j < 8; ++j) acc[i][j] = 0.f;

  #pragma unroll 2
  for (int kk = 0; kk < 128; kk += 4){
    float4 wA[4], wB[4];
    #pragma unroll
    for (int j = 0; j < 4; ++j){
      wA[j] = *(const float4*)(W + (kk + j)*D + c0);
      wB[j] = *(const float4*)(W + (kk + j)*D + c0 + 4);
    }
    int physq = (((kk >> 2) ^ (rg & 3)) << 2);
    #pragma unroll
    for (int i = 0; i < 8; ++i){
      float4 xv = *(const float4*)(Xs + (rg*8 + i)*128 + physq);
      float xj[4] = {xv.x, xv.y, xv.z, xv.w};
      #pragma unroll
      for (int j = 0; j < 4; ++j){
        float xs = xj[j];
        acc[i][0] += xs*wA[j].x; acc[i][1] += xs*wA[j].y;
        acc[i][2] += xs*wA[j].z; acc[i][3] += xs*wA[j].w;
        acc[i][4] += xs*wB[j].x; acc[i][5] += xs*wB[j].y;
        acc[i][6] += xs*wB[j].z; acc[i][7] += xs*wB[j].w;
      }
    }
  }

  // attention-scalar weights for this thread's 8 cols (all within one head)
  int hd = cg >> 2;
  int cl = c0 & 31;
  float4 a0 = *(const float4*)(as_ + hd*32 + cl);
  float4 a1 = *(const float4*)(as_ + hd*32 + cl + 4);
  float4 d0 = *(const float4*)(ad_ + hd*32 + cl);
  float4 d1 = *(const float4*)(ad_ + hd*32 + cl + 4);

  #pragma unroll
  for (int i = 0; i < 8; ++i){
    int r = rbase + rg*8 + i;
    float ps = acc[i][0]*a0.x + acc[i][1]*a0.y + acc[i][2]*a0.z + acc[i][3]*a0.w
             + acc[i][4]*a1.x + acc[i][5]*a1.y + acc[i][6]*a1.z + acc[i][7]*a1.w;
    float pd = acc[i][0]*d0.x + acc[i][1]*d0.y + acc[i][2]*d0.z + acc[i][3]*d0.w
             + acc[i][4]*d1.x + acc[i][5]*d1.y + acc[i][6]*d1.z + acc[i][7]*d1.w;
    ps += __shfl_xor(ps, 1); ps += __shfl_xor(ps, 2);
    pd += __shfl_xor(pd, 1); pd += __shfl_xor(pd, 2);
    if (r < n){
      float* yp = Y + (size_t)r*D + c0;
      *(float4*)yp       = make_float4(acc[i][0],acc[i][1],acc[i][2],acc[i][3]);
      *(float4*)(yp + 4) = make_float4(acc[i][4],acc[i][5],acc[i][6],acc[i][7]);
      if ((cg & 3) == 0){
        es[r*4 + hd] = ps;
        ed[r*4 + hd] = pd;
      }
    }
  }
}

// ------- SAGE dual GEMM: Y = Xa@Wa + bias + Xb@Wb, fused BN column stats ----
__global__ __launch_bounds__(256, 2) void k_gemm2(const float* __restrict__ Xa,
    const float* __restrict__ Wa, const float* __restrict__ Xb,
    const float* __restrict__ Wb, const float* __restrict__ bias,
    float* __restrict__ Y, int n, float* __restrict__ bnsum){
  __shared__ float Xs[128*128];
  __shared__ float red[16][128];
  int t = threadIdx.x;
  int rbase = blockIdx.x * 128;
  int rg = t >> 4, cg = t & 15;
  int c0 = cg * 8;
  float acc[8][8];
  #pragma unroll
  for (int i = 0; i < 8; ++i)
    #pragma unroll
    for (int j = 0; j < 8; ++j) acc[i][j] = 0.f;

  for (int pass = 0; pass < 2; ++pass){
    const float* X = pass ? Xb : Xa;
    const float* W = pass ? Wb : Wa;
    if (pass) __syncthreads();          // wait for previous reads
    #pragma unroll
    for (int i = 0; i < 16; ++i){
      int f = t + i*256;
      int r = f >> 5;
      int q = f & 31;
      float4 v = make_float4(0.f,0.f,0.f,0.f);
      int gr = rbase + r;
      if (gr < n) v = *(const float4*)(X + (size_t)gr*D + q*4);
      int phys = q ^ ((r >> 3) & 3);
      *(float4*)(Xs + r*128 + phys*4) = v;
    }
    __syncthreads();
    #pragma unroll 2
    for (int kk = 0; kk < 128; kk += 4){
      float4 wA[4], wB[4];
      #pragma unroll
      for (int j = 0; j < 4; ++j){
        wA[j] = *(const float4*)(W + (kk + j)*D + c0);
        wB[j] = *(const float4*)(W + (kk + j)*D + c0 + 4);
      }
      int physq = (((kk >> 2) ^ (rg & 3)) << 2);
      #pragma unroll
      for (int i = 0; i < 8; ++i){
        float4 xv = *(const float4*)(Xs + (rg*8 + i)*128 + physq);
        float xj[4] = {xv.x, xv.y, xv.z, xv.w};
        #pragma unroll
        for (int j = 0; j < 4; ++j){
          float xs = xj[j];
          acc[i][0] += xs*wA[j].x; acc[i][1] += xs*wA[j].y;
          acc[i][2] += xs*wA[j].z; acc[i][3] += xs*wA[j].w;
          acc[i][4] += xs*wB[j].x; acc[i][5] += xs*wB[j].y;
          acc[i][6] += xs*wB[j].z; acc[i][7] += xs*wB[j].w;
        }
      }
    }
  }

  float bv[8];
  #pragma unroll
  for (int j = 0; j < 8; ++j) bv[j] = bias[c0 + j];
  float colS[8], colQ[8];
  #pragma unroll
  for (int j = 0; j < 8; ++j){ colS[j] = 0.f; colQ[j] = 0.f; }

  #pragma unroll
  for (int i = 0; i < 8; ++i){
    int r = rbase + rg*8 + i;
    if (r < n){
      float o[8];
      #pragma unroll
      for (int j = 0; j < 8; ++j){
        o[j] = acc[i][j] + bv[j];
        colS[j] += o[j];
        colQ[j] += o[j]*o[j];
      }
      float* yp = Y + (size_t)r*D + c0;
      *(float4*)yp       = make_float4(o[0],o[1],o[2],o[3]);
      *(float4*)(yp + 4) = make_float4(o[4],o[5],o[6],o[7]);
    }
  }
  __syncthreads();
  #pragma unroll
  for (int j = 0; j < 8; ++j) red[rg][c0 + j] = colS[j];
  __syncthreads();
  if (t < 128){
    float s = 0.f;
    #pragma unroll
    for (int g = 0; g < 16; ++g) s += red[g][t];
    atomicAdd(&bnsum[t], s);
  }
  __syncthreads();
  #pragma unroll
  for (int j = 0; j < 8; ++j) red[rg][c0 + j] = colQ[j];
  __syncthreads();
  if (t < 128){
    float s = 0.f;
    #pragma unroll
    for (int g = 0; g < 16; ++g) s += red[g][t];
    atomicAdd(&bnsum[128 + t], s);
  }
}

// --------- GAT aggregation: wave/node, lane = channel pair, no max shift ----
__global__ __launch_bounds__(256) void k_gat(const float* __restrict__ h,
    const float* __restrict__ es, const float* __restrict__ edv,
    const int* __restrict__ rowStart, const int* __restrict__ srcList,
    const float* __restrict__ bias, float* __restrict__ out){
  int i = blockIdx.x*4 + (threadIdx.x >> 6);
  if (i >= N_NODES) return;
  int lane = threadIdx.x & 63;
  int hd = lane >> 4;         // one head per lane
  int c  = lane * 2;          // channel pair
  float edi = edv[i*4 + hd];
  // self loop
  float2 self = *(const float2*)(h + (size_t)i*D + c);
  float w = __expf(lrelu(es[i*4 + hd] + edi));
  float z = w, acc0 = self.x*w, acc1 = self.y*w;
  int k0 = rowStart[i], ke = rowStart[i + 1];
  int k = k0;
  for (; k + 1 < ke; k += 2){
    int s0 = srcList[k], s1 = srcList[k + 1];
    float2 h0 = *(const float2*)(h + (size_t)s0*D + c);
    float2 h1 = *(const float2*)(h + (size_t)s1*D + c);
    float e0 = es[s0*4 + hd], e1 = es[s1*4 + hd];
    float w0 = __expf(lrelu(e0 + edi));
    float w1 = __expf(lrelu(e1 + edi));
    z += w0 + w1;
    acc0 += h0.x*w0 + h1.x*w1;
    acc1 += h0.y*w0 + h1.y*w1;
  }
  if (k < ke){
    int s0 = srcList[k];
    float2 h0 = *(const float2*)(h + (size_t)s0*D + c);
    float w0 = __expf(lrelu(es[s0*4 + hd] + edi));
    z += w0; acc0 += h0.x*w0; acc1 += h0.y*w0;
  }
  float inv = 1.f / z;
  float2 bv = *(const float2*)(bias + c);
  *(float2*)(out + (size_t)i*D + c) = make_float2(acc0*inv + bv.x, acc1*inv + bv.y);
}

// ---------------- SAGE mean aggregation: wave/node, float2, unroll 4 --------
__global__ __launch_bounds__(256) void k_sage_mean(const float* __restrict__ h,
    const int* __restrict__ rowStart, const int* __restrict__ srcList,
    float* __restrict__ out){
  int i = blockIdx.x*4 + (threadIdx.x >> 6);
  if (i >= N_NODES) return;
  int lane = threadIdx.x & 63;
  int c = lane * 2;
  int k0 = rowStart[i], k1 = rowStart[i + 1];
  float a0 = 0.f, a1 = 0.f;
  int k = k0;
  for (; k + 3 < k1; k += 4){
    int s0 = srcList[k], s1 = srcList[k+1], s2 = srcList[k+2], s3 = srcList[k+3];
    float2 v0 = *(const float2*)(h + (size_t)s0*D + c);
    float2 v1 = *(const float2*)(h + (size_t)s1*D + c);
    float2 v2 = *(const float2*)(h + (size_t)s2*D + c);
    float2 v3 = *(const float2*)(h + (size_t)s3*D + c);
    a0 += v0.x + v1.x + v2.x + v3.x;
    a1 += v0.y + v1.y + v2.y + v3.y;
  }
  for (; k < k1; ++k){
    int s0 = srcList[k];
    float2 v0 = *(const float2*)(h + (size_t)s0*D + c);
    a0 += v0.x; a1 += v0.y;
  }
  int dg = k1 - k0;
  float inv = 1.f / (float)(dg > 0 ? dg : 1);
  *(float2*)(out + (size_t)i*D + c) = make_float2(a0*inv, a1*inv);
}

// ---------------- BatchNorm stats (sum, sumsq per column) ----------------
__global__ __launch_bounds__(256) void k_bnstat(const float* __restrict__ x,
                                                float* __restrict__ sums){
  int col = threadIdx.x & 127;
  int ro  = threadIdx.x >> 7;
  float s = 0.f, s2 = 0.f;
  for (int r = blockIdx.x*2 + ro; r < N_NODES; r += gridDim.x*2){
    float v = x[(size_t)r*D + col];
    s += v; s2 += v*v;
  }
  __shared__ float rs[256], rq[256];
  rs[threadIdx.x] = s; rq[threadIdx.x] = s2;
  __syncthreads();
  if (threadIdx.x < 128){
    atomicAdd(&sums[col],       rs[threadIdx.x] + rs[threadIdx.x + 128]);
    atomicAdd(&sums[128 + col], rq[threadIdx.x] + rq[threadIdx.x + 128]);
  }
}

// ---------------- BN apply (+optional residual) + leaky relu ----------------
__global__ void k_bnapply(const float* __restrict__ x, const float* __restrict__ sums,
    const float* __restrict__ g, const float* __restrict__ b,
    const float* __restrict__ res, float* __restrict__ y){
  int f = blockIdx.x*256 + threadIdx.x;
  if (f >= N_NODES*32) return;
  int c = (f & 31) * 4;
  float4 v = *(const float4*)(x + (size_t)f*4);
  float vv[4] = {v.x, v.y, v.z, v.w};
  float rr[4] = {0.f, 0.f, 0.f, 0.f};
  if (res){
    float4 rv = *(const float4*)(res + (size_t)f*4);
    rr[0]=rv.x; rr[1]=rv.y; rr[2]=rv.z; rr[3]=rv.w;
  }
  float o[4];
  const float invn = 1.f / (float)N_NODES;
  #pragma unroll
  for (int j = 0; j < 4; ++j){
    int cc = c + j;
    float mu  = sums[cc] * invn;
    float var = sums[128 + cc] * invn - mu*mu;
    float rs  = rsqrtf(var + EPSV);
    o[j] = lrelu((vv[j] - mu)*rs*g[cc] + b[cc] + rr[j]);
  }
  *(float4*)(y + (size_t)f*4) = make_float4(o[0], o[1], o[2], o[3]);
}

// ---------------- global mean pool (batch sorted -> run-length) -------------
__global__ __launch_bounds__(256) void k_pool(const float* __restrict__ h,
    const int* __restrict__ batch, float* __restrict__ pooled,
    float* __restrict__ cnt){
  int col = threadIdx.x & 127;
  int ro  = threadIdx.x >> 7;
  int base = blockIdx.x * 128;
  int g_cur = -1; float acc = 0.f, cacc = 0.f;
  for (int ii = 0; ii < 64; ++ii){
    int r = base + ro + ii*2;
    if (r >= N_NODES) break;
    int g = batch[r];
    if (g != g_cur){
      if (g_cur >= 0){
        atomicAdd(&pooled[g_cur*D + col], acc);
        if (col == 0) atomicAdd(&cnt[g_cur], cacc);
      }
      acc = 0.f; cacc = 0.f; g_cur = g;
    }
    acc  += h[(size_t)r*D + col];
    cacc += 1.f;
  }
  if (g_cur >= 0){
    atomicAdd(&pooled[g_cur*D + col], acc);
    if (col == 0) atomicAdd(&cnt[g_cur], cacc);
  }
}

// ---------------- final FC on pooled ----------------
__global__ void k_fc(const float* __restrict__ pooled, const float* __restrict__ cnt,
    const float* __restrict__ W, const float* __restrict__ b, float* __restrict__ out){
  int idx = blockIdx.x*256 + threadIdx.x;
  if (idx >= GR*64) return;
  int g = idx >> 6, o = idx & 63;
  const float* p = pooled + g*D;
  float s = 0.f;
  for (int c2 = 0; c2 < D; ++c2) s += p[c2] * W[c2*64 + o];
  float inv = 1.f / fmaxf(cnt[g], 1.f);
  out[idx] = s*inv + b[o];
}

extern "C" void kernel_launch(void* const* d_in, const int* in_sizes, int n_in,
                              void* d_out, int out_size, void* d_ws, size_t ws_size,
                              hipStream_t stream){
  (void)in_sizes; (void)n_in; (void)out_size; (void)ws_size;
  const float* x       = (const float*)d_in[0];
  const int*   ei      = (const int*)  d_in[1];
  const int*   batch   = (const int*)  d_in[2];
  const float* gat1_W  = (const float*)d_in[3];
  const float* gat1_as = (const float*)d_in[4];
  const float* gat1_ad = (const float*)d_in[5];
  const float* gat1_b  = (const float*)d_in[6];
  const float* gat2_W  = (const float*)d_in[7];
  const float* gat2_as = (const float*)d_in[8];
  const float* gat2_ad = (const float*)d_in[9];
  const float* gat2_b  = (const float*)d_in[10];
  const float* s3_Wl   = (const float*)d_in[11];
  const float* s3_bl   = (const float*)d_in[12];
  const float* s3_Wr   = (const float*)d_in[13];
  const float* s4_Wl   = (const float*)d_in[14];
  const float* s4_bl   = (const float*)d_in[15];
  const float* s4_Wr   = (const float*)d_in[16];
  const float* s5_Wl   = (const float*)d_in[17];
  const float* s5_bl   = (const float*)d_in[18];
  const float* s5_Wr   = (const float*)d_in[19];
  const float* bn1_g = (const float*)d_in[20]; const float* bn1_b = (const float*)d_in[21];
  const float* bn2_g = (const float*)d_in[22]; const float* bn2_b = (const float*)d_in[23];
  const float* bn3_g = (const float*)d_in[24]; const float* bn3_b = (const float*)d_in[25];
  const float* bn4_g = (const float*)d_in[26]; const float* bn4_b = (const float*)d_in[27];
  const float* bn5_g = (const float*)d_in[28]; const float* bn5_b = (const float*)d_in[29];
  const float* res1_W = (const float*)d_in[30]; const float* res1_b = (const float*)d_in[31];
  const float* res2_W = (const float*)d_in[32]; const float* res2_b = (const float*)d_in[33];
  const float* fc_W   = (const float*)d_in[34]; const float* fc_b   = (const float*)d_in[35];
  float* out = (float*)d_out;

  char* ws = (char*)d_ws;
  size_t off = 0;
  auto alloc = [&](size_t bytes) -> void* {
    void* p = ws + off; off += (bytes + 255) & ~(size_t)255; return p;
  };
  int*   rowStart = (int*)  alloc((N_NODES + 1) * 4);
  int*   cursor   = (int*)  alloc((size_t)N_NODES * 4);   // doubles as deg
  int*   srcList  = (int*)  alloc((size_t)N_EDGES * 4);
  int*   bsum     = (int*)  alloc(256 * 4);
  float* bnsums   = (float*)alloc(5 * 256 * 4);           // 5 layers x (sum|sumsq)
  float* pooled   = (float*)alloc(GR * D * 4);            // pooled+cnt contiguous
  float* cnt      = (float*)alloc(64 * 4);
  float* es       = (float*)alloc((size_t)N_NODES * 4 * 4);
  float* edv      = (float*)alloc((size_t)N_NODES * 4 * 4);
  float* B1       = (float*)alloc((size_t)N_NODES * D * 4);
  float* B2       = (float*)alloc((size_t)N_NODES * D * 4);
  float* B3       = (float*)alloc((size_t)N_NODES * D * 4);

  const int* srcE = ei;
  const int* dstE = ei + N_EDGES;
  const int nb = (N_NODES + 255) / 256;
  const int egrid = (N_EDGES + 255) / 256;
  const int ggrid = (N_NODES + 127) / 128;
  const int agrid = (N_NODES + 3) / 4;
  const int bgrid = (N_NODES*32 + 255) / 256;

  // CSR build
  hipMemsetAsync(cursor, 0, (size_t)N_NODES*4, stream);
  k_count<<<egrid, 256, 0, stream>>>(dstE, cursor);
  k_scan1<<<nb, 256, 0, stream>>>(cursor, bsum);
  k_scan2<<<1, 1, 0, stream>>>(bsum, nb, rowStart);
  k_scan3<<<nb, 256, 0, stream>>>(cursor, bsum, rowStart);
  hipMemsetAsync(cursor, 0, (size_t)N_NODES*4, stream);
  k_fill<<<egrid, 256, 0, stream>>>(srcE, dstE, rowStart, cursor, srcList);

  hipMemsetAsync(bnsums, 0, 5*256*4, stream);

  // ---- layer 1 (GAT) ----
  k_gemm<<<ggrid, 256, 0, stream>>>(x, res1_W, res1_b, B1, N_NODES);
  k_gemm_gat<<<ggrid, 256, 0, stream>>>(x, gat1_W, gat1_as, gat1_ad, B2, es, edv, N_NODES);
  k_gat<<<agrid, 256, 0, stream>>>(B2, es, edv, rowStart, srcList, gat1_b, B3);
  k_bnstat<<<256, 256, 0, stream>>>(B3, bnsums);
  k_bnapply<<<bgrid, 256, 0, stream>>>(B3, bnsums, bn1_g, bn1_b, B1, B2); // h1 -> B2

  // ---- layer 2 (GAT) ----
  k_gemm<<<ggrid, 256, 0, stream>>>(B2, res2_W, res2_b, B1, N_NODES);
  k_gemm_gat<<<ggrid, 256, 0, stream>>>(B2, gat2_W, gat2_as, gat2_ad, B3, es, edv, N_NODES);
  k_gat<<<agrid, 256, 0, stream>>>(B3, es, edv, rowStart, srcList, gat2_b, B2);
  k_bnstat<<<256, 256, 0, stream>>>(B2, bnsums + 256);
  k_bnapply<<<bgrid, 256, 0, stream>>>(B2, bnsums + 256, bn2_g, bn2_b, B1, B2); // h2 -> B2

  // ---- layer 3 (SAGE) ----
  k_sage_mean<<<agrid, 256, 0, stream>>>(B2, rowStart, srcList, B3);
  k_gemm2<<<ggrid, 256, 0, stream>>>(B3, s3_Wl, B2, s3_Wr, s3_bl, B1, N_NODES, bnsums + 2*256);
  k_bnapply<<<bgrid, 256, 0, stream>>>(B1, bnsums + 2*256, bn3_g, bn3_b, nullptr, B1);

  // ---- layer 4 (SAGE) ----
  k_sage_mean<<<agrid, 256, 0, stream>>>(B1, rowStart, srcList, B3);
  k_gemm2<<<ggrid, 256, 0, stream>>>(B3, s4_Wl, B1, s4_Wr, s4_bl, B2, N_NODES, bnsums + 3*256);
  k_bnapply<<<bgrid, 256, 0, stream>>>(B2, bnsums + 3*256, bn4_g, bn4_b, nullptr, B2);

  // ---- layer 5 (SAGE) ----
  k_sage_mean<<<agrid, 256, 0, stream>>>(B2, rowStart, srcList, B3);
  k_gemm2<<<ggrid, 256, 0, stream>>>(B3, s5_Wl, B2, s5_Wr, s5_bl, B1, N_NODES, bnsums + 4*256);
  k_bnapply<<<bgrid, 256, 0, stream>>>(B1, bnsums + 4*256, bn5_g, bn5_b, nullptr, B1);

  // ---- pool + fc ----
  hipMemsetAsync(pooled, 0, (GR*D + 64)*4, stream);
  k_pool<<<ggrid, 256, 0, stream>>>(B1, batch, pooled, cnt);
  k_fc<<<(GR*64 + 255)/256, 256, 0, stream>>>(pooled, cnt, fc_W, fc_b, out);
}

// Round 3
// 924.590 us; speedup vs baseline: 1.3943x; 1.1199x over previous
//
#include <hip/hip_runtime.h>
#include <math.h>
#include <stdint.h>

#define N_NODES 50000
#define N_EDGES 800000
#define D 128
#define GR 50
#define EPSV 1e-5f

__device__ __forceinline__ float lrelu(float v){ return v > 0.f ? v : 0.2f*v; }

// bf16 pack/unpack (round-to-nearest-even)
__device__ __forceinline__ unsigned int f2bf(float f){
  union { float f; uint32_t i; } v; v.f = f;
  uint32_t r = v.i + 0x7fffu + ((v.i >> 16) & 1u);
  return r >> 16;
}
__device__ __forceinline__ float2 bf2f2(uint32_t u){
  union { uint32_t i; float f; } a, b;
  a.i = u << 16;
  b.i = u & 0xffff0000u;
  return make_float2(a.f, b.f);
}

// ---------------- CSR build (bucket edges by dst) ----------------
__global__ void k_count(const int* __restrict__ dst, int* __restrict__ deg){
  int e = blockIdx.x*256 + threadIdx.x;
  if (e < N_EDGES) atomicAdd(&deg[dst[e]], 1);
}

__global__ void k_scan1(const int* __restrict__ deg, int* __restrict__ bsum){
  __shared__ int s[256];
  int i = blockIdx.x*256 + threadIdx.x;
  int v = (i < N_NODES) ? deg[i] : 0;
  s[threadIdx.x] = v; __syncthreads();
  for (int off = 128; off > 0; off >>= 1){
    if (threadIdx.x < off) s[threadIdx.x] += s[threadIdx.x + off];
    __syncthreads();
  }
  if (threadIdx.x == 0) bsum[blockIdx.x] = s[0];
}

__global__ void k_scan2(int* bsum, int nb, int* rowStart){
  int run = 0;
  for (int b = 0; b < nb; ++b){ int t = bsum[b]; bsum[b] = run; run += t; }
  rowStart[N_NODES] = run;
}

__global__ void k_scan3(const int* __restrict__ deg, const int* __restrict__ bsum,
                        int* __restrict__ rowStart){
  __shared__ int s[256];
  int i = blockIdx.x*256 + threadIdx.x;
  int v = (i < N_NODES) ? deg[i] : 0;
  s[threadIdx.x] = v; __syncthreads();
  for (int off = 1; off < 256; off <<= 1){
    int xv = (threadIdx.x >= off) ? s[threadIdx.x - off] : 0;
    __syncthreads();
    s[threadIdx.x] += xv;
    __syncthreads();
  }
  if (i < N_NODES) rowStart[i] = bsum[blockIdx.x] + s[threadIdx.x] - v;
}

__global__ void k_fill(const int* __restrict__ src, const int* __restrict__ dst,
                       const int* __restrict__ rowStart, int* __restrict__ cursor,
                       int* __restrict__ srcList){
  int e = blockIdx.x*256 + threadIdx.x;
  if (e < N_EDGES){
    int d = dst[e];
    int pos = rowStart[d] + atomicAdd(&cursor[d], 1);
    srcList[pos] = src[e];
  }
}

// ---------------- fp32 GEMM: Y = X@W + bias (residual projections) ----------
__global__ __launch_bounds__(256, 2) void k_gemm(const float* __restrict__ X,
    const float* __restrict__ W, const float* __restrict__ bias,
    float* __restrict__ Y, int n){
  __shared__ float Xs[128*128];
  int t = threadIdx.x;
  int rbase = blockIdx.x * 128;
  #pragma unroll
  for (int i = 0; i < 16; ++i){
    int f = t + i*256;
    int r = f >> 5;
    int q = f & 31;
    float4 v = make_float4(0.f,0.f,0.f,0.f);
    int gr = rbase + r;
    if (gr < n) v = *(const float4*)(X + (size_t)gr*D + q*4);
    int phys = q ^ ((r >> 3) & 3);
    *(float4*)(Xs + r*128 + phys*4) = v;
  }
  __syncthreads();

  int rg = t >> 4, cg = t & 15;
  int c0 = cg * 8;
  float acc[8][8];
  #pragma unroll
  for (int i = 0; i < 8; ++i)
    #pragma unroll
    for (int j = 0; j < 8; ++j) acc[i][j] = 0.f;

  #pragma unroll 2
  for (int kk = 0; kk < 128; kk += 4){
    float4 wA[4], wB[4];
    #pragma unroll
    for (int j = 0; j < 4; ++j){
      wA[j] = *(const float4*)(W + (kk + j)*D + c0);
      wB[j] = *(const float4*)(W + (kk + j)*D + c0 + 4);
    }
    int physq = (((kk >> 2) ^ (rg & 3)) << 2);
    #pragma unroll
    for (int i = 0; i < 8; ++i){
      float4 xv = *(const float4*)(Xs + (rg*8 + i)*128 + physq);
      float xj[4] = {xv.x, xv.y, xv.z, xv.w};
      #pragma unroll
      for (int j = 0; j < 4; ++j){
        float xs = xj[j];
        acc[i][0] += xs*wA[j].x; acc[i][1] += xs*wA[j].y;
        acc[i][2] += xs*wA[j].z; acc[i][3] += xs*wA[j].w;
        acc[i][4] += xs*wB[j].x; acc[i][5] += xs*wB[j].y;
        acc[i][6] += xs*wB[j].z; acc[i][7] += xs*wB[j].w;
      }
    }
  }

  float4 bv0 = *(const float4*)(bias + c0);
  float4 bv1 = *(const float4*)(bias + c0 + 4);
  #pragma unroll
  for (int i = 0; i < 8; ++i){
    int r = rbase + rg*8 + i;
    if (r < n){
      float* yp = Y + (size_t)r*D + c0;
      *(float4*)yp       = make_float4(acc[i][0]+bv0.x, acc[i][1]+bv0.y,
                                       acc[i][2]+bv0.z, acc[i][3]+bv0.w);
      *(float4*)(yp + 4) = make_float4(acc[i][4]+bv1.x, acc[i][5]+bv1.y,
                                       acc[i][6]+bv1.z, acc[i][7]+bv1.w);
    }
  }
}

// --------- GAT GEMM: h16 = bf16(X@W), fused es/ed attention scalars ---------
// fp32 output is NOT written (nothing consumes it).
__global__ __launch_bounds__(256, 2) void k_gemm_gat(const float* __restrict__ X,
    const float* __restrict__ W, const float* __restrict__ as_,
    const float* __restrict__ ad_, unsigned int* __restrict__ y16,
    float* __restrict__ es, float* __restrict__ ed, int n){
  __shared__ float Xs[128*128];
  int t = threadIdx.x;
  int rbase = blockIdx.x * 128;
  #pragma unroll
  for (int i = 0; i < 16; ++i){
    int f = t + i*256;
    int r = f >> 5;
    int q = f & 31;
    float4 v = make_float4(0.f,0.f,0.f,0.f);
    int gr = rbase + r;
    if (gr < n) v = *(const float4*)(X + (size_t)gr*D + q*4);
    int phys = q ^ ((r >> 3) & 3);
    *(float4*)(Xs + r*128 + phys*4) = v;
  }
  __syncthreads();

  int rg = t >> 4, cg = t & 15;
  int c0 = cg * 8;
  float acc[8][8];
  #pragma unroll
  for (int i = 0; i < 8; ++i)
    #pragma unroll
    for (int j = 0; j < 8; ++j) acc[i][j] = 0.f;

  #pragma unroll 2
  for (int kk = 0; kk < 128; kk += 4){
    float4 wA[4], wB[4];
    #pragma unroll
    for (int j = 0; j < 4; ++j){
      wA[j] = *(const float4*)(W + (kk + j)*D + c0);
      wB[j] = *(const float4*)(W + (kk + j)*D + c0 + 4);
    }
    int physq = (((kk >> 2) ^ (rg & 3)) << 2);
    #pragma unroll
    for (int i = 0; i < 8; ++i){
      float4 xv = *(const float4*)(Xs + (rg*8 + i)*128 + physq);
      float xj[4] = {xv.x, xv.y, xv.z, xv.w};
      #pragma unroll
      for (int j = 0; j < 4; ++j){
        float xs = xj[j];
        acc[i][0] += xs*wA[j].x; acc[i][1] += xs*wA[j].y;
        acc[i][2] += xs*wA[j].z; acc[i][3] += xs*wA[j].w;
        acc[i][4] += xs*wB[j].x; acc[i][5] += xs*wB[j].y;
        acc[i][6] += xs*wB[j].z; acc[i][7] += xs*wB[j].w;
      }
    }
  }

  int hd = cg >> 2;
  int cl = c0 & 31;
  float4 a0 = *(const float4*)(as_ + hd*32 + cl);
  float4 a1 = *(const float4*)(as_ + hd*32 + cl + 4);
  float4 d0 = *(const float4*)(ad_ + hd*32 + cl);
  float4 d1 = *(const float4*)(ad_ + hd*32 + cl + 4);

  #pragma unroll
  for (int i = 0; i < 8; ++i){
    int r = rbase + rg*8 + i;
    float ps = acc[i][0]*a0.x + acc[i][1]*a0.y + acc[i][2]*a0.z + acc[i][3]*a0.w
             + acc[i][4]*a1.x + acc[i][5]*a1.y + acc[i][6]*a1.z + acc[i][7]*a1.w;
    float pd = acc[i][0]*d0.x + acc[i][1]*d0.y + acc[i][2]*d0.z + acc[i][3]*d0.w
             + acc[i][4]*d1.x + acc[i][5]*d1.y + acc[i][6]*d1.z + acc[i][7]*d1.w;
    ps += __shfl_xor(ps, 1); ps += __shfl_xor(ps, 2);
    pd += __shfl_xor(pd, 1); pd += __shfl_xor(pd, 2);
    if (r < n){
      uint4 pk;
      pk.x = f2bf(acc[i][0]) | (f2bf(acc[i][1]) << 16);
      pk.y = f2bf(acc[i][2]) | (f2bf(acc[i][3]) << 16);
      pk.z = f2bf(acc[i][4]) | (f2bf(acc[i][5]) << 16);
      pk.w = f2bf(acc[i][6]) | (f2bf(acc[i][7]) << 16);
      *(uint4*)(y16 + (size_t)r*64 + (c0 >> 1)) = pk;
      if ((cg & 3) == 0){
        es[r*4 + hd] = ps;
        ed[r*4 + hd] = pd;
      }
    }
  }
}

// ------- SAGE dual GEMM: Y = Xa@Wa + bias + Xb@Wb, fused BN column stats ----
__global__ __launch_bounds__(256, 2) void k_gemm2(const float* __restrict__ Xa,
    const float* __restrict__ Wa, const float* __restrict__ Xb,
    const float* __restrict__ Wb, const float* __restrict__ bias,
    float* __restrict__ Y, int n, float* __restrict__ bnsum){
  __shared__ float Xs[128*128];
  __shared__ float red[16][128];
  int t = threadIdx.x;
  int rbase = blockIdx.x * 128;
  int rg = t >> 4, cg = t & 15;
  int c0 = cg * 8;
  float acc[8][8];
  #pragma unroll
  for (int i = 0; i < 8; ++i)
    #pragma unroll
    for (int j = 0; j < 8; ++j) acc[i][j] = 0.f;

  for (int pass = 0; pass < 2; ++pass){
    const float* X = pass ? Xb : Xa;
    const float* W = pass ? Wb : Wa;
    if (pass) __syncthreads();
    #pragma unroll
    for (int i = 0; i < 16; ++i){
      int f = t + i*256;
      int r = f >> 5;
      int q = f & 31;
      float4 v = make_float4(0.f,0.f,0.f,0.f);
      int gr = rbase + r;
      if (gr < n) v = *(const float4*)(X + (size_t)gr*D + q*4);
      int phys = q ^ ((r >> 3) & 3);
      *(float4*)(Xs + r*128 + phys*4) = v;
    }
    __syncthreads();
    #pragma unroll 2
    for (int kk = 0; kk < 128; kk += 4){
      float4 wA[4], wB[4];
      #pragma unroll
      for (int j = 0; j < 4; ++j){
        wA[j] = *(const float4*)(W + (kk + j)*D + c0);
        wB[j] = *(const float4*)(W + (kk + j)*D + c0 + 4);
      }
      int physq = (((kk >> 2) ^ (rg & 3)) << 2);
      #pragma unroll
      for (int i = 0; i < 8; ++i){
        float4 xv = *(const float4*)(Xs + (rg*8 + i)*128 + physq);
        float xj[4] = {xv.x, xv.y, xv.z, xv.w};
        #pragma unroll
        for (int j = 0; j < 4; ++j){
          float xs = xj[j];
          acc[i][0] += xs*wA[j].x; acc[i][1] += xs*wA[j].y;
          acc[i][2] += xs*wA[j].z; acc[i][3] += xs*wA[j].w;
          acc[i][4] += xs*wB[j].x; acc[i][5] += xs*wB[j].y;
          acc[i][6] += xs*wB[j].z; acc[i][7] += xs*wB[j].w;
        }
      }
    }
  }

  float bv[8];
  #pragma unroll
  for (int j = 0; j < 8; ++j) bv[j] = bias[c0 + j];
  float colS[8], colQ[8];
  #pragma unroll
  for (int j = 0; j < 8; ++j){ colS[j] = 0.f; colQ[j] = 0.f; }

  #pragma unroll
  for (int i = 0; i < 8; ++i){
    int r = rbase + rg*8 + i;
    if (r < n){
      float o[8];
      #pragma unroll
      for (int j = 0; j < 8; ++j){
        o[j] = acc[i][j] + bv[j];
        colS[j] += o[j];
        colQ[j] += o[j]*o[j];
      }
      float* yp = Y + (size_t)r*D + c0;
      *(float4*)yp       = make_float4(o[0],o[1],o[2],o[3]);
      *(float4*)(yp + 4) = make_float4(o[4],o[5],o[6],o[7]);
    }
  }
  __syncthreads();
  #pragma unroll
  for (int j = 0; j < 8; ++j) red[rg][c0 + j] = colS[j];
  __syncthreads();
  if (t < 128){
    float s = 0.f;
    #pragma unroll
    for (int g = 0; g < 16; ++g) s += red[g][t];
    atomicAdd(&bnsum[t], s);
  }
  __syncthreads();
  #pragma unroll
  for (int j = 0; j < 8; ++j) red[rg][c0 + j] = colQ[j];
  __syncthreads();
  if (t < 128){
    float s = 0.f;
    #pragma unroll
    for (int g = 0; g < 16; ++g) s += red[g][t];
    atomicAdd(&bnsum[128 + t], s);
  }
}

// --------- GAT aggregation: wave/node, bf16 gathers, fp32 accumulate --------
__global__ __launch_bounds__(256) void k_gat(const unsigned int* __restrict__ h16,
    const float* __restrict__ es, const float* __restrict__ edv,
    const int* __restrict__ rowStart, const int* __restrict__ srcList,
    const float* __restrict__ bias, float* __restrict__ out){
  int i = blockIdx.x*4 + (threadIdx.x >> 6);
  if (i >= N_NODES) return;
  int lane = threadIdx.x & 63;
  int hd = lane >> 4;
  int c  = lane * 2;
  float edi = edv[i*4 + hd];
  // self loop
  float2 self = bf2f2(h16[(size_t)i*64 + lane]);
  float w = __expf(lrelu(es[i*4 + hd] + edi));
  float z = w, acc0 = self.x*w, acc1 = self.y*w;
  int k0 = rowStart[i], ke = rowStart[i + 1];
  int k = k0;
  for (; k + 3 < ke; k += 4){
    int s0 = srcList[k], s1 = srcList[k+1], s2 = srcList[k+2], s3 = srcList[k+3];
    uint32_t u0 = h16[(size_t)s0*64 + lane];
    uint32_t u1 = h16[(size_t)s1*64 + lane];
    uint32_t u2 = h16[(size_t)s2*64 + lane];
    uint32_t u3 = h16[(size_t)s3*64 + lane];
    float e0 = es[s0*4 + hd], e1 = es[s1*4 + hd];
    float e2 = es[s2*4 + hd], e3 = es[s3*4 + hd];
    float w0 = __expf(lrelu(e0 + edi));
    float w1 = __expf(lrelu(e1 + edi));
    float w2 = __expf(lrelu(e2 + edi));
    float w3 = __expf(lrelu(e3 + edi));
    float2 v0 = bf2f2(u0), v1 = bf2f2(u1), v2 = bf2f2(u2), v3 = bf2f2(u3);
    z += w0 + w1 + w2 + w3;
    acc0 += v0.x*w0 + v1.x*w1 + v2.x*w2 + v3.x*w3;
    acc1 += v0.y*w0 + v1.y*w1 + v2.y*w2 + v3.y*w3;
  }
  for (; k < ke; ++k){
    int s0 = srcList[k];
    uint32_t u0 = h16[(size_t)s0*64 + lane];
    float w0 = __expf(lrelu(es[s0*4 + hd] + edi));
    float2 v0 = bf2f2(u0);
    z += w0; acc0 += v0.x*w0; acc1 += v0.y*w0;
  }
  float inv = 1.f / z;
  float2 bv = *(const float2*)(bias + c);
  *(float2*)(out + (size_t)i*D + c) = make_float2(acc0*inv + bv.x, acc1*inv + bv.y);
}

// ---------------- SAGE mean aggregation: bf16 gathers ----------------
__global__ __launch_bounds__(256) void k_sage_mean(const unsigned int* __restrict__ h16,
    const int* __restrict__ rowStart, const int* __restrict__ srcList,
    float* __restrict__ out){
  int i = blockIdx.x*4 + (threadIdx.x >> 6);
  if (i >= N_NODES) return;
  int lane = threadIdx.x & 63;
  int c = lane * 2;
  int k0 = rowStart[i], k1 = rowStart[i + 1];
  float a0 = 0.f, a1 = 0.f;
  int k = k0;
  for (; k + 3 < k1; k += 4){
    int s0 = srcList[k], s1 = srcList[k+1], s2 = srcList[k+2], s3 = srcList[k+3];
    uint32_t u0 = h16[(size_t)s0*64 + lane];
    uint32_t u1 = h16[(size_t)s1*64 + lane];
    uint32_t u2 = h16[(size_t)s2*64 + lane];
    uint32_t u3 = h16[(size_t)s3*64 + lane];
    float2 v0 = bf2f2(u0), v1 = bf2f2(u1), v2 = bf2f2(u2), v3 = bf2f2(u3);
    a0 += v0.x + v1.x + v2.x + v3.x;
    a1 += v0.y + v1.y + v2.y + v3.y;
  }
  for (; k < k1; ++k){
    uint32_t u0 = h16[(size_t)srcList[k]*64 + lane];
    float2 v0 = bf2f2(u0);
    a0 += v0.x; a1 += v0.y;
  }
  int dg = k1 - k0;
  float inv = 1.f / (float)(dg > 0 ? dg : 1);
  *(float2*)(out + (size_t)i*D + c) = make_float2(a0*inv, a1*inv);
}

// ---------------- BatchNorm stats (sum, sumsq per column) ----------------
__global__ __launch_bounds__(256) void k_bnstat(const float* __restrict__ x,
                                                float* __restrict__ sums){
  int col = threadIdx.x & 127;
  int ro  = threadIdx.x >> 7;
  float s = 0.f, s2 = 0.f;
  for (int r = blockIdx.x*2 + ro; r < N_NODES; r += gridDim.x*2){
    float v = x[(size_t)r*D + col];
    s += v; s2 += v*v;
  }
  __shared__ float rs[256], rq[256];
  rs[threadIdx.x] = s; rq[threadIdx.x] = s2;
  __syncthreads();
  if (threadIdx.x < 128){
    atomicAdd(&sums[col],       rs[threadIdx.x] + rs[threadIdx.x + 128]);
    atomicAdd(&sums[128 + col], rq[threadIdx.x] + rq[threadIdx.x + 128]);
  }
}

// --------- BN apply (+opt residual) + lrelu, optional bf16 shadow copy ------
__global__ void k_bnapply(const float* __restrict__ x, const float* __restrict__ sums,
    const float* __restrict__ g, const float* __restrict__ b,
    const float* __restrict__ res, float* __restrict__ y,
    unsigned int* __restrict__ y16){
  int f = blockIdx.x*256 + threadIdx.x;
  if (f >= N_NODES*32) return;
  int c = (f & 31) * 4;
  float4 v = *(const float4*)(x + (size_t)f*4);
  float vv[4] = {v.x, v.y, v.z, v.w};
  float rr[4] = {0.f, 0.f, 0.f, 0.f};
  if (res){
    float4 rv = *(const float4*)(res + (size_t)f*4);
    rr[0]=rv.x; rr[1]=rv.y; rr[2]=rv.z; rr[3]=rv.w;
  }
  float o[4];
  const float invn = 1.f / (float)N_NODES;
  #pragma unroll
  for (int j = 0; j < 4; ++j){
    int cc = c + j;
    float mu  = sums[cc] * invn;
    float var = sums[128 + cc] * invn - mu*mu;
    float rs  = rsqrtf(var + EPSV);
    o[j] = lrelu((vv[j] - mu)*rs*g[cc] + b[cc] + rr[j]);
  }
  *(float4*)(y + (size_t)f*4) = make_float4(o[0], o[1], o[2], o[3]);
  if (y16){
    uint2 pk;
    pk.x = f2bf(o[0]) | (f2bf(o[1]) << 16);
    pk.y = f2bf(o[2]) | (f2bf(o[3]) << 16);
    *(uint2*)(y16 + (size_t)f*2) = pk;
  }
}

// ---------------- global mean pool (batch sorted -> run-length) -------------
__global__ __launch_bounds__(256) void k_pool(const float* __restrict__ h,
    const int* __restrict__ batch, float* __restrict__ pooled,
    float* __restrict__ cnt){
  int col = threadIdx.x & 127;
  int ro  = threadIdx.x >> 7;
  int base = blockIdx.x * 128;
  int g_cur = -1; float acc = 0.f, cacc = 0.f;
  for (int ii = 0; ii < 64; ++ii){
    int r = base + ro + ii*2;
    if (r >= N_NODES) break;
    int g = batch[r];
    if (g != g_cur){
      if (g_cur >= 0){
        atomicAdd(&pooled[g_cur*D + col], acc);
        if (col == 0) atomicAdd(&cnt[g_cur], cacc);
      }
      acc = 0.f; cacc = 0.f; g_cur = g;
    }
    acc  += h[(size_t)r*D + col];
    cacc += 1.f;
  }
  if (g_cur >= 0){
    atomicAdd(&pooled[g_cur*D + col], acc);
    if (col == 0) atomicAdd(&cnt[g_cur], cacc);
  }
}

// ---------------- final FC on pooled ----------------
__global__ void k_fc(const float* __restrict__ pooled, const float* __restrict__ cnt,
    const float* __restrict__ W, const float* __restrict__ b, float* __restrict__ out){
  int idx = blockIdx.x*256 + threadIdx.x;
  if (idx >= GR*64) return;
  int g = idx >> 6, o = idx & 63;
  const float* p = pooled + g*D;
  float s = 0.f;
  for (int c2 = 0; c2 < D; ++c2) s += p[c2] * W[c2*64 + o];
  float inv = 1.f / fmaxf(cnt[g], 1.f);
  out[idx] = s*inv + b[o];
}

extern "C" void kernel_launch(void* const* d_in, const int* in_sizes, int n_in,
                              void* d_out, int out_size, void* d_ws, size_t ws_size,
                              hipStream_t stream){
  (void)in_sizes; (void)n_in; (void)out_size; (void)ws_size;
  const float* x       = (const float*)d_in[0];
  const int*   ei      = (const int*)  d_in[1];
  const int*   batch   = (const int*)  d_in[2];
  const float* gat1_W  = (const float*)d_in[3];
  const float* gat1_as = (const float*)d_in[4];
  const float* gat1_ad = (const float*)d_in[5];
  const float* gat1_b  = (const float*)d_in[6];
  const float* gat2_W  = (const float*)d_in[7];
  const float* gat2_as = (const float*)d_in[8];
  const float* gat2_ad = (const float*)d_in[9];
  const float* gat2_b  = (const float*)d_in[10];
  const float* s3_Wl   = (const float*)d_in[11];
  const float* s3_bl   = (const float*)d_in[12];
  const float* s3_Wr   = (const float*)d_in[13];
  const float* s4_Wl   = (const float*)d_in[14];
  const float* s4_bl   = (const float*)d_in[15];
  const float* s4_Wr   = (const float*)d_in[16];
  const float* s5_Wl   = (const float*)d_in[17];
  const float* s5_bl   = (const float*)d_in[18];
  const float* s5_Wr   = (const float*)d_in[19];
  const float* bn1_g = (const float*)d_in[20]; const float* bn1_b = (const float*)d_in[21];
  const float* bn2_g = (const float*)d_in[22]; const float* bn2_b = (const float*)d_in[23];
  const float* bn3_g = (const float*)d_in[24]; const float* bn3_b = (const float*)d_in[25];
  const float* bn4_g = (const float*)d_in[26]; const float* bn4_b = (const float*)d_in[27];
  const float* bn5_g = (const float*)d_in[28]; const float* bn5_b = (const float*)d_in[29];
  const float* res1_W = (const float*)d_in[30]; const float* res1_b = (const float*)d_in[31];
  const float* res2_W = (const float*)d_in[32]; const float* res2_b = (const float*)d_in[33];
  const float* fc_W   = (const float*)d_in[34]; const float* fc_b   = (const float*)d_in[35];
  float* out = (float*)d_out;

  char* ws = (char*)d_ws;
  size_t off = 0;
  auto alloc = [&](size_t bytes) -> void* {
    void* p = ws + off; off += (bytes + 255) & ~(size_t)255; return p;
  };
  int*   rowStart = (int*)  alloc((N_NODES + 1) * 4);
  int*   cursor   = (int*)  alloc((size_t)N_NODES * 4);
  int*   srcList  = (int*)  alloc((size_t)N_EDGES * 4);
  int*   bsum     = (int*)  alloc(256 * 4);
  float* bnsums   = (float*)alloc(5 * 256 * 4);
  float* pooled   = (float*)alloc(GR * D * 4);
  float* cnt      = (float*)alloc(64 * 4);
  float* es       = (float*)alloc((size_t)N_NODES * 4 * 4);
  float* edv      = (float*)alloc((size_t)N_NODES * 4 * 4);
  unsigned int* H16 = (unsigned int*)alloc((size_t)N_NODES * 64 * 4); // bf16 shadow
  float* B1       = (float*)alloc((size_t)N_NODES * D * 4);
  float* B2       = (float*)alloc((size_t)N_NODES * D * 4);
  float* B3       = (float*)alloc((size_t)N_NODES * D * 4);

  const int* srcE = ei;
  const int* dstE = ei + N_EDGES;
  const int nb = (N_NODES + 255) / 256;
  const int egrid = (N_EDGES + 255) / 256;
  const int ggrid = (N_NODES + 127) / 128;
  const int agrid = (N_NODES + 3) / 4;
  const int bgrid = (N_NODES*32 + 255) / 256;

  // CSR build
  hipMemsetAsync(cursor, 0, (size_t)N_NODES*4, stream);
  k_count<<<egrid, 256, 0, stream>>>(dstE, cursor);
  k_scan1<<<nb, 256, 0, stream>>>(cursor, bsum);
  k_scan2<<<1, 1, 0, stream>>>(bsum, nb, rowStart);
  k_scan3<<<nb, 256, 0, stream>>>(cursor, bsum, rowStart);
  hipMemsetAsync(cursor, 0, (size_t)N_NODES*4, stream);
  k_fill<<<egrid, 256, 0, stream>>>(srcE, dstE, rowStart, cursor, srcList);

  hipMemsetAsync(bnsums, 0, 5*256*4, stream);

  // ---- layer 1 (GAT) ----
  k_gemm<<<ggrid, 256, 0, stream>>>(x, res1_W, res1_b, B1, N_NODES);
  k_gemm_gat<<<ggrid, 256, 0, stream>>>(x, gat1_W, gat1_as, gat1_ad, H16, es, edv, N_NODES);
  k_gat<<<agrid, 256, 0, stream>>>(H16, es, edv, rowStart, srcList, gat1_b, B3);
  k_bnstat<<<256, 256, 0, stream>>>(B3, bnsums);
  k_bnapply<<<bgrid, 256, 0, stream>>>(B3, bnsums, bn1_g, bn1_b, B1, B2, nullptr); // h1 -> B2

  // ---- layer 2 (GAT) ----
  k_gemm<<<ggrid, 256, 0, stream>>>(B2, res2_W, res2_b, B1, N_NODES);
  k_gemm_gat<<<ggrid, 256, 0, stream>>>(B2, gat2_W, gat2_as, gat2_ad, H16, es, edv, N_NODES);
  k_gat<<<agrid, 256, 0, stream>>>(H16, es, edv, rowStart, srcList, gat2_b, B2);
  k_bnstat<<<256, 256, 0, stream>>>(B2, bnsums + 256);
  k_bnapply<<<bgrid, 256, 0, stream>>>(B2, bnsums + 256, bn2_g, bn2_b, B1, B2, H16); // h2 -> B2,H16

  // ---- layer 3 (SAGE) ----
  k_sage_mean<<<agrid, 256, 0, stream>>>(H16, rowStart, srcList, B3);
  k_gemm2<<<ggrid, 256, 0, stream>>>(B3, s3_Wl, B2, s3_Wr, s3_bl, B1, N_NODES, bnsums + 2*256);
  k_bnapply<<<bgrid, 256, 0, stream>>>(B1, bnsums + 2*256, bn3_g, bn3_b, nullptr, B1, H16); // h3 -> B1,H16

  // ---- layer 4 (SAGE) ----
  k_sage_mean<<<agrid, 256, 0, stream>>>(H16, rowStart, srcList, B3);
  k_gemm2<<<ggrid, 256, 0, stream>>>(B3, s4_Wl, B1, s4_Wr, s4_bl, B2, N_NODES, bnsums + 3*256);
  k_bnapply<<<bgrid, 256, 0, stream>>>(B2, bnsums + 3*256, bn4_g, bn4_b, nullptr, B2, H16); // h4 -> B2,H16

  // ---- layer 5 (SAGE) ----
  k_sage_mean<<<agrid, 256, 0, stream>>>(H16, rowStart, srcList, B3);
  k_gemm2<<<ggrid, 256, 0, stream>>>(B3, s5_Wl, B2, s5_Wr, s5_bl, B1, N_NODES, bnsums + 4*256);
  k_bnapply<<<bgrid, 256, 0, stream>>>(B1, bnsums + 4*256, bn5_g, bn5_b, nullptr, B1, nullptr); // h5 -> B1

  // ---- pool + fc ----
  hipMemsetAsync(pooled, 0, (GR*D + 64)*4, stream);
  k_pool<<<ggrid, 256, 0, stream>>>(B1, batch, pooled, cnt);
  k_fc<<<(GR*64 + 255)/256, 256, 0, stream>>>(pooled, cnt, fc_W, fc_b, out);
}

// Round 4
// 780.778 us; speedup vs baseline: 1.6511x; 1.1842x over previous
//
#include <hip/hip_runtime.h>
#include <math.h>
#include <stdint.h>

#define N_NODES 50000
#define N_EDGES 800000
#define D 128
#define GR 50
#define EPSV 1e-5f

typedef __attribute__((ext_vector_type(8))) short bf16x8;
typedef __attribute__((ext_vector_type(4))) float f32x4;

__device__ __forceinline__ float lrelu(float v){ return v > 0.f ? v : 0.2f*v; }

__device__ __forceinline__ unsigned int f2bf(float f){
  union { float f; uint32_t i; } v; v.f = f;
  uint32_t r = v.i + 0x7fffu + ((v.i >> 16) & 1u);
  return r >> 16;
}
__device__ __forceinline__ float2 bf2f2(uint32_t u){
  union { uint32_t i; float f; } a, b;
  a.i = u << 16;
  b.i = u & 0xffff0000u;
  return make_float2(a.f, b.f);
}

// ---------------- CSR build ----------------
__global__ void k_count(const int* __restrict__ dst, int* __restrict__ deg){
  int e = blockIdx.x*256 + threadIdx.x;
  if (e < N_EDGES) atomicAdd(&deg[dst[e]], 1);
}
__global__ void k_scan1(const int* __restrict__ deg, int* __restrict__ bsum){
  __shared__ int s[256];
  int i = blockIdx.x*256 + threadIdx.x;
  int v = (i < N_NODES) ? deg[i] : 0;
  s[threadIdx.x] = v; __syncthreads();
  for (int off = 128; off > 0; off >>= 1){
    if (threadIdx.x < off) s[threadIdx.x] += s[threadIdx.x + off];
    __syncthreads();
  }
  if (threadIdx.x == 0) bsum[blockIdx.x] = s[0];
}
__global__ void k_scan2(int* bsum, int nb, int* rowStart){
  int run = 0;
  for (int b = 0; b < nb; ++b){ int t = bsum[b]; bsum[b] = run; run += t; }
  rowStart[N_NODES] = run;
}
__global__ void k_scan3(const int* __restrict__ deg, const int* __restrict__ bsum,
                        int* __restrict__ rowStart){
  __shared__ int s[256];
  int i = blockIdx.x*256 + threadIdx.x;
  int v = (i < N_NODES) ? deg[i] : 0;
  s[threadIdx.x] = v; __syncthreads();
  for (int off = 1; off < 256; off <<= 1){
    int xv = (threadIdx.x >= off) ? s[threadIdx.x - off] : 0;
    __syncthreads();
    s[threadIdx.x] += xv;
    __syncthreads();
  }
  if (i < N_NODES) rowStart[i] = bsum[blockIdx.x] + s[threadIdx.x] - v;
}
__global__ void k_fill(const int* __restrict__ src, const int* __restrict__ dst,
                       const int* __restrict__ rowStart, int* __restrict__ cursor,
                       int* __restrict__ srcList){
  int e = blockIdx.x*256 + threadIdx.x;
  if (e < N_EDGES){
    int d = dst[e];
    int pos = rowStart[d] + atomicAdd(&cursor[d], 1);
    srcList[pos] = src[e];
  }
}

// ---------------- casts ----------------
__global__ void k_cast_x(const float* __restrict__ x, unsigned short* __restrict__ x16){
  int idx = blockIdx.x*256 + threadIdx.x;     // float4 granule
  if (idx >= N_NODES*32) return;
  float4 v = *(const float4*)(x + (size_t)idx*4);
  uint2 pk;
  pk.x = f2bf(v.x) | (f2bf(v.y) << 16);
  pk.y = f2bf(v.z) | (f2bf(v.w) << 16);
  *(uint2*)(x16 + (size_t)idx*4) = pk;
}

struct WPack { const float* w[10]; };
// Wt16[mat][c*128 + k] = bf16(W[mat][k*128 + c])   (col-major transpose)
__global__ void k_castw(WPack p, unsigned short* __restrict__ wt){
  int mat = blockIdx.x >> 6;
  int local = (blockIdx.x & 63)*256 + threadIdx.x;  // 0..16383
  int c = local >> 7, k = local & 127;
  wt[(size_t)mat*16384 + c*128 + k] = (unsigned short)f2bf(p.w[mat][k*128 + c]);
}

// ======================= MFMA GEMM family =======================
// Block: 256 thr = 4 waves; block tile 64 rows x 128 cols; wave = 16 rows.
// A: X16 row-major bf16 (stride 128). B: Wt16 col-major bf16 staged in LDS
// (pad col stride to 136). mfma_f32_16x16x32_bf16:
//   A[m=lane&15][k=quad*8+j], B[k=quad*8+j][n=lane&15], D[row=quad*4+reg][col=lane&15].

__device__ __forceinline__ void stage_w(const unsigned short* __restrict__ wt,
                                        unsigned short* __restrict__ lds, int t){
  #pragma unroll
  for (int i = 0; i < 8; ++i){
    int ch = i*256 + t;             // 16B chunk id, 2048 total
    int col = ch >> 4, kc = ch & 15;
    *(uint4*)(&lds[col*136 + kc*8]) = *(const uint4*)(wt + ((size_t)col << 7) + (kc << 3));
  }
}

__device__ __forceinline__ void mfma_k128(const unsigned short* __restrict__ xrow,
                                          const unsigned short* __restrict__ lds,
                                          int lane, f32x4 acc[8]){
  int quad = lane >> 4, m = lane & 15;
  #pragma unroll
  for (int ks = 0; ks < 4; ++ks){
    bf16x8 a = *(const bf16x8*)(xrow + ks*32 + quad*8);
    #pragma unroll
    for (int nt = 0; nt < 8; ++nt){
      bf16x8 b = *(const bf16x8*)(&lds[(nt*16 + m)*136 + ks*32 + quad*8]);
      acc[nt] = __builtin_amdgcn_mfma_f32_16x16x32_bf16(a, b, acc[nt], 0, 0, 0);
    }
  }
}

// ---- residual GEMM: Y(fp32) = X16 @ W + bias ----
__global__ __launch_bounds__(256) void k_mgemm(const unsigned short* __restrict__ X16,
    const unsigned short* __restrict__ wt, const float* __restrict__ bias,
    float* __restrict__ Y, int n){
  __shared__ __align__(16) unsigned short Wlds[128*136];
  int t = threadIdx.x, lane = t & 63, w = t >> 6;
  int quad = lane >> 4, m = lane & 15;
  int rbase = blockIdx.x*64 + w*16;
  stage_w(wt, Wlds, t);
  f32x4 acc[8];
  #pragma unroll
  for (int nt = 0; nt < 8; ++nt){ acc[nt][0]=0.f; acc[nt][1]=0.f; acc[nt][2]=0.f; acc[nt][3]=0.f; }
  int rowA = rbase + m; if (rowA >= n) rowA = n - 1;
  __syncthreads();
  mfma_k128(X16 + (size_t)rowA*128, Wlds, lane, acc);
  #pragma unroll
  for (int nt = 0; nt < 8; ++nt){
    int col = nt*16 + m;
    float bv = bias[col];
    #pragma unroll
    for (int reg = 0; reg < 4; ++reg){
      int row = rbase + quad*4 + reg;
      if (row < n) Y[(size_t)row*128 + col] = acc[nt][reg] + bv;
    }
  }
}

// ---- GAT GEMM: H16 = bf16(X16 @ W), fused es/ed ----
__global__ __launch_bounds__(256) void k_mgemm_gat(const unsigned short* __restrict__ X16,
    const unsigned short* __restrict__ wt, const float* __restrict__ as_,
    const float* __restrict__ ad_, unsigned short* __restrict__ H16,
    float* __restrict__ es, float* __restrict__ ed, int n){
  __shared__ __align__(16) unsigned short Wlds[128*136];
  int t = threadIdx.x, lane = t & 63, w = t >> 6;
  int quad = lane >> 4, m = lane & 15;
  int rbase = blockIdx.x*64 + w*16;
  stage_w(wt, Wlds, t);
  f32x4 acc[8];
  #pragma unroll
  for (int nt = 0; nt < 8; ++nt){ acc[nt][0]=0.f; acc[nt][1]=0.f; acc[nt][2]=0.f; acc[nt][3]=0.f; }
  int rowA = rbase + m; if (rowA >= n) rowA = n - 1;
  __syncthreads();
  mfma_k128(X16 + (size_t)rowA*128, Wlds, lane, acc);

  float asv[8], adv[8];
  #pragma unroll
  for (int nt = 0; nt < 8; ++nt){ asv[nt] = as_[nt*16 + m]; adv[nt] = ad_[nt*16 + m]; }

  #pragma unroll
  for (int reg = 0; reg < 4; ++reg){
    int row = rbase + quad*4 + reg;
    float pe[4], pd[4];
    #pragma unroll
    for (int h = 0; h < 4; ++h){
      pe[h] = acc[2*h][reg]*asv[2*h] + acc[2*h+1][reg]*asv[2*h+1];
      pd[h] = acc[2*h][reg]*adv[2*h] + acc[2*h+1][reg]*adv[2*h+1];
    }
    #pragma unroll
    for (int h = 0; h < 4; ++h){
      pe[h] += __shfl_xor(pe[h], 1); pe[h] += __shfl_xor(pe[h], 2);
      pe[h] += __shfl_xor(pe[h], 4); pe[h] += __shfl_xor(pe[h], 8);
      pd[h] += __shfl_xor(pd[h], 1); pd[h] += __shfl_xor(pd[h], 2);
      pd[h] += __shfl_xor(pd[h], 4); pd[h] += __shfl_xor(pd[h], 8);
    }
    if (m == 0 && row < n){
      #pragma unroll
      for (int h = 0; h < 4; ++h){ es[row*4 + h] = pe[h]; ed[row*4 + h] = pd[h]; }
    }
  }
  #pragma unroll
  for (int nt = 0; nt < 8; ++nt){
    int col = nt*16 + m;
    #pragma unroll
    for (int reg = 0; reg < 4; ++reg){
      int row = rbase + quad*4 + reg;
      if (row < n) H16[(size_t)row*128 + col] = (unsigned short)f2bf(acc[nt][reg]);
    }
  }
}

// ---- SAGE dual GEMM: Y(fp32) = Xa16@Wa + bias + Xb16@Wb, fused BN stats ----
__global__ __launch_bounds__(256) void k_mgemm2(const unsigned short* __restrict__ Xa,
    const unsigned short* __restrict__ wta, const unsigned short* __restrict__ Xb,
    const unsigned short* __restrict__ wtb, const float* __restrict__ bias,
    float* __restrict__ Y, int n, float* __restrict__ bnsum){
  __shared__ __align__(16) unsigned short Wlds[128*136];
  __shared__ float redS[128], redQ[128];
  int t = threadIdx.x, lane = t & 63, w = t >> 6;
  int quad = lane >> 4, m = lane & 15;
  int rbase = blockIdx.x*64 + w*16;
  if (t < 128){ redS[t] = 0.f; redQ[t] = 0.f; }
  f32x4 acc[8];
  #pragma unroll
  for (int nt = 0; nt < 8; ++nt){ acc[nt][0]=0.f; acc[nt][1]=0.f; acc[nt][2]=0.f; acc[nt][3]=0.f; }
  int rowA = rbase + m; if (rowA >= n) rowA = n - 1;

  stage_w(wta, Wlds, t);
  __syncthreads();
  mfma_k128(Xa + (size_t)rowA*128, Wlds, lane, acc);
  __syncthreads();
  stage_w(wtb, Wlds, t);
  __syncthreads();
  mfma_k128(Xb + (size_t)rowA*128, Wlds, lane, acc);

  #pragma unroll
  for (int nt = 0; nt < 8; ++nt){
    int col = nt*16 + m;
    float bv = bias[col];
    float s = 0.f, q = 0.f;
    #pragma unroll
    for (int reg = 0; reg < 4; ++reg){
      int row = rbase + quad*4 + reg;
      if (row < n){
        float o = acc[nt][reg] + bv;
        Y[(size_t)row*128 + col] = o;
        s += o; q += o*o;
      }
    }
    atomicAdd(&redS[col], s);
    atomicAdd(&redQ[col], q);
  }
  __syncthreads();
  if (t < 128){
    atomicAdd(&bnsum[t],       redS[t]);
    atomicAdd(&bnsum[128 + t], redQ[t]);
  }
}

// --------- GAT aggregation: wave/node, bf16 gathers ----------
__global__ __launch_bounds__(256) void k_gat(const unsigned int* __restrict__ h16,
    const float* __restrict__ es, const float* __restrict__ edv,
    const int* __restrict__ rowStart, const int* __restrict__ srcList,
    const float* __restrict__ bias, float* __restrict__ out){
  int i = blockIdx.x*4 + (threadIdx.x >> 6);
  if (i >= N_NODES) return;
  int lane = threadIdx.x & 63;
  int hd = lane >> 4;
  int c  = lane * 2;
  float edi = edv[i*4 + hd];
  float2 self = bf2f2(h16[(size_t)i*64 + lane]);
  float w = __expf(lrelu(es[i*4 + hd] + edi));
  float z = w, acc0 = self.x*w, acc1 = self.y*w;
  int k0 = rowStart[i], ke = rowStart[i + 1];
  int k = k0;
  for (; k + 3 < ke; k += 4){
    int s0 = srcList[k], s1 = srcList[k+1], s2 = srcList[k+2], s3 = srcList[k+3];
    uint32_t u0 = h16[(size_t)s0*64 + lane];
    uint32_t u1 = h16[(size_t)s1*64 + lane];
    uint32_t u2 = h16[(size_t)s2*64 + lane];
    uint32_t u3 = h16[(size_t)s3*64 + lane];
    float w0 = __expf(lrelu(es[s0*4 + hd] + edi));
    float w1 = __expf(lrelu(es[s1*4 + hd] + edi));
    float w2 = __expf(lrelu(es[s2*4 + hd] + edi));
    float w3 = __expf(lrelu(es[s3*4 + hd] + edi));
    float2 v0 = bf2f2(u0), v1 = bf2f2(u1), v2 = bf2f2(u2), v3 = bf2f2(u3);
    z += w0 + w1 + w2 + w3;
    acc0 += v0.x*w0 + v1.x*w1 + v2.x*w2 + v3.x*w3;
    acc1 += v0.y*w0 + v1.y*w1 + v2.y*w2 + v3.y*w3;
  }
  for (; k < ke; ++k){
    int s0 = srcList[k];
    uint32_t u0 = h16[(size_t)s0*64 + lane];
    float w0 = __expf(lrelu(es[s0*4 + hd] + edi));
    float2 v0 = bf2f2(u0);
    z += w0; acc0 += v0.x*w0; acc1 += v0.y*w0;
  }
  float inv = 1.f / z;
  float2 bv = *(const float2*)(bias + c);
  *(float2*)(out + (size_t)i*D + c) = make_float2(acc0*inv + bv.x, acc1*inv + bv.y);
}

// ---------------- SAGE mean aggregation: bf16 in, bf16 out ----------------
__global__ __launch_bounds__(256) void k_sage_mean(const unsigned int* __restrict__ h16,
    const int* __restrict__ rowStart, const int* __restrict__ srcList,
    unsigned int* __restrict__ out16){
  int i = blockIdx.x*4 + (threadIdx.x >> 6);
  if (i >= N_NODES) return;
  int lane = threadIdx.x & 63;
  int k0 = rowStart[i], k1 = rowStart[i + 1];
  float a0 = 0.f, a1 = 0.f;
  int k = k0;
  for (; k + 3 < k1; k += 4){
    int s0 = srcList[k], s1 = srcList[k+1], s2 = srcList[k+2], s3 = srcList[k+3];
    uint32_t u0 = h16[(size_t)s0*64 + lane];
    uint32_t u1 = h16[(size_t)s1*64 + lane];
    uint32_t u2 = h16[(size_t)s2*64 + lane];
    uint32_t u3 = h16[(size_t)s3*64 + lane];
    float2 v0 = bf2f2(u0), v1 = bf2f2(u1), v2 = bf2f2(u2), v3 = bf2f2(u3);
    a0 += v0.x + v1.x + v2.x + v3.x;
    a1 += v0.y + v1.y + v2.y + v3.y;
  }
  for (; k < k1; ++k){
    uint32_t u0 = h16[(size_t)srcList[k]*64 + lane];
    float2 v0 = bf2f2(u0);
    a0 += v0.x; a1 += v0.y;
  }
  int dg = k1 - k0;
  float inv = 1.f / (float)(dg > 0 ? dg : 1);
  out16[(size_t)i*64 + lane] = f2bf(a0*inv) | (f2bf(a1*inv) << 16);
}

// ---------------- BatchNorm stats ----------------
__global__ __launch_bounds__(256) void k_bnstat(const float* __restrict__ x,
                                                float* __restrict__ sums){
  int col = threadIdx.x & 127;
  int ro  = threadIdx.x >> 7;
  float s = 0.f, s2 = 0.f;
  for (int r = blockIdx.x*2 + ro; r < N_NODES; r += gridDim.x*2){
    float v = x[(size_t)r*D + col];
    s += v; s2 += v*v;
  }
  __shared__ float rs[256], rq[256];
  rs[threadIdx.x] = s; rq[threadIdx.x] = s2;
  __syncthreads();
  if (threadIdx.x < 128){
    atomicAdd(&sums[col],       rs[threadIdx.x] + rs[threadIdx.x + 128]);
    atomicAdd(&sums[128 + col], rq[threadIdx.x] + rq[threadIdx.x + 128]);
  }
}

// --------- BN apply (+opt residual) + lrelu; optional fp32 / bf16 outputs ---
__global__ void k_bnapply(const float* __restrict__ x, const float* __restrict__ sums,
    const float* __restrict__ g, const float* __restrict__ b,
    const float* __restrict__ res, float* __restrict__ y,
    unsigned int* __restrict__ y16){
  int f = blockIdx.x*256 + threadIdx.x;
  if (f >= N_NODES*32) return;
  int c = (f & 31) * 4;
  float4 v = *(const float4*)(x + (size_t)f*4);
  float vv[4] = {v.x, v.y, v.z, v.w};
  float rr[4] = {0.f, 0.f, 0.f, 0.f};
  if (res){
    float4 rv = *(const float4*)(res + (size_t)f*4);
    rr[0]=rv.x; rr[1]=rv.y; rr[2]=rv.z; rr[3]=rv.w;
  }
  float o[4];
  const float invn = 1.f / (float)N_NODES;
  #pragma unroll
  for (int j = 0; j < 4; ++j){
    int cc = c + j;
    float mu  = sums[cc] * invn;
    float var = sums[128 + cc] * invn - mu*mu;
    float rs  = rsqrtf(var + EPSV);
    o[j] = lrelu((vv[j] - mu)*rs*g[cc] + b[cc] + rr[j]);
  }
  if (y) *(float4*)(y + (size_t)f*4) = make_float4(o[0], o[1], o[2], o[3]);
  if (y16){
    uint2 pk;
    pk.x = f2bf(o[0]) | (f2bf(o[1]) << 16);
    pk.y = f2bf(o[2]) | (f2bf(o[3]) << 16);
    *(uint2*)(y16 + (size_t)f*2) = pk;
  }
}

// ---------------- global mean pool ----------------
__global__ __launch_bounds__(256) void k_pool(const float* __restrict__ h,
    const int* __restrict__ batch, float* __restrict__ pooled,
    float* __restrict__ cnt){
  int col = threadIdx.x & 127;
  int ro  = threadIdx.x >> 7;
  int base = blockIdx.x * 128;
  int g_cur = -1; float acc = 0.f, cacc = 0.f;
  for (int ii = 0; ii < 64; ++ii){
    int r = base + ro + ii*2;
    if (r >= N_NODES) break;
    int g = batch[r];
    if (g != g_cur){
      if (g_cur >= 0){
        atomicAdd(&pooled[g_cur*D + col], acc);
        if (col == 0) atomicAdd(&cnt[g_cur], cacc);
      }
      acc = 0.f; cacc = 0.f; g_cur = g;
    }
    acc  += h[(size_t)r*D + col];
    cacc += 1.f;
  }
  if (g_cur >= 0){
    atomicAdd(&pooled[g_cur*D + col], acc);
    if (col == 0) atomicAdd(&cnt[g_cur], cacc);
  }
}

// ---------------- final FC ----------------
__global__ void k_fc(const float* __restrict__ pooled, const float* __restrict__ cnt,
    const float* __restrict__ W, const float* __restrict__ b, float* __restrict__ out){
  int idx = blockIdx.x*256 + threadIdx.x;
  if (idx >= GR*64) return;
  int g = idx >> 6, o = idx & 63;
  const float* p = pooled + g*D;
  float s = 0.f;
  for (int c2 = 0; c2 < D; ++c2) s += p[c2] * W[c2*64 + o];
  float inv = 1.f / fmaxf(cnt[g], 1.f);
  out[idx] = s*inv + b[o];
}

extern "C" void kernel_launch(void* const* d_in, const int* in_sizes, int n_in,
                              void* d_out, int out_size, void* d_ws, size_t ws_size,
                              hipStream_t stream){
  (void)in_sizes; (void)n_in; (void)out_size; (void)ws_size;
  const float* x       = (const float*)d_in[0];
  const int*   ei      = (const int*)  d_in[1];
  const int*   batch   = (const int*)  d_in[2];
  const float* gat1_W  = (const float*)d_in[3];
  const float* gat1_as = (const float*)d_in[4];
  const float* gat1_ad = (const float*)d_in[5];
  const float* gat1_b  = (const float*)d_in[6];
  const float* gat2_W  = (const float*)d_in[7];
  const float* gat2_as = (const float*)d_in[8];
  const float* gat2_ad = (const float*)d_in[9];
  const float* gat2_b  = (const float*)d_in[10];
  const float* s3_Wl   = (const float*)d_in[11];
  const float* s3_bl   = (const float*)d_in[12];
  const float* s3_Wr   = (const float*)d_in[13];
  const float* s4_Wl   = (const float*)d_in[14];
  const float* s4_bl   = (const float*)d_in[15];
  const float* s4_Wr   = (const float*)d_in[16];
  const float* s5_Wl   = (const float*)d_in[17];
  const float* s5_bl   = (const float*)d_in[18];
  const float* s5_Wr   = (const float*)d_in[19];
  const float* bn1_g = (const float*)d_in[20]; const float* bn1_b = (const float*)d_in[21];
  const float* bn2_g = (const float*)d_in[22]; const float* bn2_b = (const float*)d_in[23];
  const float* bn3_g = (const float*)d_in[24]; const float* bn3_b = (const float*)d_in[25];
  const float* bn4_g = (const float*)d_in[26]; const float* bn4_b = (const float*)d_in[27];
  const float* bn5_g = (const float*)d_in[28]; const float* bn5_b = (const float*)d_in[29];
  const float* res1_W = (const float*)d_in[30]; const float* res1_b = (const float*)d_in[31];
  const float* res2_W = (const float*)d_in[32]; const float* res2_b = (const float*)d_in[33];
  const float* fc_W   = (const float*)d_in[34]; const float* fc_b   = (const float*)d_in[35];
  float* out = (float*)d_out;

  char* ws = (char*)d_ws;
  size_t off = 0;
  auto alloc = [&](size_t bytes) -> void* {
    void* p = ws + off; off += (bytes + 255) & ~(size_t)255; return p;
  };
  int*   rowStart = (int*)  alloc((N_NODES + 1) * 4);
  int*   cursor   = (int*)  alloc((size_t)N_NODES * 4);
  int*   srcList  = (int*)  alloc((size_t)N_EDGES * 4);
  int*   bsum     = (int*)  alloc(256 * 4);
  float* bnsums   = (float*)alloc(5 * 256 * 4);
  float* pooled   = (float*)alloc(GR * D * 4);
  float* cnt      = (float*)alloc(64 * 4);
  float* es       = (float*)alloc((size_t)N_NODES * 4 * 4);
  float* edv      = (float*)alloc((size_t)N_NODES * 4 * 4);
  unsigned short* Wt16 = (unsigned short*)alloc(10 * 16384 * 2);
  unsigned short* HX   = (unsigned short*)alloc((size_t)N_NODES * D * 2); // x16 / gat2-h / mean16
  unsigned short* H16a = (unsigned short*)alloc((size_t)N_NODES * D * 2); // gat1-h / h1..h4
  float* B1 = (float*)alloc((size_t)N_NODES * D * 4);  // res / gemm2 out
  float* B3 = (float*)alloc((size_t)N_NODES * D * 4);  // GAT agg out / h5

  const int* srcE = ei;
  const int* dstE = ei + N_EDGES;
  const int nb = (N_NODES + 255) / 256;
  const int egrid = (N_EDGES + 255) / 256;
  const int mgrid = (N_NODES + 63) / 64;     // mfma gemm blocks (64 rows)
  const int agrid = (N_NODES + 3) / 4;
  const int bgrid = (N_NODES*32 + 255) / 256;
  const int pgrid = (N_NODES + 127) / 128;

  // CSR build
  hipMemsetAsync(cursor, 0, (size_t)N_NODES*4, stream);
  k_count<<<egrid, 256, 0, stream>>>(dstE, cursor);
  k_scan1<<<nb, 256, 0, stream>>>(cursor, bsum);
  k_scan2<<<1, 1, 0, stream>>>(bsum, nb, rowStart);
  k_scan3<<<nb, 256, 0, stream>>>(cursor, bsum, rowStart);
  hipMemsetAsync(cursor, 0, (size_t)N_NODES*4, stream);
  k_fill<<<egrid, 256, 0, stream>>>(srcE, dstE, rowStart, cursor, srcList);

  // weight + input casts
  WPack wp;
  wp.w[0]=res1_W; wp.w[1]=gat1_W; wp.w[2]=res2_W; wp.w[3]=gat2_W;
  wp.w[4]=s3_Wl;  wp.w[5]=s3_Wr;  wp.w[6]=s4_Wl;  wp.w[7]=s4_Wr;
  wp.w[8]=s5_Wl;  wp.w[9]=s5_Wr;
  k_castw<<<640, 256, 0, stream>>>(wp, Wt16);
  k_cast_x<<<bgrid, 256, 0, stream>>>(x, HX);
  hipMemsetAsync(bnsums, 0, 5*256*4, stream);

  // ---- layer 1 (GAT) ----
  k_mgemm<<<mgrid, 256, 0, stream>>>(HX, Wt16 + 0*16384, res1_b, B1, N_NODES);
  k_mgemm_gat<<<mgrid, 256, 0, stream>>>(HX, Wt16 + 1*16384, gat1_as, gat1_ad,
                                         H16a, es, edv, N_NODES);
  k_gat<<<agrid, 256, 0, stream>>>((const unsigned int*)H16a, es, edv, rowStart, srcList, gat1_b, B3);
  k_bnstat<<<256, 256, 0, stream>>>(B3, bnsums);
  k_bnapply<<<bgrid, 256, 0, stream>>>(B3, bnsums, bn1_g, bn1_b, B1,
                                       nullptr, (unsigned int*)H16a);   // h1 -> H16a

  // ---- layer 2 (GAT) ----
  k_mgemm<<<mgrid, 256, 0, stream>>>(H16a, Wt16 + 2*16384, res2_b, B1, N_NODES);
  k_mgemm_gat<<<mgrid, 256, 0, stream>>>(H16a, Wt16 + 3*16384, gat2_as, gat2_ad,
                                         HX, es, edv, N_NODES);
  k_gat<<<agrid, 256, 0, stream>>>((const unsigned int*)HX, es, edv, rowStart, srcList, gat2_b, B3);
  k_bnstat<<<256, 256, 0, stream>>>(B3, bnsums + 256);
  k_bnapply<<<bgrid, 256, 0, stream>>>(B3, bnsums + 256, bn2_g, bn2_b, B1,
                                       nullptr, (unsigned int*)H16a);   // h2 -> H16a

  // ---- layer 3 (SAGE) ----
  k_sage_mean<<<agrid, 256, 0, stream>>>((const unsigned int*)H16a, rowStart, srcList,
                                         (unsigned int*)HX);
  k_mgemm2<<<mgrid, 256, 0, stream>>>(HX, Wt16 + 4*16384, H16a, Wt16 + 5*16384,
                                      s3_bl, B1, N_NODES, bnsums + 512);
  k_bnapply<<<bgrid, 256, 0, stream>>>(B1, bnsums + 512, bn3_g, bn3_b, nullptr,
                                       nullptr, (unsigned int*)H16a);   // h3 -> H16a

  // ---- layer 4 (SAGE) ----
  k_sage_mean<<<agrid, 256, 0, stream>>>((const unsigned int*)H16a, rowStart, srcList,
                                         (unsigned int*)HX);
  k_mgemm2<<<mgrid, 256, 0, stream>>>(HX, Wt16 + 6*16384, H16a, Wt16 + 7*16384,
                                      s4_bl, B1, N_NODES, bnsums + 768);
  k_bnapply<<<bgrid, 256, 0, stream>>>(B1, bnsums + 768, bn4_g, bn4_b, nullptr,
                                       nullptr, (unsigned int*)H16a);   // h4 -> H16a

  // ---- layer 5 (SAGE) ----
  k_sage_mean<<<agrid, 256, 0, stream>>>((const unsigned int*)H16a, rowStart, srcList,
                                         (unsigned int*)HX);
  k_mgemm2<<<mgrid, 256, 0, stream>>>(HX, Wt16 + 8*16384, H16a, Wt16 + 9*16384,
                                      s5_bl, B1, N_NODES, bnsums + 1024);
  k_bnapply<<<bgrid, 256, 0, stream>>>(B1, bnsums + 1024, bn5_g, bn5_b, nullptr,
                                       B3, nullptr);                    // h5 -> B3 (fp32)

  // ---- pool + fc ----
  hipMemsetAsync(pooled, 0, (GR*D + 64)*4, stream);
  k_pool<<<pgrid, 256, 0, stream>>>(B3, batch, pooled, cnt);
  k_fc<<<(GR*64 + 255)/256, 256, 0, stream>>>(pooled, cnt, fc_W, fc_b, out);
}

// Round 5
// 728.033 us; speedup vs baseline: 1.7707x; 1.0724x over previous
//
#include <hip/hip_runtime.h>
#include <math.h>
#include <stdint.h>

#define N_NODES 50000
#define N_EDGES 800000
#define D 128
#define GR 50
#define EPSV 1e-5f

typedef __attribute__((ext_vector_type(8))) short bf16x8;
typedef __attribute__((ext_vector_type(4))) float f32x4;

__device__ __forceinline__ float lrelu(float v){ return v > 0.f ? v : 0.2f*v; }

__device__ __forceinline__ unsigned int f2bf(float f){
  union { float f; uint32_t i; } v; v.f = f;
  uint32_t r = v.i + 0x7fffu + ((v.i >> 16) & 1u);
  return r >> 16;
}
__device__ __forceinline__ float2 bf2f2(uint32_t u){
  union { uint32_t i; float f; } a, b;
  a.i = u << 16;
  b.i = u & 0xffff0000u;
  return make_float2(a.f, b.f);
}

// ---------------- CSR build (one atomic pass) ----------------
__global__ void k_countrank(const int* __restrict__ dst, int* __restrict__ deg,
                            int* __restrict__ rank){
  int e = blockIdx.x*256 + threadIdx.x;
  if (e < N_EDGES) rank[e] = atomicAdd(&deg[dst[e]], 1);
}
__global__ void k_scan1(const int* __restrict__ deg, int* __restrict__ bsum){
  __shared__ int s[256];
  int i = blockIdx.x*256 + threadIdx.x;
  int v = (i < N_NODES) ? deg[i] : 0;
  s[threadIdx.x] = v; __syncthreads();
  for (int off = 128; off > 0; off >>= 1){
    if (threadIdx.x < off) s[threadIdx.x] += s[threadIdx.x + off];
    __syncthreads();
  }
  if (threadIdx.x == 0) bsum[blockIdx.x] = s[0];
}
// single-block parallel exclusive scan of block sums (nb <= 256)
__global__ void k_scan2b(int* __restrict__ bsum, int nb, int* __restrict__ rowStart){
  __shared__ int s[256];
  int t = threadIdx.x;
  int v = (t < nb) ? bsum[t] : 0;
  s[t] = v; __syncthreads();
  for (int off = 1; off < 256; off <<= 1){
    int xv = (t >= off) ? s[t - off] : 0;
    __syncthreads();
    s[t] += xv;
    __syncthreads();
  }
  if (t < nb) bsum[t] = s[t] - v;
  if (t == 255) rowStart[N_NODES] = s[255];
}
__global__ void k_scan3(const int* __restrict__ deg, const int* __restrict__ bsum,
                        int* __restrict__ rowStart){
  __shared__ int s[256];
  int i = blockIdx.x*256 + threadIdx.x;
  int v = (i < N_NODES) ? deg[i] : 0;
  s[threadIdx.x] = v; __syncthreads();
  for (int off = 1; off < 256; off <<= 1){
    int xv = (threadIdx.x >= off) ? s[threadIdx.x - off] : 0;
    __syncthreads();
    s[threadIdx.x] += xv;
    __syncthreads();
  }
  if (i < N_NODES) rowStart[i] = bsum[blockIdx.x] + s[threadIdx.x] - v;
}
// atomic-free scatter
__global__ void k_scatter(const int* __restrict__ src, const int* __restrict__ dst,
                          const int* __restrict__ rank, const int* __restrict__ rowStart,
                          int* __restrict__ srcList){
  int e = blockIdx.x*256 + threadIdx.x;
  if (e < N_EDGES)
    srcList[rowStart[dst[e]] + rank[e]] = src[e];
}

// ---------------- casts ----------------
__global__ void k_cast_x(const float* __restrict__ x, unsigned short* __restrict__ x16){
  int idx = blockIdx.x*256 + threadIdx.x;
  if (idx >= N_NODES*32) return;
  float4 v = *(const float4*)(x + (size_t)idx*4);
  uint2 pk;
  pk.x = f2bf(v.x) | (f2bf(v.y) << 16);
  pk.y = f2bf(v.z) | (f2bf(v.w) << 16);
  *(uint2*)(x16 + (size_t)idx*4) = pk;
}

struct WPack { const float* w[10]; };
__global__ void k_castw(WPack p, unsigned short* __restrict__ wt){
  int mat = blockIdx.x >> 6;
  int local = (blockIdx.x & 63)*256 + threadIdx.x;
  int c = local >> 7, k = local & 127;
  wt[(size_t)mat*16384 + c*128 + k] = (unsigned short)f2bf(p.w[mat][k*128 + c]);
}

// ======================= MFMA GEMM family =======================
__device__ __forceinline__ void stage_w(const unsigned short* __restrict__ wt,
                                        unsigned short* __restrict__ lds, int t){
  #pragma unroll
  for (int i = 0; i < 8; ++i){
    int ch = i*256 + t;
    int col = ch >> 4, kc = ch & 15;
    *(uint4*)(&lds[col*136 + kc*8]) = *(const uint4*)(wt + ((size_t)col << 7) + (kc << 3));
  }
}

__device__ __forceinline__ void mfma_k128(const unsigned short* __restrict__ xrow,
                                          const unsigned short* __restrict__ lds,
                                          int lane, f32x4 acc[8]){
  int quad = lane >> 4, m = lane & 15;
  #pragma unroll
  for (int ks = 0; ks < 4; ++ks){
    bf16x8 a = *(const bf16x8*)(xrow + ks*32 + quad*8);
    #pragma unroll
    for (int nt = 0; nt < 8; ++nt){
      bf16x8 b = *(const bf16x8*)(&lds[(nt*16 + m)*136 + ks*32 + quad*8]);
      acc[nt] = __builtin_amdgcn_mfma_f32_16x16x32_bf16(a, b, acc[nt], 0, 0, 0);
    }
  }
}

__global__ __launch_bounds__(256) void k_mgemm(const unsigned short* __restrict__ X16,
    const unsigned short* __restrict__ wt, const float* __restrict__ bias,
    float* __restrict__ Y, int n){
  __shared__ __align__(16) unsigned short Wlds[128*136];
  int t = threadIdx.x, lane = t & 63, w = t >> 6;
  int quad = lane >> 4, m = lane & 15;
  int rbase = blockIdx.x*64 + w*16;
  stage_w(wt, Wlds, t);
  f32x4 acc[8];
  #pragma unroll
  for (int nt = 0; nt < 8; ++nt){ acc[nt][0]=0.f; acc[nt][1]=0.f; acc[nt][2]=0.f; acc[nt][3]=0.f; }
  int rowA = rbase + m; if (rowA >= n) rowA = n - 1;
  __syncthreads();
  mfma_k128(X16 + (size_t)rowA*128, Wlds, lane, acc);
  #pragma unroll
  for (int nt = 0; nt < 8; ++nt){
    int col = nt*16 + m;
    float bv = bias[col];
    #pragma unroll
    for (int reg = 0; reg < 4; ++reg){
      int row = rbase + quad*4 + reg;
      if (row < n) Y[(size_t)row*128 + col] = acc[nt][reg] + bv;
    }
  }
}

__global__ __launch_bounds__(256) void k_mgemm_gat(const unsigned short* __restrict__ X16,
    const unsigned short* __restrict__ wt, const float* __restrict__ as_,
    const float* __restrict__ ad_, unsigned short* __restrict__ H16,
    float* __restrict__ es, float* __restrict__ ed, int n){
  __shared__ __align__(16) unsigned short Wlds[128*136];
  int t = threadIdx.x, lane = t & 63, w = t >> 6;
  int quad = lane >> 4, m = lane & 15;
  int rbase = blockIdx.x*64 + w*16;
  stage_w(wt, Wlds, t);
  f32x4 acc[8];
  #pragma unroll
  for (int nt = 0; nt < 8; ++nt){ acc[nt][0]=0.f; acc[nt][1]=0.f; acc[nt][2]=0.f; acc[nt][3]=0.f; }
  int rowA = rbase + m; if (rowA >= n) rowA = n - 1;
  __syncthreads();
  mfma_k128(X16 + (size_t)rowA*128, Wlds, lane, acc);

  float asv[8], adv[8];
  #pragma unroll
  for (int nt = 0; nt < 8; ++nt){ asv[nt] = as_[nt*16 + m]; adv[nt] = ad_[nt*16 + m]; }

  #pragma unroll
  for (int reg = 0; reg < 4; ++reg){
    int row = rbase + quad*4 + reg;
    float pe[4], pd[4];
    #pragma unroll
    for (int h = 0; h < 4; ++h){
      pe[h] = acc[2*h][reg]*asv[2*h] + acc[2*h+1][reg]*asv[2*h+1];
      pd[h] = acc[2*h][reg]*adv[2*h] + acc[2*h+1][reg]*adv[2*h+1];
    }
    #pragma unroll
    for (int h = 0; h < 4; ++h){
      pe[h] += __shfl_xor(pe[h], 1); pe[h] += __shfl_xor(pe[h], 2);
      pe[h] += __shfl_xor(pe[h], 4); pe[h] += __shfl_xor(pe[h], 8);
      pd[h] += __shfl_xor(pd[h], 1); pd[h] += __shfl_xor(pd[h], 2);
      pd[h] += __shfl_xor(pd[h], 4); pd[h] += __shfl_xor(pd[h], 8);
    }
    if (m == 0 && row < n){
      #pragma unroll
      for (int h = 0; h < 4; ++h){ es[row*4 + h] = pe[h]; ed[row*4 + h] = pd[h]; }
    }
  }
  #pragma unroll
  for (int nt = 0; nt < 8; ++nt){
    int col = nt*16 + m;
    #pragma unroll
    for (int reg = 0; reg < 4; ++reg){
      int row = rbase + quad*4 + reg;
      if (row < n) H16[(size_t)row*128 + col] = (unsigned short)f2bf(acc[nt][reg]);
    }
  }
}

__global__ __launch_bounds__(256) void k_mgemm2(const unsigned short* __restrict__ Xa,
    const unsigned short* __restrict__ wta, const unsigned short* __restrict__ Xb,
    const unsigned short* __restrict__ wtb, const float* __restrict__ bias,
    float* __restrict__ Y, int n, float* __restrict__ bnsum){
  __shared__ __align__(16) unsigned short Wlds[128*136];
  __shared__ float redS[128], redQ[128];
  int t = threadIdx.x, lane = t & 63, w = t >> 6;
  int quad = lane >> 4, m = lane & 15;
  int rbase = blockIdx.x*64 + w*16;
  if (t < 128){ redS[t] = 0.f; redQ[t] = 0.f; }
  f32x4 acc[8];
  #pragma unroll
  for (int nt = 0; nt < 8; ++nt){ acc[nt][0]=0.f; acc[nt][1]=0.f; acc[nt][2]=0.f; acc[nt][3]=0.f; }
  int rowA = rbase + m; if (rowA >= n) rowA = n - 1;

  stage_w(wta, Wlds, t);
  __syncthreads();
  mfma_k128(Xa + (size_t)rowA*128, Wlds, lane, acc);
  __syncthreads();
  stage_w(wtb, Wlds, t);
  __syncthreads();
  mfma_k128(Xb + (size_t)rowA*128, Wlds, lane, acc);

  #pragma unroll
  for (int nt = 0; nt < 8; ++nt){
    int col = nt*16 + m;
    float bv = bias[col];
    float s = 0.f, q = 0.f;
    #pragma unroll
    for (int reg = 0; reg < 4; ++reg){
      int row = rbase + quad*4 + reg;
      if (row < n){
        float o = acc[nt][reg] + bv;
        Y[(size_t)row*128 + col] = o;
        s += o; q += o*o;
      }
    }
    atomicAdd(&redS[col], s);
    atomicAdd(&redQ[col], q);
  }
  __syncthreads();
  if (t < 128){
    atomicAdd(&bnsum[t],       redS[t]);
    atomicAdd(&bnsum[128 + t], redQ[t]);
  }
}

// --------- GAT aggregation: wave/node, bf16 gathers, unroll 8 ----------
__global__ __launch_bounds__(256) void k_gat(const unsigned int* __restrict__ h16,
    const float* __restrict__ es, const float* __restrict__ edv,
    const int* __restrict__ rowStart, const int* __restrict__ srcList,
    const float* __restrict__ bias, float* __restrict__ out){
  int i = blockIdx.x*4 + (threadIdx.x >> 6);
  if (i >= N_NODES) return;
  int lane = threadIdx.x & 63;
  int hd = lane >> 4;
  int c  = lane * 2;
  float edi = edv[i*4 + hd];
  float2 self = bf2f2(h16[(size_t)i*64 + lane]);
  float w = __expf(lrelu(es[i*4 + hd] + edi));
  float z = w, acc0 = self.x*w, acc1 = self.y*w;
  int k0 = rowStart[i], ke = rowStart[i + 1];
  int k = k0;
  for (; k + 7 < ke; k += 8){
    int s[8]; uint32_t u[8]; float ev[8];
    #pragma unroll
    for (int j = 0; j < 8; ++j) s[j] = srcList[k + j];
    #pragma unroll
    for (int j = 0; j < 8; ++j) u[j] = h16[(size_t)s[j]*64 + lane];
    #pragma unroll
    for (int j = 0; j < 8; ++j) ev[j] = es[s[j]*4 + hd];
    #pragma unroll
    for (int j = 0; j < 8; ++j){
      float wj = __expf(lrelu(ev[j] + edi));
      float2 v = bf2f2(u[j]);
      z += wj; acc0 += v.x*wj; acc1 += v.y*wj;
    }
  }
  for (; k < ke; ++k){
    int s0 = srcList[k];
    uint32_t u0 = h16[(size_t)s0*64 + lane];
    float w0 = __expf(lrelu(es[s0*4 + hd] + edi));
    float2 v0 = bf2f2(u0);
    z += w0; acc0 += v0.x*w0; acc1 += v0.y*w0;
  }
  float inv = 1.f / z;
  float2 bv = *(const float2*)(bias + c);
  *(float2*)(out + (size_t)i*D + c) = make_float2(acc0*inv + bv.x, acc1*inv + bv.y);
}

// ---------------- SAGE mean aggregation: bf16 in/out, unroll 8 --------------
__global__ __launch_bounds__(256) void k_sage_mean(const unsigned int* __restrict__ h16,
    const int* __restrict__ rowStart, const int* __restrict__ srcList,
    unsigned int* __restrict__ out16){
  int i = blockIdx.x*4 + (threadIdx.x >> 6);
  if (i >= N_NODES) return;
  int lane = threadIdx.x & 63;
  int k0 = rowStart[i], k1 = rowStart[i + 1];
  float a0 = 0.f, a1 = 0.f;
  int k = k0;
  for (; k + 7 < k1; k += 8){
    int s[8]; uint32_t u[8];
    #pragma unroll
    for (int j = 0; j < 8; ++j) s[j] = srcList[k + j];
    #pragma unroll
    for (int j = 0; j < 8; ++j) u[j] = h16[(size_t)s[j]*64 + lane];
    #pragma unroll
    for (int j = 0; j < 8; ++j){
      float2 v = bf2f2(u[j]);
      a0 += v.x; a1 += v.y;
    }
  }
  for (; k < k1; ++k){
    uint32_t u0 = h16[(size_t)srcList[k]*64 + lane];
    float2 v0 = bf2f2(u0);
    a0 += v0.x; a1 += v0.y;
  }
  int dg = k1 - k0;
  float inv = 1.f / (float)(dg > 0 ? dg : 1);
  out16[(size_t)i*64 + lane] = f2bf(a0*inv) | (f2bf(a1*inv) << 16);
}

// ---------------- BatchNorm stats ----------------
__global__ __launch_bounds__(256) void k_bnstat(const float* __restrict__ x,
                                                float* __restrict__ sums){
  int col = threadIdx.x & 127;
  int ro  = threadIdx.x >> 7;
  float s = 0.f, s2 = 0.f;
  for (int r = blockIdx.x*2 + ro; r < N_NODES; r += gridDim.x*2){
    float v = x[(size_t)r*D + col];
    s += v; s2 += v*v;
  }
  __shared__ float rs[256], rq[256];
  rs[threadIdx.x] = s; rq[threadIdx.x] = s2;
  __syncthreads();
  if (threadIdx.x < 128){
    atomicAdd(&sums[col],       rs[threadIdx.x] + rs[threadIdx.x + 128]);
    atomicAdd(&sums[128 + col], rq[threadIdx.x] + rq[threadIdx.x + 128]);
  }
}

// --------- BN apply (+opt residual) + lrelu; optional fp32 / bf16 outputs ---
__global__ void k_bnapply(const float* __restrict__ x, const float* __restrict__ sums,
    const float* __restrict__ g, const float* __restrict__ b,
    const float* __restrict__ res, float* __restrict__ y,
    unsigned int* __restrict__ y16){
  int f = blockIdx.x*256 + threadIdx.x;
  if (f >= N_NODES*32) return;
  int c = (f & 31) * 4;
  float4 v = *(const float4*)(x + (size_t)f*4);
  float vv[4] = {v.x, v.y, v.z, v.w};
  float rr[4] = {0.f, 0.f, 0.f, 0.f};
  if (res){
    float4 rv = *(const float4*)(res + (size_t)f*4);
    rr[0]=rv.x; rr[1]=rv.y; rr[2]=rv.z; rr[3]=rv.w;
  }
  float o[4];
  const float invn = 1.f / (float)N_NODES;
  #pragma unroll
  for (int j = 0; j < 4; ++j){
    int cc = c + j;
    float mu  = sums[cc] * invn;
    float var = sums[128 + cc] * invn - mu*mu;
    float rs  = rsqrtf(var + EPSV);
    o[j] = lrelu((vv[j] - mu)*rs*g[cc] + b[cc] + rr[j]);
  }
  if (y) *(float4*)(y + (size_t)f*4) = make_float4(o[0], o[1], o[2], o[3]);
  if (y16){
    uint2 pk;
    pk.x = f2bf(o[0]) | (f2bf(o[1]) << 16);
    pk.y = f2bf(o[2]) | (f2bf(o[3]) << 16);
    *(uint2*)(y16 + (size_t)f*2) = pk;
  }
}

// ---------------- global mean pool ----------------
__global__ __launch_bounds__(256) void k_pool(const float* __restrict__ h,
    const int* __restrict__ batch, float* __restrict__ pooled,
    float* __restrict__ cnt){
  int col = threadIdx.x & 127;
  int ro  = threadIdx.x >> 7;
  int base = blockIdx.x * 128;
  int g_cur = -1; float acc = 0.f, cacc = 0.f;
  for (int ii = 0; ii < 64; ++ii){
    int r = base + ro + ii*2;
    if (r >= N_NODES) break;
    int g = batch[r];
    if (g != g_cur){
      if (g_cur >= 0){
        atomicAdd(&pooled[g_cur*D + col], acc);
        if (col == 0) atomicAdd(&cnt[g_cur], cacc);
      }
      acc = 0.f; cacc = 0.f; g_cur = g;
    }
    acc  += h[(size_t)r*D + col];
    cacc += 1.f;
  }
  if (g_cur >= 0){
    atomicAdd(&pooled[g_cur*D + col], acc);
    if (col == 0) atomicAdd(&cnt[g_cur], cacc);
  }
}

// ---------------- final FC ----------------
__global__ void k_fc(const float* __restrict__ pooled, const float* __restrict__ cnt,
    const float* __restrict__ W, const float* __restrict__ b, float* __restrict__ out){
  int idx = blockIdx.x*256 + threadIdx.x;
  if (idx >= GR*64) return;
  int g = idx >> 6, o = idx & 63;
  const float* p = pooled + g*D;
  float s = 0.f;
  for (int c2 = 0; c2 < D; ++c2) s += p[c2] * W[c2*64 + o];
  float inv = 1.f / fmaxf(cnt[g], 1.f);
  out[idx] = s*inv + b[o];
}

extern "C" void kernel_launch(void* const* d_in, const int* in_sizes, int n_in,
                              void* d_out, int out_size, void* d_ws, size_t ws_size,
                              hipStream_t stream){
  (void)in_sizes; (void)n_in; (void)out_size; (void)ws_size;
  const float* x       = (const float*)d_in[0];
  const int*   ei      = (const int*)  d_in[1];
  const int*   batch   = (const int*)  d_in[2];
  const float* gat1_W  = (const float*)d_in[3];
  const float* gat1_as = (const float*)d_in[4];
  const float* gat1_ad = (const float*)d_in[5];
  const float* gat1_b  = (const float*)d_in[6];
  const float* gat2_W  = (const float*)d_in[7];
  const float* gat2_as = (const float*)d_in[8];
  const float* gat2_ad = (const float*)d_in[9];
  const float* gat2_b  = (const float*)d_in[10];
  const float* s3_Wl   = (const float*)d_in[11];
  const float* s3_bl   = (const float*)d_in[12];
  const float* s3_Wr   = (const float*)d_in[13];
  const float* s4_Wl   = (const float*)d_in[14];
  const float* s4_bl   = (const float*)d_in[15];
  const float* s4_Wr   = (const float*)d_in[16];
  const float* s5_Wl   = (const float*)d_in[17];
  const float* s5_bl   = (const float*)d_in[18];
  const float* s5_Wr   = (const float*)d_in[19];
  const float* bn1_g = (const float*)d_in[20]; const float* bn1_b = (const float*)d_in[21];
  const float* bn2_g = (const float*)d_in[22]; const float* bn2_b = (const float*)d_in[23];
  const float* bn3_g = (const float*)d_in[24]; const float* bn3_b = (const float*)d_in[25];
  const float* bn4_g = (const float*)d_in[26]; const float* bn4_b = (const float*)d_in[27];
  const float* bn5_g = (const float*)d_in[28]; const float* bn5_b = (const float*)d_in[29];
  const float* res1_W = (const float*)d_in[30]; const float* res1_b = (const float*)d_in[31];
  const float* res2_W = (const float*)d_in[32]; const float* res2_b = (const float*)d_in[33];
  const float* fc_W   = (const float*)d_in[34]; const float* fc_b   = (const float*)d_in[35];
  float* out = (float*)d_out;

  char* ws = (char*)d_ws;
  size_t off = 0;
  auto alloc = [&](size_t bytes) -> void* {
    void* p = ws + off; off += (bytes + 255) & ~(size_t)255; return p;
  };
  int*   rowStart = (int*)  alloc((N_NODES + 1) * 4);
  int*   deg      = (int*)  alloc((size_t)N_NODES * 4);
  int*   rank     = (int*)  alloc((size_t)N_EDGES * 4);
  int*   srcList  = (int*)  alloc((size_t)N_EDGES * 4);
  int*   bsum     = (int*)  alloc(256 * 4);
  // bnsums | pooled | cnt are contiguous -> single memset
  float* bnsums   = (float*)alloc(5 * 256 * 4);
  float* pooled   = (float*)alloc(GR * D * 4);
  float* cnt      = (float*)alloc(64 * 4);
  float* es       = (float*)alloc((size_t)N_NODES * 4 * 4);
  float* edv      = (float*)alloc((size_t)N_NODES * 4 * 4);
  unsigned short* Wt16 = (unsigned short*)alloc(10 * 16384 * 2);
  unsigned short* HX   = (unsigned short*)alloc((size_t)N_NODES * D * 2);
  unsigned short* H16a = (unsigned short*)alloc((size_t)N_NODES * D * 2);
  float* B1 = (float*)alloc((size_t)N_NODES * D * 4);
  float* B3 = (float*)alloc((size_t)N_NODES * D * 4);

  const int* srcE = ei;
  const int* dstE = ei + N_EDGES;
  const int nb = (N_NODES + 255) / 256;
  const int egrid = (N_EDGES + 255) / 256;
  const int mgrid = (N_NODES + 63) / 64;
  const int agrid = (N_NODES + 3) / 4;
  const int bgrid = (N_NODES*32 + 255) / 256;
  const int pgrid = (N_NODES + 127) / 128;

  // CSR build: one atomic pass + atomic-free scatter
  hipMemsetAsync(deg, 0, (size_t)N_NODES*4, stream);
  hipMemsetAsync(bnsums, 0, (5*256 + GR*D + 64)*4, stream);
  k_countrank<<<egrid, 256, 0, stream>>>(dstE, deg, rank);
  k_scan1<<<nb, 256, 0, stream>>>(deg, bsum);
  k_scan2b<<<1, 256, 0, stream>>>(bsum, nb, rowStart);
  k_scan3<<<nb, 256, 0, stream>>>(deg, bsum, rowStart);
  k_scatter<<<egrid, 256, 0, stream>>>(srcE, dstE, rank, rowStart, srcList);

  // weight + input casts
  WPack wp;
  wp.w[0]=res1_W; wp.w[1]=gat1_W; wp.w[2]=res2_W; wp.w[3]=gat2_W;
  wp.w[4]=s3_Wl;  wp.w[5]=s3_Wr;  wp.w[6]=s4_Wl;  wp.w[7]=s4_Wr;
  wp.w[8]=s5_Wl;  wp.w[9]=s5_Wr;
  k_castw<<<640, 256, 0, stream>>>(wp, Wt16);
  k_cast_x<<<bgrid, 256, 0, stream>>>(x, HX);

  // ---- layer 1 (GAT) ----
  k_mgemm<<<mgrid, 256, 0, stream>>>(HX, Wt16 + 0*16384, res1_b, B1, N_NODES);
  k_mgemm_gat<<<mgrid, 256, 0, stream>>>(HX, Wt16 + 1*16384, gat1_as, gat1_ad,
                                         H16a, es, edv, N_NODES);
  k_gat<<<agrid, 256, 0, stream>>>((const unsigned int*)H16a, es, edv, rowStart, srcList, gat1_b, B3);
  k_bnstat<<<256, 256, 0, stream>>>(B3, bnsums);
  k_bnapply<<<bgrid, 256, 0, stream>>>(B3, bnsums, bn1_g, bn1_b, B1,
                                       nullptr, (unsigned int*)H16a);

  // ---- layer 2 (GAT) ----
  k_mgemm<<<mgrid, 256, 0, stream>>>(H16a, Wt16 + 2*16384, res2_b, B1, N_NODES);
  k_mgemm_gat<<<mgrid, 256, 0, stream>>>(H16a, Wt16 + 3*16384, gat2_as, gat2_ad,
                                         HX, es, edv, N_NODES);
  k_gat<<<agrid, 256, 0, stream>>>((const unsigned int*)HX, es, edv, rowStart, srcList, gat2_b, B3);
  k_bnstat<<<256, 256, 0, stream>>>(B3, bnsums + 256);
  k_bnapply<<<bgrid, 256, 0, stream>>>(B3, bnsums + 256, bn2_g, bn2_b, B1,
                                       nullptr, (unsigned int*)H16a);

  // ---- layer 3 (SAGE) ----
  k_sage_mean<<<agrid, 256, 0, stream>>>((const unsigned int*)H16a, rowStart, srcList,
                                         (unsigned int*)HX);
  k_mgemm2<<<mgrid, 256, 0, stream>>>(HX, Wt16 + 4*16384, H16a, Wt16 + 5*16384,
                                      s3_bl, B1, N_NODES, bnsums + 512);
  k_bnapply<<<bgrid, 256, 0, stream>>>(B1, bnsums + 512, bn3_g, bn3_b, nullptr,
                                       nullptr, (unsigned int*)H16a);

  // ---- layer 4 (SAGE) ----
  k_sage_mean<<<agrid, 256, 0, stream>>>((const unsigned int*)H16a, rowStart, srcList,
                                         (unsigned int*)HX);
  k_mgemm2<<<mgrid, 256, 0, stream>>>(HX, Wt16 + 6*16384, H16a, Wt16 + 7*16384,
                                      s4_bl, B1, N_NODES, bnsums + 768);
  k_bnapply<<<bgrid, 256, 0, stream>>>(B1, bnsums + 768, bn4_g, bn4_b, nullptr,
                                       nullptr, (unsigned int*)H16a);

  // ---- layer 5 (SAGE) ----
  k_sage_mean<<<agrid, 256, 0, stream>>>((const unsigned int*)H16a, rowStart, srcList,
                                         (unsigned int*)HX);
  k_mgemm2<<<mgrid, 256, 0, stream>>>(HX, Wt16 + 8*16384, H16a, Wt16 + 9*16384,
                                      s5_bl, B1, N_NODES, bnsums + 1024);
  k_bnapply<<<bgrid, 256, 0, stream>>>(B1, bnsums + 1024, bn5_g, bn5_b, nullptr,
                                       B3, nullptr);

  // ---- pool + fc ----
  k_pool<<<pgrid, 256, 0, stream>>>(B3, batch, pooled, cnt);
  k_fc<<<(GR*64 + 255)/256, 256, 0, stream>>>(pooled, cnt, fc_W, fc_b, out);
}

// Round 6
// 653.506 us; speedup vs baseline: 1.9726x; 1.1140x over previous
//
#include <hip/hip_runtime.h>
#include <math.h>
#include <stdint.h>

#define N_NODES 50000
#define N_EDGES 800000
#define D 128
#define GR 50
#define EPSV 1e-5f

typedef __attribute__((ext_vector_type(8))) short bf16x8;
typedef __attribute__((ext_vector_type(4))) float f32x4;

__device__ __forceinline__ float lrelu(float v){ return v > 0.f ? v : 0.2f*v; }

__device__ __forceinline__ unsigned int f2bf(float f){
  union { float f; uint32_t i; } v; v.f = f;
  uint32_t r = v.i + 0x7fffu + ((v.i >> 16) & 1u);
  return r >> 16;
}
__device__ __forceinline__ float2 bf2f2(uint32_t u){
  union { uint32_t i; float f; } a, b;
  a.i = u << 16;
  b.i = u & 0xffff0000u;
  return make_float2(a.f, b.f);
}

// ---------------- CSR build (one atomic pass) ----------------
__global__ void k_countrank(const int* __restrict__ dst, int* __restrict__ deg,
                            int* __restrict__ rank){
  int e = blockIdx.x*256 + threadIdx.x;
  if (e < N_EDGES) rank[e] = atomicAdd(&deg[dst[e]], 1);
}
__global__ void k_scan1(const int* __restrict__ deg, int* __restrict__ bsum){
  __shared__ int s[256];
  int i = blockIdx.x*256 + threadIdx.x;
  int v = (i < N_NODES) ? deg[i] : 0;
  s[threadIdx.x] = v; __syncthreads();
  for (int off = 128; off > 0; off >>= 1){
    if (threadIdx.x < off) s[threadIdx.x] += s[threadIdx.x + off];
    __syncthreads();
  }
  if (threadIdx.x == 0) bsum[blockIdx.x] = s[0];
}
__global__ void k_scan2b(int* __restrict__ bsum, int nb, int* __restrict__ rowStart){
  __shared__ int s[256];
  int t = threadIdx.x;
  int v = (t < nb) ? bsum[t] : 0;
  s[t] = v; __syncthreads();
  for (int off = 1; off < 256; off <<= 1){
    int xv = (t >= off) ? s[t - off] : 0;
    __syncthreads();
    s[t] += xv;
    __syncthreads();
  }
  if (t < nb) bsum[t] = s[t] - v;
  if (t == 255) rowStart[N_NODES] = s[255];
}
__global__ void k_scan3(const int* __restrict__ deg, const int* __restrict__ bsum,
                        int* __restrict__ rowStart){
  __shared__ int s[256];
  int i = blockIdx.x*256 + threadIdx.x;
  int v = (i < N_NODES) ? deg[i] : 0;
  s[threadIdx.x] = v; __syncthreads();
  for (int off = 1; off < 256; off <<= 1){
    int xv = (threadIdx.x >= off) ? s[threadIdx.x - off] : 0;
    __syncthreads();
    s[threadIdx.x] += xv;
    __syncthreads();
  }
  if (i < N_NODES) rowStart[i] = bsum[blockIdx.x] + s[threadIdx.x] - v;
}
__global__ void k_scatter(const int* __restrict__ src, const int* __restrict__ dst,
                          const int* __restrict__ rank, const int* __restrict__ rowStart,
                          int* __restrict__ srcList){
  int e = blockIdx.x*256 + threadIdx.x;
  if (e < N_EDGES)
    srcList[rowStart[dst[e]] + rank[e]] = src[e];
}

// ---------------- casts ----------------
__global__ void k_cast_x(const float* __restrict__ x, unsigned short* __restrict__ x16){
  int idx = blockIdx.x*256 + threadIdx.x;
  if (idx >= N_NODES*32) return;
  float4 v = *(const float4*)(x + (size_t)idx*4);
  uint2 pk;
  pk.x = f2bf(v.x) | (f2bf(v.y) << 16);
  pk.y = f2bf(v.z) | (f2bf(v.w) << 16);
  *(uint2*)(x16 + (size_t)idx*4) = pk;
}

struct WPack { const float* w[10]; };
__global__ void k_castw(WPack p, unsigned short* __restrict__ wt){
  int mat = blockIdx.x >> 6;
  int local = (blockIdx.x & 63)*256 + threadIdx.x;
  int c = local >> 7, k = local & 127;
  wt[(size_t)mat*16384 + c*128 + k] = (unsigned short)f2bf(p.w[mat][k*128 + c]);
}

// ======================= MFMA GEMM family =======================
// 256 thr = 4 waves; block tile 64 rows; wave = 16 rows x 128 cols.
// W col-major bf16 staged in LDS (stride 136 shorts). A prefetched to regs.
// Epilogue: per-wave in-LDS transpose (stride 132) -> coalesced uint4 stores.

__device__ __forceinline__ void stage_w(const unsigned short* __restrict__ wt,
                                        unsigned short* __restrict__ lds, int t){
  #pragma unroll
  for (int i = 0; i < 8; ++i){
    int ch = i*256 + t;
    int col = ch >> 4, kc = ch & 15;
    *(uint4*)(&lds[col*136 + kc*8]) = *(const uint4*)(wt + ((size_t)col << 7) + (kc << 3));
  }
}

__device__ __forceinline__ void load_a(const unsigned short* __restrict__ xrow,
                                       int quad, bf16x8 a[4]){
  #pragma unroll
  for (int ks = 0; ks < 4; ++ks)
    a[ks] = *(const bf16x8*)(xrow + ks*32 + quad*8);
}

__device__ __forceinline__ void mfma_regs(const bf16x8 a[4],
                                          const unsigned short* __restrict__ lds,
                                          int lane, f32x4 acc[8]){
  int quad = lane >> 4, m = lane & 15;
  #pragma unroll
  for (int ks = 0; ks < 4; ++ks){
    #pragma unroll
    for (int nt = 0; nt < 8; ++nt){
      bf16x8 b = *(const bf16x8*)(&lds[(nt*16 + m)*136 + ks*32 + quad*8]);
      acc[nt] = __builtin_amdgcn_mfma_f32_16x16x32_bf16(a[ks], b, acc[nt], 0, 0, 0);
    }
  }
}

// write acc (+bias) as bf16 via per-wave LDS transpose, coalesced store
__device__ __forceinline__ void epi_store16(f32x4 acc[8], const float* bias,
    unsigned short* __restrict__ ldsw, unsigned short* __restrict__ Y16,
    int rbase, int lane, int n){
  int quad = lane >> 4, m = lane & 15;
  #pragma unroll
  for (int nt = 0; nt < 8; ++nt){
    int col = nt*16 + m;
    float bv = bias ? bias[col] : 0.f;
    #pragma unroll
    for (int reg = 0; reg < 4; ++reg)
      ldsw[(quad*4 + reg)*132 + col] = (unsigned short)f2bf(acc[nt][reg] + bv);
  }
  int r = lane >> 2, seg = lane & 3;
  int grow = rbase + r;
  if (grow < n){
    unsigned short* gp = Y16 + (size_t)grow*128 + seg*32;
    #pragma unroll
    for (int j = 0; j < 4; ++j)
      *(uint4*)(gp + j*8) = *(const uint4*)(&ldsw[r*132 + seg*32 + j*8]);
  }
}

// ---- residual GEMM: R16 = bf16(X16 @ W + bias) ----
__global__ __launch_bounds__(256) void k_mgemm(const unsigned short* __restrict__ X16,
    const unsigned short* __restrict__ wt, const float* __restrict__ bias,
    unsigned short* __restrict__ Y16, int n){
  __shared__ __align__(16) unsigned short Wlds[128*136];
  int t = threadIdx.x, lane = t & 63, w = t >> 6;
  int quad = lane >> 4, m = lane & 15;
  int rbase = blockIdx.x*64 + w*16;
  int rowA = rbase + m; if (rowA >= n) rowA = n - 1;
  bf16x8 a[4];
  load_a(X16 + (size_t)rowA*128, quad, a);
  stage_w(wt, Wlds, t);
  f32x4 acc[8];
  #pragma unroll
  for (int nt = 0; nt < 8; ++nt){ acc[nt][0]=0.f; acc[nt][1]=0.f; acc[nt][2]=0.f; acc[nt][3]=0.f; }
  __syncthreads();
  mfma_regs(a, Wlds, lane, acc);
  __syncthreads();          // all waves done reading Wlds -> reuse for transpose
  epi_store16(acc, bias, Wlds + w*2112, Y16, rbase, lane, n);
}

// ---- GAT GEMM: H16 = bf16(X16 @ W), fused es/ed ----
__global__ __launch_bounds__(256) void k_mgemm_gat(const unsigned short* __restrict__ X16,
    const unsigned short* __restrict__ wt, const float* __restrict__ as_,
    const float* __restrict__ ad_, unsigned short* __restrict__ H16,
    float* __restrict__ es, float* __restrict__ ed, int n){
  __shared__ __align__(16) unsigned short Wlds[128*136];
  int t = threadIdx.x, lane = t & 63, w = t >> 6;
  int quad = lane >> 4, m = lane & 15;
  int rbase = blockIdx.x*64 + w*16;
  int rowA = rbase + m; if (rowA >= n) rowA = n - 1;
  bf16x8 a[4];
  load_a(X16 + (size_t)rowA*128, quad, a);
  stage_w(wt, Wlds, t);
  f32x4 acc[8];
  #pragma unroll
  for (int nt = 0; nt < 8; ++nt){ acc[nt][0]=0.f; acc[nt][1]=0.f; acc[nt][2]=0.f; acc[nt][3]=0.f; }
  __syncthreads();
  mfma_regs(a, Wlds, lane, acc);

  float asv[8], adv[8];
  #pragma unroll
  for (int nt = 0; nt < 8; ++nt){ asv[nt] = as_[nt*16 + m]; adv[nt] = ad_[nt*16 + m]; }
  #pragma unroll
  for (int reg = 0; reg < 4; ++reg){
    int row = rbase + quad*4 + reg;
    float pe[4], pd[4];
    #pragma unroll
    for (int h = 0; h < 4; ++h){
      pe[h] = acc[2*h][reg]*asv[2*h] + acc[2*h+1][reg]*asv[2*h+1];
      pd[h] = acc[2*h][reg]*adv[2*h] + acc[2*h+1][reg]*adv[2*h+1];
    }
    #pragma unroll
    for (int h = 0; h < 4; ++h){
      pe[h] += __shfl_xor(pe[h], 1); pe[h] += __shfl_xor(pe[h], 2);
      pe[h] += __shfl_xor(pe[h], 4); pe[h] += __shfl_xor(pe[h], 8);
      pd[h] += __shfl_xor(pd[h], 1); pd[h] += __shfl_xor(pd[h], 2);
      pd[h] += __shfl_xor(pd[h], 4); pd[h] += __shfl_xor(pd[h], 8);
    }
    if (m == 0 && row < n){
      #pragma unroll
      for (int h = 0; h < 4; ++h){ es[row*4 + h] = pe[h]; ed[row*4 + h] = pd[h]; }
    }
  }
  __syncthreads();
  epi_store16(acc, nullptr, Wlds + w*2112, H16, rbase, lane, n);
}

// ---- SAGE dual GEMM: Y16 = bf16(Xa@Wa + bias + Xb@Wb), BN partials ----
__global__ __launch_bounds__(256) void k_mgemm2(const unsigned short* __restrict__ Xa,
    const unsigned short* __restrict__ wta, const unsigned short* __restrict__ Xb,
    const unsigned short* __restrict__ wtb, const float* __restrict__ bias,
    unsigned short* __restrict__ Y16, int n, float* __restrict__ bnpart){
  __shared__ __align__(16) unsigned short Wlds[128*136];
  __shared__ float wredS[4][128], wredQ[4][128];
  int t = threadIdx.x, lane = t & 63, w = t >> 6;
  int quad = lane >> 4, m = lane & 15;
  int rbase = blockIdx.x*64 + w*16;
  int rowA = rbase + m; if (rowA >= n) rowA = n - 1;
  bf16x8 aa[4], ab[4];
  load_a(Xa + (size_t)rowA*128, quad, aa);
  load_a(Xb + (size_t)rowA*128, quad, ab);
  stage_w(wta, Wlds, t);
  f32x4 acc[8];
  #pragma unroll
  for (int nt = 0; nt < 8; ++nt){ acc[nt][0]=0.f; acc[nt][1]=0.f; acc[nt][2]=0.f; acc[nt][3]=0.f; }
  __syncthreads();
  mfma_regs(aa, Wlds, lane, acc);
  __syncthreads();
  stage_w(wtb, Wlds, t);
  __syncthreads();
  mfma_regs(ab, Wlds, lane, acc);

  // bias + column stats (quad-shfl reduce, no atomics)
  float colS[8], colQ[8];
  #pragma unroll
  for (int nt = 0; nt < 8; ++nt){
    float bv = bias[nt*16 + m];
    float s = 0.f, q = 0.f;
    #pragma unroll
    for (int reg = 0; reg < 4; ++reg){
      float o = acc[nt][reg] + bv;
      acc[nt][reg] = o;
      if (rbase + quad*4 + reg < n){ s += o; q += o*o; }
    }
    s += __shfl_xor(s, 16); s += __shfl_xor(s, 32);
    q += __shfl_xor(q, 16); q += __shfl_xor(q, 32);
    colS[nt] = s; colQ[nt] = q;
  }
  if (quad == 0){
    #pragma unroll
    for (int nt = 0; nt < 8; ++nt){
      wredS[w][nt*16 + m] = colS[nt];
      wredQ[w][nt*16 + m] = colQ[nt];
    }
  }
  __syncthreads();      // wred ready; Wlds free for transpose
  if (t < 128){
    float S = wredS[0][t] + wredS[1][t] + wredS[2][t] + wredS[3][t];
    float Q = wredQ[0][t] + wredQ[1][t] + wredQ[2][t] + wredQ[3][t];
    bnpart[(size_t)blockIdx.x*256 + t]       = S;
    bnpart[(size_t)blockIdx.x*256 + 128 + t] = Q;
  }
  epi_store16(acc, nullptr, Wlds + w*2112, Y16, rbase, lane, n);
}

// reduce per-block BN partials -> bnsum (64 atomics per address)
__global__ void k_bnred(const float* __restrict__ part, int nblk,
                        float* __restrict__ sums){
  int g = blockIdx.x, t = threadIdx.x;
  int chunk = (nblk + 63) / 64;
  int b0 = g*chunk, b1 = min(nblk, b0 + chunk);
  float s = 0.f;
  for (int b = b0; b < b1; ++b) s += part[(size_t)b*256 + t];
  if (b0 < b1) atomicAdd(&sums[t], s);
}

// --------- GAT aggregation: wave/node, bf16 gathers, bf16 out ----------
__global__ __launch_bounds__(256) void k_gat(const unsigned int* __restrict__ h16,
    const float* __restrict__ es, const float* __restrict__ edv,
    const int* __restrict__ rowStart, const int* __restrict__ srcList,
    const float* __restrict__ bias, unsigned int* __restrict__ out16){
  int i = blockIdx.x*4 + (threadIdx.x >> 6);
  if (i >= N_NODES) return;
  int lane = threadIdx.x & 63;
  int hd = lane >> 4;
  int c  = lane * 2;
  float edi = edv[i*4 + hd];
  float2 self = bf2f2(h16[(size_t)i*64 + lane]);
  float w = __expf(lrelu(es[i*4 + hd] + edi));
  float z = w, acc0 = self.x*w, acc1 = self.y*w;
  int k0 = rowStart[i], ke = rowStart[i + 1];
  int k = k0;
  for (; k + 7 < ke; k += 8){
    int s[8]; uint32_t u[8]; float ev[8];
    #pragma unroll
    for (int j = 0; j < 8; ++j) s[j] = srcList[k + j];
    #pragma unroll
    for (int j = 0; j < 8; ++j) u[j] = h16[(size_t)s[j]*64 + lane];
    #pragma unroll
    for (int j = 0; j < 8; ++j) ev[j] = es[s[j]*4 + hd];
    #pragma unroll
    for (int j = 0; j < 8; ++j){
      float wj = __expf(lrelu(ev[j] + edi));
      float2 v = bf2f2(u[j]);
      z += wj; acc0 += v.x*wj; acc1 += v.y*wj;
    }
  }
  for (; k < ke; ++k){
    int s0 = srcList[k];
    uint32_t u0 = h16[(size_t)s0*64 + lane];
    float w0 = __expf(lrelu(es[s0*4 + hd] + edi));
    float2 v0 = bf2f2(u0);
    z += w0; acc0 += v0.x*w0; acc1 += v0.y*w0;
  }
  float inv = 1.f / z;
  float2 bv = *(const float2*)(bias + c);
  out16[(size_t)i*64 + lane] = f2bf(acc0*inv + bv.x) | (f2bf(acc1*inv + bv.y) << 16);
}

// ---------------- SAGE mean aggregation ----------------
__global__ __launch_bounds__(256) void k_sage_mean(const unsigned int* __restrict__ h16,
    const int* __restrict__ rowStart, const int* __restrict__ srcList,
    unsigned int* __restrict__ out16){
  int i = blockIdx.x*4 + (threadIdx.x >> 6);
  if (i >= N_NODES) return;
  int lane = threadIdx.x & 63;
  int k0 = rowStart[i], k1 = rowStart[i + 1];
  float a0 = 0.f, a1 = 0.f;
  int k = k0;
  for (; k + 7 < k1; k += 8){
    int s[8]; uint32_t u[8];
    #pragma unroll
    for (int j = 0; j < 8; ++j) s[j] = srcList[k + j];
    #pragma unroll
    for (int j = 0; j < 8; ++j) u[j] = h16[(size_t)s[j]*64 + lane];
    #pragma unroll
    for (int j = 0; j < 8; ++j){
      float2 v = bf2f2(u[j]);
      a0 += v.x; a1 += v.y;
    }
  }
  for (; k < k1; ++k){
    float2 v0 = bf2f2(h16[(size_t)srcList[k]*64 + lane]);
    a0 += v0.x; a1 += v0.y;
  }
  int dg = k1 - k0;
  float inv = 1.f / (float)(dg > 0 ? dg : 1);
  out16[(size_t)i*64 + lane] = f2bf(a0*inv) | (f2bf(a1*inv) << 16);
}

// ---------------- BatchNorm stats from bf16 ----------------
__global__ __launch_bounds__(256) void k_bnstat(const unsigned int* __restrict__ x16,
                                                float* __restrict__ sums){
  int colu = threadIdx.x & 63;
  int ro   = threadIdx.x >> 6;
  float s0 = 0.f, s1 = 0.f, q0 = 0.f, q1 = 0.f;
  for (int r = blockIdx.x*4 + ro; r < N_NODES; r += gridDim.x*4){
    float2 v = bf2f2(x16[(size_t)r*64 + colu]);
    s0 += v.x; s1 += v.y; q0 += v.x*v.x; q1 += v.y*v.y;
  }
  __shared__ float rs0[256], rs1[256], rq0[256], rq1[256];
  int t = threadIdx.x;
  rs0[t] = s0; rs1[t] = s1; rq0[t] = q0; rq1[t] = q1;
  __syncthreads();
  if (t < 64){
    float S0 = rs0[t] + rs0[t+64] + rs0[t+128] + rs0[t+192];
    float S1 = rs1[t] + rs1[t+64] + rs1[t+128] + rs1[t+192];
    float Q0 = rq0[t] + rq0[t+64] + rq0[t+128] + rq0[t+192];
    float Q1 = rq1[t] + rq1[t+64] + rq1[t+128] + rq1[t+192];
    atomicAdd(&sums[2*t],       S0);
    atomicAdd(&sums[2*t + 1],   S1);
    atomicAdd(&sums[128 + 2*t],     Q0);
    atomicAdd(&sums[128 + 2*t + 1], Q1);
  }
}

// --------- BN apply (+opt bf16 residual) + lrelu; bf16 in/out ---------
__global__ void k_bnapply(const unsigned int* __restrict__ x16,
    const float* __restrict__ sums, const float* __restrict__ g,
    const float* __restrict__ b, const unsigned int* __restrict__ res16,
    unsigned int* __restrict__ y16){
  int f = blockIdx.x*256 + threadIdx.x;
  if (f >= N_NODES*32) return;
  int c = (f & 31) * 4;
  uint2 u = *(const uint2*)(x16 + (size_t)f*2);
  float2 vA = bf2f2(u.x), vB = bf2f2(u.y);
  float vv[4] = {vA.x, vA.y, vB.x, vB.y};
  float rr[4] = {0.f, 0.f, 0.f, 0.f};
  if (res16){
    uint2 ur = *(const uint2*)(res16 + (size_t)f*2);
    float2 rA = bf2f2(ur.x), rB = bf2f2(ur.y);
    rr[0]=rA.x; rr[1]=rA.y; rr[2]=rB.x; rr[3]=rB.y;
  }
  float o[4];
  const float invn = 1.f / (float)N_NODES;
  #pragma unroll
  for (int j = 0; j < 4; ++j){
    int cc = c + j;
    float mu  = sums[cc] * invn;
    float var = sums[128 + cc] * invn - mu*mu;
    float rs  = rsqrtf(var + EPSV);
    o[j] = lrelu((vv[j] - mu)*rs*g[cc] + b[cc] + rr[j]);
  }
  uint2 pk;
  pk.x = f2bf(o[0]) | (f2bf(o[1]) << 16);
  pk.y = f2bf(o[2]) | (f2bf(o[3]) << 16);
  *(uint2*)(y16 + (size_t)f*2) = pk;
}

// ---------------- global mean pool (bf16 input) ----------------
__global__ __launch_bounds__(256) void k_pool(const unsigned int* __restrict__ h16,
    const int* __restrict__ batch, float* __restrict__ pooled,
    float* __restrict__ cnt){
  int colu = threadIdx.x & 63;
  int ro   = threadIdx.x >> 6;
  int base = blockIdx.x * 128;
  int g_cur = -1; float a0 = 0.f, a1 = 0.f, cacc = 0.f;
  for (int ii = 0; ii < 32; ++ii){
    int r = base + ro + ii*4;
    if (r >= N_NODES) break;
    int g = batch[r];
    if (g != g_cur){
      if (g_cur >= 0){
        atomicAdd(&pooled[g_cur*D + 2*colu],     a0);
        atomicAdd(&pooled[g_cur*D + 2*colu + 1], a1);
        if (colu == 0) atomicAdd(&cnt[g_cur], cacc);
      }
      a0 = 0.f; a1 = 0.f; cacc = 0.f; g_cur = g;
    }
    float2 v = bf2f2(h16[(size_t)r*64 + colu]);
    a0 += v.x; a1 += v.y; cacc += 1.f;
  }
  if (g_cur >= 0){
    atomicAdd(&pooled[g_cur*D + 2*colu],     a0);
    atomicAdd(&pooled[g_cur*D + 2*colu + 1], a1);
    if (colu == 0) atomicAdd(&cnt[g_cur], cacc);
  }
}

// ---------------- final FC ----------------
__global__ void k_fc(const float* __restrict__ pooled, const float* __restrict__ cnt,
    const float* __restrict__ W, const float* __restrict__ b, float* __restrict__ out){
  int idx = blockIdx.x*256 + threadIdx.x;
  if (idx >= GR*64) return;
  int g = idx >> 6, o = idx & 63;
  const float* p = pooled + g*D;
  float s = 0.f;
  for (int c2 = 0; c2 < D; ++c2) s += p[c2] * W[c2*64 + o];
  float inv = 1.f / fmaxf(cnt[g], 1.f);
  out[idx] = s*inv + b[o];
}

extern "C" void kernel_launch(void* const* d_in, const int* in_sizes, int n_in,
                              void* d_out, int out_size, void* d_ws, size_t ws_size,
                              hipStream_t stream){
  (void)in_sizes; (void)n_in; (void)out_size; (void)ws_size;
  const float* x       = (const float*)d_in[0];
  const int*   ei      = (const int*)  d_in[1];
  const int*   batch   = (const int*)  d_in[2];
  const float* gat1_W  = (const float*)d_in[3];
  const float* gat1_as = (const float*)d_in[4];
  const float* gat1_ad = (const float*)d_in[5];
  const float* gat1_b  = (const float*)d_in[6];
  const float* gat2_W  = (const float*)d_in[7];
  const float* gat2_as = (const float*)d_in[8];
  const float* gat2_ad = (const float*)d_in[9];
  const float* gat2_b  = (const float*)d_in[10];
  const float* s3_Wl   = (const float*)d_in[11];
  const float* s3_bl   = (const float*)d_in[12];
  const float* s3_Wr   = (const float*)d_in[13];
  const float* s4_Wl   = (const float*)d_in[14];
  const float* s4_bl   = (const float*)d_in[15];
  const float* s4_Wr   = (const float*)d_in[16];
  const float* s5_Wl   = (const float*)d_in[17];
  const float* s5_bl   = (const float*)d_in[18];
  const float* s5_Wr   = (const float*)d_in[19];
  const float* bn1_g = (const float*)d_in[20]; const float* bn1_b = (const float*)d_in[21];
  const float* bn2_g = (const float*)d_in[22]; const float* bn2_b = (const float*)d_in[23];
  const float* bn3_g = (const float*)d_in[24]; const float* bn3_b = (const float*)d_in[25];
  const float* bn4_g = (const float*)d_in[26]; const float* bn4_b = (const float*)d_in[27];
  const float* bn5_g = (const float*)d_in[28]; const float* bn5_b = (const float*)d_in[29];
  const float* res1_W = (const float*)d_in[30]; const float* res1_b = (const float*)d_in[31];
  const float* res2_W = (const float*)d_in[32]; const float* res2_b = (const float*)d_in[33];
  const float* fc_W   = (const float*)d_in[34]; const float* fc_b   = (const float*)d_in[35];
  float* out = (float*)d_out;

  char* ws = (char*)d_ws;
  size_t off = 0;
  auto alloc = [&](size_t bytes) -> void* {
    void* p = ws + off; off += (bytes + 255) & ~(size_t)255; return p;
  };
  const int mgrid = (N_NODES + 63) / 64;
  int*   rowStart = (int*)  alloc((N_NODES + 1) * 4);
  int*   deg      = (int*)  alloc((size_t)N_NODES * 4);
  int*   rank     = (int*)  alloc((size_t)N_EDGES * 4);
  int*   srcList  = (int*)  alloc((size_t)N_EDGES * 4);
  int*   bsum     = (int*)  alloc(256 * 4);
  float* bnsums   = (float*)alloc(5 * 256 * 4);
  float* pooled   = (float*)alloc(GR * D * 4);
  float* cnt      = (float*)alloc(64 * 4);
  float* es       = (float*)alloc((size_t)N_NODES * 4 * 4);
  float* edv      = (float*)alloc((size_t)N_NODES * 4 * 4);
  float* bnpart   = (float*)alloc((size_t)mgrid * 256 * 4);
  unsigned short* Wt16 = (unsigned short*)alloc(10 * 16384 * 2);
  unsigned short* HX   = (unsigned short*)alloc((size_t)N_NODES * D * 2);
  unsigned short* H16a = (unsigned short*)alloc((size_t)N_NODES * D * 2);
  unsigned short* HO   = (unsigned short*)alloc((size_t)N_NODES * D * 2);
  unsigned short* HR   = (unsigned short*)alloc((size_t)N_NODES * D * 2);

  const int* srcE = ei;
  const int* dstE = ei + N_EDGES;
  const int nb = (N_NODES + 255) / 256;
  const int egrid = (N_EDGES + 255) / 256;
  const int agrid = (N_NODES + 3) / 4;
  const int bgrid = (N_NODES*32 + 255) / 256;
  const int pgrid = (N_NODES + 127) / 128;

  // CSR build
  hipMemsetAsync(deg, 0, (size_t)N_NODES*4, stream);
  hipMemsetAsync(bnsums, 0, (5*256 + GR*D + 64)*4, stream);
  k_countrank<<<egrid, 256, 0, stream>>>(dstE, deg, rank);
  k_scan1<<<nb, 256, 0, stream>>>(deg, bsum);
  k_scan2b<<<1, 256, 0, stream>>>(bsum, nb, rowStart);
  k_scan3<<<nb, 256, 0, stream>>>(deg, bsum, rowStart);
  k_scatter<<<egrid, 256, 0, stream>>>(srcE, dstE, rank, rowStart, srcList);

  // casts
  WPack wp;
  wp.w[0]=res1_W; wp.w[1]=gat1_W; wp.w[2]=res2_W; wp.w[3]=gat2_W;
  wp.w[4]=s3_Wl;  wp.w[5]=s3_Wr;  wp.w[6]=s4_Wl;  wp.w[7]=s4_Wr;
  wp.w[8]=s5_Wl;  wp.w[9]=s5_Wr;
  k_castw<<<640, 256, 0, stream>>>(wp, Wt16);
  k_cast_x<<<bgrid, 256, 0, stream>>>(x, HX);

  // ---- layer 1 (GAT) ----
  k_mgemm<<<mgrid, 256, 0, stream>>>(HX, Wt16 + 0*16384, res1_b, HR, N_NODES);
  k_mgemm_gat<<<mgrid, 256, 0, stream>>>(HX, Wt16 + 1*16384, gat1_as, gat1_ad,
                                         H16a, es, edv, N_NODES);
  k_gat<<<agrid, 256, 0, stream>>>((const unsigned int*)H16a, es, edv, rowStart,
                                   srcList, gat1_b, (unsigned int*)HO);
  k_bnstat<<<256, 256, 0, stream>>>((const unsigned int*)HO, bnsums);
  k_bnapply<<<bgrid, 256, 0, stream>>>((const unsigned int*)HO, bnsums, bn1_g, bn1_b,
                                       (const unsigned int*)HR, (unsigned int*)H16a);

  // ---- layer 2 (GAT) ----
  k_mgemm<<<mgrid, 256, 0, stream>>>(H16a, Wt16 + 2*16384, res2_b, HR, N_NODES);
  k_mgemm_gat<<<mgrid, 256, 0, stream>>>(H16a, Wt16 + 3*16384, gat2_as, gat2_ad,
                                         HX, es, edv, N_NODES);
  k_gat<<<agrid, 256, 0, stream>>>((const unsigned int*)HX, es, edv, rowStart,
                                   srcList, gat2_b, (unsigned int*)HO);
  k_bnstat<<<256, 256, 0, stream>>>((const unsigned int*)HO, bnsums + 256);
  k_bnapply<<<bgrid, 256, 0, stream>>>((const unsigned int*)HO, bnsums + 256, bn2_g, bn2_b,
                                       (const unsigned int*)HR, (unsigned int*)H16a);

  // ---- layer 3 (SAGE) ----
  k_sage_mean<<<agrid, 256, 0, stream>>>((const unsigned int*)H16a, rowStart, srcList,
                                         (unsigned int*)HX);
  k_mgemm2<<<mgrid, 256, 0, stream>>>(HX, Wt16 + 4*16384, H16a, Wt16 + 5*16384,
                                      s3_bl, HO, N_NODES, bnpart);
  k_bnred<<<64, 256, 0, stream>>>(bnpart, mgrid, bnsums + 512);
  k_bnapply<<<bgrid, 256, 0, stream>>>((const unsigned int*)HO, bnsums + 512, bn3_g, bn3_b,
                                       nullptr, (unsigned int*)H16a);

  // ---- layer 4 (SAGE) ----
  k_sage_mean<<<agrid, 256, 0, stream>>>((const unsigned int*)H16a, rowStart, srcList,
                                         (unsigned int*)HX);
  k_mgemm2<<<mgrid, 256, 0, stream>>>(HX, Wt16 + 6*16384, H16a, Wt16 + 7*16384,
                                      s4_bl, HO, N_NODES, bnpart);
  k_bnred<<<64, 256, 0, stream>>>(bnpart, mgrid, bnsums + 768);
  k_bnapply<<<bgrid, 256, 0, stream>>>((const unsigned int*)HO, bnsums + 768, bn4_g, bn4_b,
                                       nullptr, (unsigned int*)H16a);

  // ---- layer 5 (SAGE) ----
  k_sage_mean<<<agrid, 256, 0, stream>>>((const unsigned int*)H16a, rowStart, srcList,
                                         (unsigned int*)HX);
  k_mgemm2<<<mgrid, 256, 0, stream>>>(HX, Wt16 + 8*16384, H16a, Wt16 + 9*16384,
                                      s5_bl, HO, N_NODES, bnpart);
  k_bnred<<<64, 256, 0, stream>>>(bnpart, mgrid, bnsums + 1024);
  k_bnapply<<<bgrid, 256, 0, stream>>>((const unsigned int*)HO, bnsums + 1024, bn5_g, bn5_b,
                                       nullptr, (unsigned int*)H16a);

  // ---- pool + fc ----
  k_pool<<<pgrid, 256, 0, stream>>>((const unsigned int*)H16a, batch, pooled, cnt);
  k_fc<<<(GR*64 + 255)/256, 256, 0, stream>>>(pooled, cnt, fc_W, fc_b, out);
}

// Round 7
// 628.416 us; speedup vs baseline: 2.0514x; 1.0399x over previous
//
#include <hip/hip_runtime.h>
#include <math.h>
#include <stdint.h>

#define N_NODES 50000
#define N_EDGES 800000
#define D 128
#define GR 50
#define EPSV 1e-5f

typedef __attribute__((ext_vector_type(8))) short bf16x8;
typedef __attribute__((ext_vector_type(4))) float f32x4;

__device__ __forceinline__ float lrelu(float v){ return v > 0.f ? v : 0.2f*v; }

__device__ __forceinline__ unsigned int f2bf(float f){
  union { float f; uint32_t i; } v; v.f = f;
  uint32_t r = v.i + 0x7fffu + ((v.i >> 16) & 1u);
  return r >> 16;
}
__device__ __forceinline__ float2 bf2f2(uint32_t u){
  union { uint32_t i; float f; } a, b;
  a.i = u << 16;
  b.i = u & 0xffff0000u;
  return make_float2(a.f, b.f);
}

// ---------------- CSR build (one atomic pass) ----------------
__global__ void k_countrank(const int* __restrict__ dst, int* __restrict__ deg,
                            int* __restrict__ rank){
  int e = blockIdx.x*256 + threadIdx.x;
  if (e < N_EDGES) rank[e] = atomicAdd(&deg[dst[e]], 1);
}
__global__ void k_scan1(const int* __restrict__ deg, int* __restrict__ bsum){
  __shared__ int s[256];
  int i = blockIdx.x*256 + threadIdx.x;
  int v = (i < N_NODES) ? deg[i] : 0;
  s[threadIdx.x] = v; __syncthreads();
  for (int off = 128; off > 0; off >>= 1){
    if (threadIdx.x < off) s[threadIdx.x] += s[threadIdx.x + off];
    __syncthreads();
  }
  if (threadIdx.x == 0) bsum[blockIdx.x] = s[0];
}
__global__ void k_scan2b(int* __restrict__ bsum, int nb, int* __restrict__ rowStart){
  __shared__ int s[256];
  int t = threadIdx.x;
  int v = (t < nb) ? bsum[t] : 0;
  s[t] = v; __syncthreads();
  for (int off = 1; off < 256; off <<= 1){
    int xv = (t >= off) ? s[t - off] : 0;
    __syncthreads();
    s[t] += xv;
    __syncthreads();
  }
  if (t < nb) bsum[t] = s[t] - v;
  if (t == 255) rowStart[N_NODES] = s[255];
}
__global__ void k_scan3(const int* __restrict__ deg, const int* __restrict__ bsum,
                        int* __restrict__ rowStart){
  __shared__ int s[256];
  int i = blockIdx.x*256 + threadIdx.x;
  int v = (i < N_NODES) ? deg[i] : 0;
  s[threadIdx.x] = v; __syncthreads();
  for (int off = 1; off < 256; off <<= 1){
    int xv = (threadIdx.x >= off) ? s[threadIdx.x - off] : 0;
    __syncthreads();
    s[threadIdx.x] += xv;
    __syncthreads();
  }
  if (i < N_NODES) rowStart[i] = bsum[blockIdx.x] + s[threadIdx.x] - v;
}
__global__ void k_scatter(const int* __restrict__ src, const int* __restrict__ dst,
                          const int* __restrict__ rank, const int* __restrict__ rowStart,
                          int* __restrict__ srcList){
  int e = blockIdx.x*256 + threadIdx.x;
  if (e < N_EDGES)
    srcList[rowStart[dst[e]] + rank[e]] = src[e];
}

// ---------------- casts ----------------
__global__ void k_cast_x(const float* __restrict__ x, unsigned short* __restrict__ x16){
  int idx = blockIdx.x*256 + threadIdx.x;
  if (idx >= N_NODES*32) return;
  float4 v = *(const float4*)(x + (size_t)idx*4);
  uint2 pk;
  pk.x = f2bf(v.x) | (f2bf(v.y) << 16);
  pk.y = f2bf(v.z) | (f2bf(v.w) << 16);
  *(uint2*)(x16 + (size_t)idx*4) = pk;
}

struct WPack { const float* w[10]; };
__global__ void k_castw(WPack p, unsigned short* __restrict__ wt){
  int mat = blockIdx.x >> 6;
  int local = (blockIdx.x & 63)*256 + threadIdx.x;
  int c = local >> 7, k = local & 127;
  wt[(size_t)mat*16384 + c*128 + k] = (unsigned short)f2bf(p.w[mat][k*128 + c]);
}

// ======================= MFMA GEMM family =======================
__device__ __forceinline__ void stage_w(const unsigned short* __restrict__ wt,
                                        unsigned short* __restrict__ lds, int t){
  #pragma unroll
  for (int i = 0; i < 8; ++i){
    int ch = i*256 + t;
    int col = ch >> 4, kc = ch & 15;
    *(uint4*)(&lds[col*136 + kc*8]) = *(const uint4*)(wt + ((size_t)col << 7) + (kc << 3));
  }
}

__device__ __forceinline__ void load_a(const unsigned short* __restrict__ xrow,
                                       int quad, bf16x8 a[4]){
  #pragma unroll
  for (int ks = 0; ks < 4; ++ks)
    a[ks] = *(const bf16x8*)(xrow + ks*32 + quad*8);
}

__device__ __forceinline__ void mfma_regs(const bf16x8 a[4],
                                          const unsigned short* __restrict__ lds,
                                          int lane, f32x4 acc[8]){
  int quad = lane >> 4, m = lane & 15;
  #pragma unroll
  for (int ks = 0; ks < 4; ++ks){
    #pragma unroll
    for (int nt = 0; nt < 8; ++nt){
      bf16x8 b = *(const bf16x8*)(&lds[(nt*16 + m)*136 + ks*32 + quad*8]);
      acc[nt] = __builtin_amdgcn_mfma_f32_16x16x32_bf16(a[ks], b, acc[nt], 0, 0, 0);
    }
  }
}

__device__ __forceinline__ void epi_store16(f32x4 acc[8], const float* bias,
    unsigned short* __restrict__ ldsw, unsigned short* __restrict__ Y16,
    int rbase, int lane, int n){
  int quad = lane >> 4, m = lane & 15;
  #pragma unroll
  for (int nt = 0; nt < 8; ++nt){
    int col = nt*16 + m;
    float bv = bias ? bias[col] : 0.f;
    #pragma unroll
    for (int reg = 0; reg < 4; ++reg)
      ldsw[(quad*4 + reg)*132 + col] = (unsigned short)f2bf(acc[nt][reg] + bv);
  }
  int r = lane >> 2, seg = lane & 3;
  int grow = rbase + r;
  if (grow < n){
    unsigned short* gp = Y16 + (size_t)grow*128 + seg*32;
    #pragma unroll
    for (int j = 0; j < 4; ++j)
      *(uint4*)(gp + j*8) = *(const uint4*)(&ldsw[r*132 + seg*32 + j*8]);
  }
}

// ---- residual GEMM: R16 = bf16(X16 @ W + bias) ----
__global__ __launch_bounds__(256) void k_mgemm(const unsigned short* __restrict__ X16,
    const unsigned short* __restrict__ wt, const float* __restrict__ bias,
    unsigned short* __restrict__ Y16, int n){
  __shared__ __align__(16) unsigned short Wlds[128*136];
  int t = threadIdx.x, lane = t & 63, w = t >> 6;
  int quad = lane >> 4, m = lane & 15;
  int rbase = blockIdx.x*64 + w*16;
  int rowA = rbase + m; if (rowA >= n) rowA = n - 1;
  bf16x8 a[4];
  load_a(X16 + (size_t)rowA*128, quad, a);
  stage_w(wt, Wlds, t);
  f32x4 acc[8];
  #pragma unroll
  for (int nt = 0; nt < 8; ++nt){ acc[nt][0]=0.f; acc[nt][1]=0.f; acc[nt][2]=0.f; acc[nt][3]=0.f; }
  __syncthreads();
  mfma_regs(a, Wlds, lane, acc);
  __syncthreads();
  epi_store16(acc, bias, Wlds + w*2112, Y16, rbase, lane, n);
}

// ---- GAT GEMM: H16 = bf16(X16 @ W), fused es/ed ----
__global__ __launch_bounds__(256) void k_mgemm_gat(const unsigned short* __restrict__ X16,
    const unsigned short* __restrict__ wt, const float* __restrict__ as_,
    const float* __restrict__ ad_, unsigned short* __restrict__ H16,
    float* __restrict__ es, float* __restrict__ ed, int n){
  __shared__ __align__(16) unsigned short Wlds[128*136];
  int t = threadIdx.x, lane = t & 63, w = t >> 6;
  int quad = lane >> 4, m = lane & 15;
  int rbase = blockIdx.x*64 + w*16;
  int rowA = rbase + m; if (rowA >= n) rowA = n - 1;
  bf16x8 a[4];
  load_a(X16 + (size_t)rowA*128, quad, a);
  stage_w(wt, Wlds, t);
  f32x4 acc[8];
  #pragma unroll
  for (int nt = 0; nt < 8; ++nt){ acc[nt][0]=0.f; acc[nt][1]=0.f; acc[nt][2]=0.f; acc[nt][3]=0.f; }
  __syncthreads();
  mfma_regs(a, Wlds, lane, acc);

  float asv[8], adv[8];
  #pragma unroll
  for (int nt = 0; nt < 8; ++nt){ asv[nt] = as_[nt*16 + m]; adv[nt] = ad_[nt*16 + m]; }
  #pragma unroll
  for (int reg = 0; reg < 4; ++reg){
    int row = rbase + quad*4 + reg;
    float pe[4], pd[4];
    #pragma unroll
    for (int h = 0; h < 4; ++h){
      pe[h] = acc[2*h][reg]*asv[2*h] + acc[2*h+1][reg]*asv[2*h+1];
      pd[h] = acc[2*h][reg]*adv[2*h] + acc[2*h+1][reg]*adv[2*h+1];
    }
    #pragma unroll
    for (int h = 0; h < 4; ++h){
      pe[h] += __shfl_xor(pe[h], 1); pe[h] += __shfl_xor(pe[h], 2);
      pe[h] += __shfl_xor(pe[h], 4); pe[h] += __shfl_xor(pe[h], 8);
      pd[h] += __shfl_xor(pd[h], 1); pd[h] += __shfl_xor(pd[h], 2);
      pd[h] += __shfl_xor(pd[h], 4); pd[h] += __shfl_xor(pd[h], 8);
    }
    if (m == 0 && row < n){
      #pragma unroll
      for (int h = 0; h < 4; ++h){ es[row*4 + h] = pe[h]; ed[row*4 + h] = pd[h]; }
    }
  }
  __syncthreads();
  epi_store16(acc, nullptr, Wlds + w*2112, H16, rbase, lane, n);
}

// ---- SAGE dual GEMM: Y16 = bf16(Xa@Wa + bias + Xb@Wb), BN partials ----
__global__ __launch_bounds__(256) void k_mgemm2(const unsigned short* __restrict__ Xa,
    const unsigned short* __restrict__ wta, const unsigned short* __restrict__ Xb,
    const unsigned short* __restrict__ wtb, const float* __restrict__ bias,
    unsigned short* __restrict__ Y16, int n, float* __restrict__ bnpart){
  __shared__ __align__(16) unsigned short Wlds[128*136];
  __shared__ float wredS[4][128], wredQ[4][128];
  int t = threadIdx.x, lane = t & 63, w = t >> 6;
  int quad = lane >> 4, m = lane & 15;
  int rbase = blockIdx.x*64 + w*16;
  int rowA = rbase + m; if (rowA >= n) rowA = n - 1;
  bf16x8 aa[4], ab[4];
  load_a(Xa + (size_t)rowA*128, quad, aa);
  load_a(Xb + (size_t)rowA*128, quad, ab);
  stage_w(wta, Wlds, t);
  f32x4 acc[8];
  #pragma unroll
  for (int nt = 0; nt < 8; ++nt){ acc[nt][0]=0.f; acc[nt][1]=0.f; acc[nt][2]=0.f; acc[nt][3]=0.f; }
  __syncthreads();
  mfma_regs(aa, Wlds, lane, acc);
  __syncthreads();
  stage_w(wtb, Wlds, t);
  __syncthreads();
  mfma_regs(ab, Wlds, lane, acc);

  float colS[8], colQ[8];
  #pragma unroll
  for (int nt = 0; nt < 8; ++nt){
    float bv = bias[nt*16 + m];
    float s = 0.f, q = 0.f;
    #pragma unroll
    for (int reg = 0; reg < 4; ++reg){
      float o = acc[nt][reg] + bv;
      acc[nt][reg] = o;
      if (rbase + quad*4 + reg < n){ s += o; q += o*o; }
    }
    s += __shfl_xor(s, 16); s += __shfl_xor(s, 32);
    q += __shfl_xor(q, 16); q += __shfl_xor(q, 32);
    colS[nt] = s; colQ[nt] = q;
  }
  if (quad == 0){
    #pragma unroll
    for (int nt = 0; nt < 8; ++nt){
      wredS[w][nt*16 + m] = colS[nt];
      wredQ[w][nt*16 + m] = colQ[nt];
    }
  }
  __syncthreads();
  if (t < 128){
    float S = wredS[0][t] + wredS[1][t] + wredS[2][t] + wredS[3][t];
    float Q = wredQ[0][t] + wredQ[1][t] + wredQ[2][t] + wredQ[3][t];
    bnpart[(size_t)blockIdx.x*256 + t]       = S;
    bnpart[(size_t)blockIdx.x*256 + 128 + t] = Q;
  }
  epi_store16(acc, nullptr, Wlds + w*2112, Y16, rbase, lane, n);
}

__global__ void k_bnred(const float* __restrict__ part, int nblk,
                        float* __restrict__ sums){
  int g = blockIdx.x, t = threadIdx.x;
  int chunk = (nblk + 63) / 64;
  int b0 = g*chunk, b1 = min(nblk, b0 + chunk);
  float s = 0.f;
  for (int b = b0; b < b1; ++b) s += part[(size_t)b*256 + t];
  if (b0 < b1) atomicAdd(&sums[t], s);
}

// --------- GAT aggregation: 4 edge slots x 16 channel-groups, uint4 gathers -
__global__ __launch_bounds__(256) void k_gat(const uint4* __restrict__ h16,
    const float* __restrict__ es, const float* __restrict__ edv,
    const int* __restrict__ rowStart, const int* __restrict__ srcList,
    const float* __restrict__ bias, uint4* __restrict__ out16){
  int i = blockIdx.x*4 + (threadIdx.x >> 6);
  if (i >= N_NODES) return;
  int lane = threadIdx.x & 63;
  int sub = lane >> 4;            // edge slot 0..3
  int m   = lane & 15;            // channel group: ch = m*8 .. m*8+7
  int hd  = m >> 2;               // head of these channels
  float edi = edv[i*4 + hd];
  float acc[8];
  #pragma unroll
  for (int j = 0; j < 8; ++j) acc[j] = 0.f;
  float z = 0.f;
  if (sub == 0){                  // self loop counted once
    float ws = __expf(lrelu(es[i*4 + hd] + edi));
    uint4 u = h16[(size_t)i*16 + m];
    float2 v0=bf2f2(u.x), v1=bf2f2(u.y), v2=bf2f2(u.z), v3=bf2f2(u.w);
    acc[0]=v0.x*ws; acc[1]=v0.y*ws; acc[2]=v1.x*ws; acc[3]=v1.y*ws;
    acc[4]=v2.x*ws; acc[5]=v2.y*ws; acc[6]=v3.x*ws; acc[7]=v3.y*ws;
    z = ws;
  }
  int k0 = rowStart[i], ke = rowStart[i + 1];
  for (int k = k0; k < ke; k += 8){
    int e0 = k + sub, e1 = k + 4 + sub;
    int c0 = e0 < ke ? e0 : ke - 1;
    int c1 = e1 < ke ? e1 : ke - 1;
    int s0 = srcList[c0];
    int s1 = srcList[c1];
    uint4 u0 = h16[(size_t)s0*16 + m];
    uint4 u1 = h16[(size_t)s1*16 + m];
    float w0 = (e0 < ke) ? __expf(lrelu(es[s0*4 + hd] + edi)) : 0.f;
    float w1 = (e1 < ke) ? __expf(lrelu(es[s1*4 + hd] + edi)) : 0.f;
    z += w0 + w1;
    float2 a0=bf2f2(u0.x), a1=bf2f2(u0.y), a2=bf2f2(u0.z), a3=bf2f2(u0.w);
    float2 b0=bf2f2(u1.x), b1=bf2f2(u1.y), b2=bf2f2(u1.z), b3=bf2f2(u1.w);
    acc[0] += a0.x*w0 + b0.x*w1;  acc[1] += a0.y*w0 + b0.y*w1;
    acc[2] += a1.x*w0 + b1.x*w1;  acc[3] += a1.y*w0 + b1.y*w1;
    acc[4] += a2.x*w0 + b2.x*w1;  acc[5] += a2.y*w0 + b2.y*w1;
    acc[6] += a3.x*w0 + b3.x*w1;  acc[7] += a3.y*w0 + b3.y*w1;
  }
  #pragma unroll
  for (int j = 0; j < 8; ++j){
    acc[j] += __shfl_xor(acc[j], 16);
    acc[j] += __shfl_xor(acc[j], 32);
  }
  z += __shfl_xor(z, 16);
  z += __shfl_xor(z, 32);
  if (sub == 0){
    float inv = 1.f / z;
    float4 bv0 = *(const float4*)(bias + m*8);
    float4 bv1 = *(const float4*)(bias + m*8 + 4);
    uint4 pk;
    pk.x = f2bf(acc[0]*inv + bv0.x) | (f2bf(acc[1]*inv + bv0.y) << 16);
    pk.y = f2bf(acc[2]*inv + bv0.z) | (f2bf(acc[3]*inv + bv0.w) << 16);
    pk.z = f2bf(acc[4]*inv + bv1.x) | (f2bf(acc[5]*inv + bv1.y) << 16);
    pk.w = f2bf(acc[6]*inv + bv1.z) | (f2bf(acc[7]*inv + bv1.w) << 16);
    out16[(size_t)i*16 + m] = pk;
  }
}

// ---------------- SAGE mean aggregation: same slot structure ----------------
__global__ __launch_bounds__(256) void k_sage_mean(const uint4* __restrict__ h16,
    const int* __restrict__ rowStart, const int* __restrict__ srcList,
    uint4* __restrict__ out16){
  int i = blockIdx.x*4 + (threadIdx.x >> 6);
  if (i >= N_NODES) return;
  int lane = threadIdx.x & 63;
  int sub = lane >> 4;
  int m   = lane & 15;
  float acc[8];
  #pragma unroll
  for (int j = 0; j < 8; ++j) acc[j] = 0.f;
  int k0 = rowStart[i], ke = rowStart[i + 1];
  for (int k = k0; k < ke; k += 8){
    int e0 = k + sub, e1 = k + 4 + sub;
    int c0 = e0 < ke ? e0 : ke - 1;
    int c1 = e1 < ke ? e1 : ke - 1;
    int s0 = srcList[c0];
    int s1 = srcList[c1];
    uint4 u0 = h16[(size_t)s0*16 + m];
    uint4 u1 = h16[(size_t)s1*16 + m];
    float w0 = (e0 < ke) ? 1.f : 0.f;
    float w1 = (e1 < ke) ? 1.f : 0.f;
    float2 a0=bf2f2(u0.x), a1=bf2f2(u0.y), a2=bf2f2(u0.z), a3=bf2f2(u0.w);
    float2 b0=bf2f2(u1.x), b1=bf2f2(u1.y), b2=bf2f2(u1.z), b3=bf2f2(u1.w);
    acc[0] += a0.x*w0 + b0.x*w1;  acc[1] += a0.y*w0 + b0.y*w1;
    acc[2] += a1.x*w0 + b1.x*w1;  acc[3] += a1.y*w0 + b1.y*w1;
    acc[4] += a2.x*w0 + b2.x*w1;  acc[5] += a2.y*w0 + b2.y*w1;
    acc[6] += a3.x*w0 + b3.x*w1;  acc[7] += a3.y*w0 + b3.y*w1;
  }
  #pragma unroll
  for (int j = 0; j < 8; ++j){
    acc[j] += __shfl_xor(acc[j], 16);
    acc[j] += __shfl_xor(acc[j], 32);
  }
  if (sub == 0){
    int dg = ke - k0;
    float inv = 1.f / (float)(dg > 0 ? dg : 1);
    uint4 pk;
    pk.x = f2bf(acc[0]*inv) | (f2bf(acc[1]*inv) << 16);
    pk.y = f2bf(acc[2]*inv) | (f2bf(acc[3]*inv) << 16);
    pk.z = f2bf(acc[4]*inv) | (f2bf(acc[5]*inv) << 16);
    pk.w = f2bf(acc[6]*inv) | (f2bf(acc[7]*inv) << 16);
    out16[(size_t)i*16 + m] = pk;
  }
}

// ---------------- BatchNorm stats from bf16 ----------------
__global__ __launch_bounds__(256) void k_bnstat(const unsigned int* __restrict__ x16,
                                                float* __restrict__ sums){
  int colu = threadIdx.x & 63;
  int ro   = threadIdx.x >> 6;
  float s0 = 0.f, s1 = 0.f, q0 = 0.f, q1 = 0.f;
  for (int r = blockIdx.x*4 + ro; r < N_NODES; r += gridDim.x*4){
    float2 v = bf2f2(x16[(size_t)r*64 + colu]);
    s0 += v.x; s1 += v.y; q0 += v.x*v.x; q1 += v.y*v.y;
  }
  __shared__ float rs0[256], rs1[256], rq0[256], rq1[256];
  int t = threadIdx.x;
  rs0[t] = s0; rs1[t] = s1; rq0[t] = q0; rq1[t] = q1;
  __syncthreads();
  if (t < 64){
    float S0 = rs0[t] + rs0[t+64] + rs0[t+128] + rs0[t+192];
    float S1 = rs1[t] + rs1[t+64] + rs1[t+128] + rs1[t+192];
    float Q0 = rq0[t] + rq0[t+64] + rq0[t+128] + rq0[t+192];
    float Q1 = rq1[t] + rq1[t+64] + rq1[t+128] + rq1[t+192];
    atomicAdd(&sums[2*t],       S0);
    atomicAdd(&sums[2*t + 1],   S1);
    atomicAdd(&sums[128 + 2*t],     Q0);
    atomicAdd(&sums[128 + 2*t + 1], Q1);
  }
}

// --------- BN apply (+opt bf16 residual) + lrelu; bf16 in/out ---------
__global__ void k_bnapply(const unsigned int* __restrict__ x16,
    const float* __restrict__ sums, const float* __restrict__ g,
    const float* __restrict__ b, const unsigned int* __restrict__ res16,
    unsigned int* __restrict__ y16){
  int f = blockIdx.x*256 + threadIdx.x;
  if (f >= N_NODES*32) return;
  int c = (f & 31) * 4;
  uint2 u = *(const uint2*)(x16 + (size_t)f*2);
  float2 vA = bf2f2(u.x), vB = bf2f2(u.y);
  float vv[4] = {vA.x, vA.y, vB.x, vB.y};
  float rr[4] = {0.f, 0.f, 0.f, 0.f};
  if (res16){
    uint2 ur = *(const uint2*)(res16 + (size_t)f*2);
    float2 rA = bf2f2(ur.x), rB = bf2f2(ur.y);
    rr[0]=rA.x; rr[1]=rA.y; rr[2]=rB.x; rr[3]=rB.y;
  }
  float o[4];
  const float invn = 1.f / (float)N_NODES;
  #pragma unroll
  for (int j = 0; j < 4; ++j){
    int cc = c + j;
    float mu  = sums[cc] * invn;
    float var = sums[128 + cc] * invn - mu*mu;
    float rs  = rsqrtf(var + EPSV);
    o[j] = lrelu((vv[j] - mu)*rs*g[cc] + b[cc] + rr[j]);
  }
  uint2 pk;
  pk.x = f2bf(o[0]) | (f2bf(o[1]) << 16);
  pk.y = f2bf(o[2]) | (f2bf(o[3]) << 16);
  *(uint2*)(y16 + (size_t)f*2) = pk;
}

// ---------------- global mean pool (bf16 input) ----------------
__global__ __launch_bounds__(256) void k_pool(const unsigned int* __restrict__ h16,
    const int* __restrict__ batch, float* __restrict__ pooled,
    float* __restrict__ cnt){
  int colu = threadIdx.x & 63;
  int ro   = threadIdx.x >> 6;
  int base = blockIdx.x * 128;
  int g_cur = -1; float a0 = 0.f, a1 = 0.f, cacc = 0.f;
  for (int ii = 0; ii < 32; ++ii){
    int r = base + ro + ii*4;
    if (r >= N_NODES) break;
    int g = batch[r];
    if (g != g_cur){
      if (g_cur >= 0){
        atomicAdd(&pooled[g_cur*D + 2*colu],     a0);
        atomicAdd(&pooled[g_cur*D + 2*colu + 1], a1);
        if (colu == 0) atomicAdd(&cnt[g_cur], cacc);
      }
      a0 = 0.f; a1 = 0.f; cacc = 0.f; g_cur = g;
    }
    float2 v = bf2f2(h16[(size_t)r*64 + colu]);
    a0 += v.x; a1 += v.y; cacc += 1.f;
  }
  if (g_cur >= 0){
    atomicAdd(&pooled[g_cur*D + 2*colu],     a0);
    atomicAdd(&pooled[g_cur*D + 2*colu + 1], a1);
    if (colu == 0) atomicAdd(&cnt[g_cur], cacc);
  }
}

// ---------------- final FC ----------------
__global__ void k_fc(const float* __restrict__ pooled, const float* __restrict__ cnt,
    const float* __restrict__ W, const float* __restrict__ b, float* __restrict__ out){
  int idx = blockIdx.x*256 + threadIdx.x;
  if (idx >= GR*64) return;
  int g = idx >> 6, o = idx & 63;
  const float* p = pooled + g*D;
  float s = 0.f;
  for (int c2 = 0; c2 < D; ++c2) s += p[c2] * W[c2*64 + o];
  float inv = 1.f / fmaxf(cnt[g], 1.f);
  out[idx] = s*inv + b[o];
}

extern "C" void kernel_launch(void* const* d_in, const int* in_sizes, int n_in,
                              void* d_out, int out_size, void* d_ws, size_t ws_size,
                              hipStream_t stream){
  (void)in_sizes; (void)n_in; (void)out_size; (void)ws_size;
  const float* x       = (const float*)d_in[0];
  const int*   ei      = (const int*)  d_in[1];
  const int*   batch   = (const int*)  d_in[2];
  const float* gat1_W  = (const float*)d_in[3];
  const float* gat1_as = (const float*)d_in[4];
  const float* gat1_ad = (const float*)d_in[5];
  const float* gat1_b  = (const float*)d_in[6];
  const float* gat2_W  = (const float*)d_in[7];
  const float* gat2_as = (const float*)d_in[8];
  const float* gat2_ad = (const float*)d_in[9];
  const float* gat2_b  = (const float*)d_in[10];
  const float* s3_Wl   = (const float*)d_in[11];
  const float* s3_bl   = (const float*)d_in[12];
  const float* s3_Wr   = (const float*)d_in[13];
  const float* s4_Wl   = (const float*)d_in[14];
  const float* s4_bl   = (const float*)d_in[15];
  const float* s4_Wr   = (const float*)d_in[16];
  const float* s5_Wl   = (const float*)d_in[17];
  const float* s5_bl   = (const float*)d_in[18];
  const float* s5_Wr   = (const float*)d_in[19];
  const float* bn1_g = (const float*)d_in[20]; const float* bn1_b = (const float*)d_in[21];
  const float* bn2_g = (const float*)d_in[22]; const float* bn2_b = (const float*)d_in[23];
  const float* bn3_g = (const float*)d_in[24]; const float* bn3_b = (const float*)d_in[25];
  const float* bn4_g = (const float*)d_in[26]; const float* bn4_b = (const float*)d_in[27];
  const float* bn5_g = (const float*)d_in[28]; const float* bn5_b = (const float*)d_in[29];
  const float* res1_W = (const float*)d_in[30]; const float* res1_b = (const float*)d_in[31];
  const float* res2_W = (const float*)d_in[32]; const float* res2_b = (const float*)d_in[33];
  const float* fc_W   = (const float*)d_in[34]; const float* fc_b   = (const float*)d_in[35];
  float* out = (float*)d_out;

  char* ws = (char*)d_ws;
  size_t off = 0;
  auto alloc = [&](size_t bytes) -> void* {
    void* p = ws + off; off += (bytes + 255) & ~(size_t)255; return p;
  };
  const int mgrid = (N_NODES + 63) / 64;
  int*   rowStart = (int*)  alloc((N_NODES + 1) * 4);
  int*   deg      = (int*)  alloc((size_t)N_NODES * 4);
  int*   rank     = (int*)  alloc((size_t)N_EDGES * 4);
  int*   srcList  = (int*)  alloc((size_t)N_EDGES * 4);
  int*   bsum     = (int*)  alloc(256 * 4);
  float* bnsums   = (float*)alloc(5 * 256 * 4);
  float* pooled   = (float*)alloc(GR * D * 4);
  float* cnt      = (float*)alloc(64 * 4);
  float* es       = (float*)alloc((size_t)N_NODES * 4 * 4);
  float* edv      = (float*)alloc((size_t)N_NODES * 4 * 4);
  float* bnpart   = (float*)alloc((size_t)mgrid * 256 * 4);
  unsigned short* Wt16 = (unsigned short*)alloc(10 * 16384 * 2);
  unsigned short* HX   = (unsigned short*)alloc((size_t)N_NODES * D * 2);
  unsigned short* H16a = (unsigned short*)alloc((size_t)N_NODES * D * 2);
  unsigned short* HO   = (unsigned short*)alloc((size_t)N_NODES * D * 2);
  unsigned short* HR   = (unsigned short*)alloc((size_t)N_NODES * D * 2);

  const int* srcE = ei;
  const int* dstE = ei + N_EDGES;
  const int nb = (N_NODES + 255) / 256;
  const int egrid = (N_EDGES + 255) / 256;
  const int agrid = (N_NODES + 3) / 4;
  const int bgrid = (N_NODES*32 + 255) / 256;
  const int pgrid = (N_NODES + 127) / 128;

  // CSR build
  hipMemsetAsync(deg, 0, (size_t)N_NODES*4, stream);
  hipMemsetAsync(bnsums, 0, (5*256 + GR*D + 64)*4, stream);
  k_countrank<<<egrid, 256, 0, stream>>>(dstE, deg, rank);
  k_scan1<<<nb, 256, 0, stream>>>(deg, bsum);
  k_scan2b<<<1, 256, 0, stream>>>(bsum, nb, rowStart);
  k_scan3<<<nb, 256, 0, stream>>>(deg, bsum, rowStart);
  k_scatter<<<egrid, 256, 0, stream>>>(srcE, dstE, rank, rowStart, srcList);

  // casts
  WPack wp;
  wp.w[0]=res1_W; wp.w[1]=gat1_W; wp.w[2]=res2_W; wp.w[3]=gat2_W;
  wp.w[4]=s3_Wl;  wp.w[5]=s3_Wr;  wp.w[6]=s4_Wl;  wp.w[7]=s4_Wr;
  wp.w[8]=s5_Wl;  wp.w[9]=s5_Wr;
  k_castw<<<640, 256, 0, stream>>>(wp, Wt16);
  k_cast_x<<<bgrid, 256, 0, stream>>>(x, HX);

  // ---- layer 1 (GAT) ----
  k_mgemm<<<mgrid, 256, 0, stream>>>(HX, Wt16 + 0*16384, res1_b, HR, N_NODES);
  k_mgemm_gat<<<mgrid, 256, 0, stream>>>(HX, Wt16 + 1*16384, gat1_as, gat1_ad,
                                         H16a, es, edv, N_NODES);
  k_gat<<<agrid, 256, 0, stream>>>((const uint4*)H16a, es, edv, rowStart,
                                   srcList, gat1_b, (uint4*)HO);
  k_bnstat<<<256, 256, 0, stream>>>((const unsigned int*)HO, bnsums);
  k_bnapply<<<bgrid, 256, 0, stream>>>((const unsigned int*)HO, bnsums, bn1_g, bn1_b,
                                       (const unsigned int*)HR, (unsigned int*)H16a);

  // ---- layer 2 (GAT) ----
  k_mgemm<<<mgrid, 256, 0, stream>>>(H16a, Wt16 + 2*16384, res2_b, HR, N_NODES);
  k_mgemm_gat<<<mgrid, 256, 0, stream>>>(H16a, Wt16 + 3*16384, gat2_as, gat2_ad,
                                         HX, es, edv, N_NODES);
  k_gat<<<agrid, 256, 0, stream>>>((const uint4*)HX, es, edv, rowStart,
                                   srcList, gat2_b, (uint4*)HO);
  k_bnstat<<<256, 256, 0, stream>>>((const unsigned int*)HO, bnsums + 256);
  k_bnapply<<<bgrid, 256, 0, stream>>>((const unsigned int*)HO, bnsums + 256, bn2_g, bn2_b,
                                       (const unsigned int*)HR, (unsigned int*)H16a);

  // ---- layer 3 (SAGE) ----
  k_sage_mean<<<agrid, 256, 0, stream>>>((const uint4*)H16a, rowStart, srcList,
                                         (uint4*)HX);
  k_mgemm2<<<mgrid, 256, 0, stream>>>(HX, Wt16 + 4*16384, H16a, Wt16 + 5*16384,
                                      s3_bl, HO, N_NODES, bnpart);
  k_bnred<<<64, 256, 0, stream>>>(bnpart, mgrid, bnsums + 512);
  k_bnapply<<<bgrid, 256, 0, stream>>>((const unsigned int*)HO, bnsums + 512, bn3_g, bn3_b,
                                       nullptr, (unsigned int*)H16a);

  // ---- layer 4 (SAGE) ----
  k_sage_mean<<<agrid, 256, 0, stream>>>((const uint4*)H16a, rowStart, srcList,
                                         (uint4*)HX);
  k_mgemm2<<<mgrid, 256, 0, stream>>>(HX, Wt16 + 6*16384, H16a, Wt16 + 7*16384,
                                      s4_bl, HO, N_NODES, bnpart);
  k_bnred<<<64, 256, 0, stream>>>(bnpart, mgrid, bnsums + 768);
  k_bnapply<<<bgrid, 256, 0, stream>>>((const unsigned int*)HO, bnsums + 768, bn4_g, bn4_b,
                                       nullptr, (unsigned int*)H16a);

  // ---- layer 5 (SAGE) ----
  k_sage_mean<<<agrid, 256, 0, stream>>>((const uint4*)H16a, rowStart, srcList,
                                         (uint4*)HX);
  k_mgemm2<<<mgrid, 256, 0, stream>>>(HX, Wt16 + 8*16384, H16a, Wt16 + 9*16384,
                                      s5_bl, HO, N_NODES, bnpart);
  k_bnred<<<64, 256, 0, stream>>>(bnpart, mgrid, bnsums + 1024);
  k_bnapply<<<bgrid, 256, 0, stream>>>((const unsigned int*)HO, bnsums + 1024, bn5_g, bn5_b,
                                       nullptr, (unsigned int*)H16a);

  // ---- pool + fc ----
  k_pool<<<pgrid, 256, 0, stream>>>((const unsigned int*)H16a, batch, pooled, cnt);
  k_fc<<<(GR*64 + 255)/256, 256, 0, stream>>>(pooled, cnt, fc_W, fc_b, out);
}

// Round 8
// 611.180 us; speedup vs baseline: 2.1092x; 1.0282x over previous
//
#include <hip/hip_runtime.h>
#include <math.h>
#include <stdint.h>

#define N_NODES 50000
#define N_EDGES 800000
#define D 128
#define GR 50
#define EPSV 1e-5f
#define GATGRID 2048

typedef __attribute__((ext_vector_type(8))) short bf16x8;
typedef __attribute__((ext_vector_type(4))) float f32x4;

__device__ __forceinline__ float lrelu(float v){ return v > 0.f ? v : 0.2f*v; }

__device__ __forceinline__ unsigned int f2bf(float f){
  union { float f; uint32_t i; } v; v.f = f;
  uint32_t r = v.i + 0x7fffu + ((v.i >> 16) & 1u);
  return r >> 16;
}
__device__ __forceinline__ float2 bf2f2(uint32_t u){
  union { uint32_t i; float f; } a, b;
  a.i = u << 16;
  b.i = u & 0xffff0000u;
  return make_float2(a.f, b.f);
}

// ---------------- CSR build (one atomic pass) ----------------
__global__ void k_countrank(const int* __restrict__ dst, int* __restrict__ deg,
                            int* __restrict__ rank){
  int e = blockIdx.x*256 + threadIdx.x;
  if (e < N_EDGES) rank[e] = atomicAdd(&deg[dst[e]], 1);
}
__global__ void k_scan1(const int* __restrict__ deg, int* __restrict__ bsum){
  __shared__ int s[256];
  int i = blockIdx.x*256 + threadIdx.x;
  int v = (i < N_NODES) ? deg[i] : 0;
  s[threadIdx.x] = v; __syncthreads();
  for (int off = 128; off > 0; off >>= 1){
    if (threadIdx.x < off) s[threadIdx.x] += s[threadIdx.x + off];
    __syncthreads();
  }
  if (threadIdx.x == 0) bsum[blockIdx.x] = s[0];
}
__global__ void k_scan2b(int* __restrict__ bsum, int nb, int* __restrict__ rowStart){
  __shared__ int s[256];
  int t = threadIdx.x;
  int v = (t < nb) ? bsum[t] : 0;
  s[t] = v; __syncthreads();
  for (int off = 1; off < 256; off <<= 1){
    int xv = (t >= off) ? s[t - off] : 0;
    __syncthreads();
    s[t] += xv;
    __syncthreads();
  }
  if (t < nb) bsum[t] = s[t] - v;
  if (t == 255) rowStart[N_NODES] = s[255];
}
__global__ void k_scan3(const int* __restrict__ deg, const int* __restrict__ bsum,
                        int* __restrict__ rowStart){
  __shared__ int s[256];
  int i = blockIdx.x*256 + threadIdx.x;
  int v = (i < N_NODES) ? deg[i] : 0;
  s[threadIdx.x] = v; __syncthreads();
  for (int off = 1; off < 256; off <<= 1){
    int xv = (threadIdx.x >= off) ? s[threadIdx.x - off] : 0;
    __syncthreads();
    s[threadIdx.x] += xv;
    __syncthreads();
  }
  if (i < N_NODES) rowStart[i] = bsum[blockIdx.x] + s[threadIdx.x] - v;
}
__global__ void k_scatter(const int* __restrict__ src, const int* __restrict__ dst,
                          const int* __restrict__ rank, const int* __restrict__ rowStart,
                          int* __restrict__ srcList){
  int e = blockIdx.x*256 + threadIdx.x;
  if (e < N_EDGES)
    srcList[rowStart[dst[e]] + rank[e]] = src[e];
}

// ---------------- casts ----------------
__global__ void k_cast_x(const float* __restrict__ x, unsigned short* __restrict__ x16){
  int idx = blockIdx.x*256 + threadIdx.x;
  if (idx >= N_NODES*32) return;
  float4 v = *(const float4*)(x + (size_t)idx*4);
  uint2 pk;
  pk.x = f2bf(v.x) | (f2bf(v.y) << 16);
  pk.y = f2bf(v.z) | (f2bf(v.w) << 16);
  *(uint2*)(x16 + (size_t)idx*4) = pk;
}

struct WPack { const float* w[10]; };
__global__ void k_castw(WPack p, unsigned short* __restrict__ wt){
  int mat = blockIdx.x >> 6;
  int local = (blockIdx.x & 63)*256 + threadIdx.x;
  int c = local >> 7, k = local & 127;
  wt[(size_t)mat*16384 + c*128 + k] = (unsigned short)f2bf(p.w[mat][k*128 + c]);
}

// ======================= MFMA GEMM family =======================
__device__ __forceinline__ void stage_w(const unsigned short* __restrict__ wt,
                                        unsigned short* __restrict__ lds, int t){
  #pragma unroll
  for (int i = 0; i < 8; ++i){
    int ch = i*256 + t;
    int col = ch >> 4, kc = ch & 15;
    *(uint4*)(&lds[col*136 + kc*8]) = *(const uint4*)(wt + ((size_t)col << 7) + (kc << 3));
  }
}

__device__ __forceinline__ void load_a(const unsigned short* __restrict__ xrow,
                                       int quad, bf16x8 a[4]){
  #pragma unroll
  for (int ks = 0; ks < 4; ++ks)
    a[ks] = *(const bf16x8*)(xrow + ks*32 + quad*8);
}

__device__ __forceinline__ void mfma_regs(const bf16x8 a[4],
                                          const unsigned short* __restrict__ lds,
                                          int lane, f32x4 acc[8]){
  int quad = lane >> 4, m = lane & 15;
  #pragma unroll
  for (int ks = 0; ks < 4; ++ks){
    #pragma unroll
    for (int nt = 0; nt < 8; ++nt){
      bf16x8 b = *(const bf16x8*)(&lds[(nt*16 + m)*136 + ks*32 + quad*8]);
      acc[nt] = __builtin_amdgcn_mfma_f32_16x16x32_bf16(a[ks], b, acc[nt], 0, 0, 0);
    }
  }
}

__device__ __forceinline__ void epi_store16(f32x4 acc[8], const float* bias,
    unsigned short* __restrict__ ldsw, unsigned short* __restrict__ Y16,
    int rbase, int lane, int n){
  int quad = lane >> 4, m = lane & 15;
  #pragma unroll
  for (int nt = 0; nt < 8; ++nt){
    int col = nt*16 + m;
    float bv = bias ? bias[col] : 0.f;
    #pragma unroll
    for (int reg = 0; reg < 4; ++reg)
      ldsw[(quad*4 + reg)*132 + col] = (unsigned short)f2bf(acc[nt][reg] + bv);
  }
  int r = lane >> 2, seg = lane & 3;
  int grow = rbase + r;
  if (grow < n){
    unsigned short* gp = Y16 + (size_t)grow*128 + seg*32;
    #pragma unroll
    for (int j = 0; j < 4; ++j)
      *(uint4*)(gp + j*8) = *(const uint4*)(&ldsw[r*132 + seg*32 + j*8]);
  }
}

// ---- GAT-layer dual GEMM: R16 = bf16(X@Wres + bres); H16 = bf16(X@Wgat); es/ed
__global__ __launch_bounds__(256) void k_mgemm_dual(const unsigned short* __restrict__ X16,
    const unsigned short* __restrict__ wtres, const unsigned short* __restrict__ wtgat,
    const float* __restrict__ bres, const float* __restrict__ as_,
    const float* __restrict__ ad_, unsigned short* __restrict__ R16,
    unsigned short* __restrict__ H16, float* __restrict__ es, float* __restrict__ ed,
    int n){
  __shared__ __align__(16) unsigned short Wlds[128*136];
  int t = threadIdx.x, lane = t & 63, w = t >> 6;
  int quad = lane >> 4, m = lane & 15;
  int rbase = blockIdx.x*64 + w*16;
  int rowA = rbase + m; if (rowA >= n) rowA = n - 1;
  bf16x8 a[4];
  load_a(X16 + (size_t)rowA*128, quad, a);
  stage_w(wtres, Wlds, t);
  f32x4 accR[8], accG[8];
  #pragma unroll
  for (int nt = 0; nt < 8; ++nt){
    accR[nt][0]=0.f; accR[nt][1]=0.f; accR[nt][2]=0.f; accR[nt][3]=0.f;
    accG[nt][0]=0.f; accG[nt][1]=0.f; accG[nt][2]=0.f; accG[nt][3]=0.f;
  }
  __syncthreads();
  mfma_regs(a, Wlds, lane, accR);
  __syncthreads();
  stage_w(wtgat, Wlds, t);
  __syncthreads();
  mfma_regs(a, Wlds, lane, accG);

  // es/ed from accG
  float asv[8], adv[8];
  #pragma unroll
  for (int nt = 0; nt < 8; ++nt){ asv[nt] = as_[nt*16 + m]; adv[nt] = ad_[nt*16 + m]; }
  #pragma unroll
  for (int reg = 0; reg < 4; ++reg){
    int row = rbase + quad*4 + reg;
    float pe[4], pd[4];
    #pragma unroll
    for (int h = 0; h < 4; ++h){
      pe[h] = accG[2*h][reg]*asv[2*h] + accG[2*h+1][reg]*asv[2*h+1];
      pd[h] = accG[2*h][reg]*adv[2*h] + accG[2*h+1][reg]*adv[2*h+1];
    }
    #pragma unroll
    for (int h = 0; h < 4; ++h){
      pe[h] += __shfl_xor(pe[h], 1); pe[h] += __shfl_xor(pe[h], 2);
      pe[h] += __shfl_xor(pe[h], 4); pe[h] += __shfl_xor(pe[h], 8);
      pd[h] += __shfl_xor(pd[h], 1); pd[h] += __shfl_xor(pd[h], 2);
      pd[h] += __shfl_xor(pd[h], 4); pd[h] += __shfl_xor(pd[h], 8);
    }
    if (m == 0 && row < n){
      #pragma unroll
      for (int h = 0; h < 4; ++h){ es[row*4 + h] = pe[h]; ed[row*4 + h] = pd[h]; }
    }
  }
  __syncthreads();          // done reading Wlds -> reuse per-wave for transpose
  epi_store16(accR, bres,    Wlds + w*2112, R16, rbase, lane, n);
  epi_store16(accG, nullptr, Wlds + w*2112, H16, rbase, lane, n);
}

// ---- SAGE dual GEMM: Y16 = bf16(Xa@Wa + bias + Xb@Wb), BN partials ----
__global__ __launch_bounds__(256) void k_mgemm2(const unsigned short* __restrict__ Xa,
    const unsigned short* __restrict__ wta, const unsigned short* __restrict__ Xb,
    const unsigned short* __restrict__ wtb, const float* __restrict__ bias,
    unsigned short* __restrict__ Y16, int n, float* __restrict__ bnpart){
  __shared__ __align__(16) unsigned short Wlds[128*136];
  __shared__ float wredS[4][128], wredQ[4][128];
  int t = threadIdx.x, lane = t & 63, w = t >> 6;
  int quad = lane >> 4, m = lane & 15;
  int rbase = blockIdx.x*64 + w*16;
  int rowA = rbase + m; if (rowA >= n) rowA = n - 1;
  bf16x8 aa[4], ab[4];
  load_a(Xa + (size_t)rowA*128, quad, aa);
  load_a(Xb + (size_t)rowA*128, quad, ab);
  stage_w(wta, Wlds, t);
  f32x4 acc[8];
  #pragma unroll
  for (int nt = 0; nt < 8; ++nt){ acc[nt][0]=0.f; acc[nt][1]=0.f; acc[nt][2]=0.f; acc[nt][3]=0.f; }
  __syncthreads();
  mfma_regs(aa, Wlds, lane, acc);
  __syncthreads();
  stage_w(wtb, Wlds, t);
  __syncthreads();
  mfma_regs(ab, Wlds, lane, acc);

  float colS[8], colQ[8];
  #pragma unroll
  for (int nt = 0; nt < 8; ++nt){
    float bv = bias[nt*16 + m];
    float s = 0.f, q = 0.f;
    #pragma unroll
    for (int reg = 0; reg < 4; ++reg){
      float o = acc[nt][reg] + bv;
      acc[nt][reg] = o;
      if (rbase + quad*4 + reg < n){ s += o; q += o*o; }
    }
    s += __shfl_xor(s, 16); s += __shfl_xor(s, 32);
    q += __shfl_xor(q, 16); q += __shfl_xor(q, 32);
    colS[nt] = s; colQ[nt] = q;
  }
  if (quad == 0){
    #pragma unroll
    for (int nt = 0; nt < 8; ++nt){
      wredS[w][nt*16 + m] = colS[nt];
      wredQ[w][nt*16 + m] = colQ[nt];
    }
  }
  __syncthreads();
  if (t < 128){
    float S = wredS[0][t] + wredS[1][t] + wredS[2][t] + wredS[3][t];
    float Q = wredQ[0][t] + wredQ[1][t] + wredQ[2][t] + wredQ[3][t];
    bnpart[(size_t)blockIdx.x*256 + t]       = S;
    bnpart[(size_t)blockIdx.x*256 + 128 + t] = Q;
  }
  epi_store16(acc, nullptr, Wlds + w*2112, Y16, rbase, lane, n);
}

__global__ void k_bnred(const float* __restrict__ part, int nblk,
                        float* __restrict__ sums){
  int g = blockIdx.x, t = threadIdx.x;
  int chunk = (nblk + 63) / 64;
  int b0 = g*chunk, b1 = min(nblk, b0 + chunk);
  float s = 0.f;
  for (int b = b0; b < b1; ++b) s += part[(size_t)b*256 + t];
  if (b0 < b1) atomicAdd(&sums[t], s);
}

// --------- GAT aggregation: grid-stride, fused BN partials ----------
__global__ __launch_bounds__(256) void k_gat(const uint4* __restrict__ h16,
    const float* __restrict__ es, const float* __restrict__ edv,
    const int* __restrict__ rowStart, const int* __restrict__ srcList,
    const float* __restrict__ bias, uint4* __restrict__ out16,
    float* __restrict__ bnpart){
  __shared__ float wredS[4][128], wredQ[4][128];
  int t = threadIdx.x;
  int lane = t & 63, wv = t >> 6;
  int sub = lane >> 4;            // edge slot 0..3
  int m   = lane & 15;            // channel group
  int hd  = m >> 2;
  float4 bv0 = *(const float4*)(bias + m*8);
  float4 bv1 = *(const float4*)(bias + m*8 + 4);
  float colS[8], colQ[8];
  #pragma unroll
  for (int j = 0; j < 8; ++j){ colS[j] = 0.f; colQ[j] = 0.f; }

  for (int i = blockIdx.x*4 + wv; i < N_NODES; i += GATGRID*4){
    float edi = edv[i*4 + hd];
    float acc[8];
    #pragma unroll
    for (int j = 0; j < 8; ++j) acc[j] = 0.f;
    float z = 0.f;
    if (sub == 0){
      float ws = __expf(lrelu(es[i*4 + hd] + edi));
      uint4 u = h16[i*16 + m];
      float2 v0=bf2f2(u.x), v1=bf2f2(u.y), v2=bf2f2(u.z), v3=bf2f2(u.w);
      acc[0]=v0.x*ws; acc[1]=v0.y*ws; acc[2]=v1.x*ws; acc[3]=v1.y*ws;
      acc[4]=v2.x*ws; acc[5]=v2.y*ws; acc[6]=v3.x*ws; acc[7]=v3.y*ws;
      z = ws;
    }
    int k0 = rowStart[i], ke = rowStart[i + 1];
    for (int k = k0; k < ke; k += 8){
      int e0 = k + sub, e1 = k + 4 + sub;
      int c0 = e0 < ke ? e0 : ke - 1;
      int c1 = e1 < ke ? e1 : ke - 1;
      int s0 = srcList[c0];
      int s1 = srcList[c1];
      uint4 u0 = h16[s0*16 + m];
      uint4 u1 = h16[s1*16 + m];
      float w0 = (e0 < ke) ? __expf(lrelu(es[s0*4 + hd] + edi)) : 0.f;
      float w1 = (e1 < ke) ? __expf(lrelu(es[s1*4 + hd] + edi)) : 0.f;
      z += w0 + w1;
      float2 a0=bf2f2(u0.x), a1=bf2f2(u0.y), a2=bf2f2(u0.z), a3=bf2f2(u0.w);
      float2 b0=bf2f2(u1.x), b1=bf2f2(u1.y), b2=bf2f2(u1.z), b3=bf2f2(u1.w);
      acc[0] += a0.x*w0 + b0.x*w1;  acc[1] += a0.y*w0 + b0.y*w1;
      acc[2] += a1.x*w0 + b1.x*w1;  acc[3] += a1.y*w0 + b1.y*w1;
      acc[4] += a2.x*w0 + b2.x*w1;  acc[5] += a2.y*w0 + b2.y*w1;
      acc[6] += a3.x*w0 + b3.x*w1;  acc[7] += a3.y*w0 + b3.y*w1;
    }
    #pragma unroll
    for (int j = 0; j < 8; ++j){
      acc[j] += __shfl_xor(acc[j], 16);
      acc[j] += __shfl_xor(acc[j], 32);
    }
    z += __shfl_xor(z, 16);
    z += __shfl_xor(z, 32);
    if (sub == 0){
      float inv = 1.f / z;
      float o[8];
      o[0]=acc[0]*inv+bv0.x; o[1]=acc[1]*inv+bv0.y; o[2]=acc[2]*inv+bv0.z; o[3]=acc[3]*inv+bv0.w;
      o[4]=acc[4]*inv+bv1.x; o[5]=acc[5]*inv+bv1.y; o[6]=acc[6]*inv+bv1.z; o[7]=acc[7]*inv+bv1.w;
      #pragma unroll
      for (int j = 0; j < 8; ++j){ colS[j] += o[j]; colQ[j] += o[j]*o[j]; }
      uint4 pk;
      pk.x = f2bf(o[0]) | (f2bf(o[1]) << 16);
      pk.y = f2bf(o[2]) | (f2bf(o[3]) << 16);
      pk.z = f2bf(o[4]) | (f2bf(o[5]) << 16);
      pk.w = f2bf(o[6]) | (f2bf(o[7]) << 16);
      out16[i*16 + m] = pk;
    }
  }
  // per-block BN partial reduce
  if (sub == 0){
    #pragma unroll
    for (int j = 0; j < 8; ++j){
      wredS[wv][m*8 + j] = colS[j];
      wredQ[wv][m*8 + j] = colQ[j];
    }
  }
  __syncthreads();
  if (t < 128){
    float S = wredS[0][t] + wredS[1][t] + wredS[2][t] + wredS[3][t];
    float Q = wredQ[0][t] + wredQ[1][t] + wredQ[2][t] + wredQ[3][t];
    bnpart[(size_t)blockIdx.x*256 + t]       = S;
    bnpart[(size_t)blockIdx.x*256 + 128 + t] = Q;
  }
}

// ---------------- SAGE mean aggregation ----------------
__global__ __launch_bounds__(256) void k_sage_mean(const uint4* __restrict__ h16,
    const int* __restrict__ rowStart, const int* __restrict__ srcList,
    uint4* __restrict__ out16){
  int i = blockIdx.x*4 + (threadIdx.x >> 6);
  if (i >= N_NODES) return;
  int lane = threadIdx.x & 63;
  int sub = lane >> 4;
  int m   = lane & 15;
  float acc[8];
  #pragma unroll
  for (int j = 0; j < 8; ++j) acc[j] = 0.f;
  int k0 = rowStart[i], ke = rowStart[i + 1];
  for (int k = k0; k < ke; k += 8){
    int e0 = k + sub, e1 = k + 4 + sub;
    int c0 = e0 < ke ? e0 : ke - 1;
    int c1 = e1 < ke ? e1 : ke - 1;
    int s0 = srcList[c0];
    int s1 = srcList[c1];
    uint4 u0 = h16[s0*16 + m];
    uint4 u1 = h16[s1*16 + m];
    float w0 = (e0 < ke) ? 1.f : 0.f;
    float w1 = (e1 < ke) ? 1.f : 0.f;
    float2 a0=bf2f2(u0.x), a1=bf2f2(u0.y), a2=bf2f2(u0.z), a3=bf2f2(u0.w);
    float2 b0=bf2f2(u1.x), b1=bf2f2(u1.y), b2=bf2f2(u1.z), b3=bf2f2(u1.w);
    acc[0] += a0.x*w0 + b0.x*w1;  acc[1] += a0.y*w0 + b0.y*w1;
    acc[2] += a1.x*w0 + b1.x*w1;  acc[3] += a1.y*w0 + b1.y*w1;
    acc[4] += a2.x*w0 + b2.x*w1;  acc[5] += a2.y*w0 + b2.y*w1;
    acc[6] += a3.x*w0 + b3.x*w1;  acc[7] += a3.y*w0 + b3.y*w1;
  }
  #pragma unroll
  for (int j = 0; j < 8; ++j){
    acc[j] += __shfl_xor(acc[j], 16);
    acc[j] += __shfl_xor(acc[j], 32);
  }
  if (sub == 0){
    int dg = ke - k0;
    float inv = 1.f / (float)(dg > 0 ? dg : 1);
    uint4 pk;
    pk.x = f2bf(acc[0]*inv) | (f2bf(acc[1]*inv) << 16);
    pk.y = f2bf(acc[2]*inv) | (f2bf(acc[3]*inv) << 16);
    pk.z = f2bf(acc[4]*inv) | (f2bf(acc[5]*inv) << 16);
    pk.w = f2bf(acc[6]*inv) | (f2bf(acc[7]*inv) << 16);
    out16[i*16 + m] = pk;
  }
}

// --------- BN apply (+opt bf16 residual) + lrelu; bf16 in/out ---------
__global__ void k_bnapply(const unsigned int* __restrict__ x16,
    const float* __restrict__ sums, const float* __restrict__ g,
    const float* __restrict__ b, const unsigned int* __restrict__ res16,
    unsigned int* __restrict__ y16){
  int f = blockIdx.x*256 + threadIdx.x;
  if (f >= N_NODES*32) return;
  int c = (f & 31) * 4;
  uint2 u = *(const uint2*)(x16 + (size_t)f*2);
  float2 vA = bf2f2(u.x), vB = bf2f2(u.y);
  float vv[4] = {vA.x, vA.y, vB.x, vB.y};
  float rr[4] = {0.f, 0.f, 0.f, 0.f};
  if (res16){
    uint2 ur = *(const uint2*)(res16 + (size_t)f*2);
    float2 rA = bf2f2(ur.x), rB = bf2f2(ur.y);
    rr[0]=rA.x; rr[1]=rA.y; rr[2]=rB.x; rr[3]=rB.y;
  }
  float o[4];
  const float invn = 1.f / (float)N_NODES;
  #pragma unroll
  for (int j = 0; j < 4; ++j){
    int cc = c + j;
    float mu  = sums[cc] * invn;
    float var = sums[128 + cc] * invn - mu*mu;
    float rs  = rsqrtf(var + EPSV);
    o[j] = lrelu((vv[j] - mu)*rs*g[cc] + b[cc] + rr[j]);
  }
  uint2 pk;
  pk.x = f2bf(o[0]) | (f2bf(o[1]) << 16);
  pk.y = f2bf(o[2]) | (f2bf(o[3]) << 16);
  *(uint2*)(y16 + (size_t)f*2) = pk;
}

// ---------------- global mean pool (bf16 input) ----------------
__global__ __launch_bounds__(256) void k_pool(const unsigned int* __restrict__ h16,
    const int* __restrict__ batch, float* __restrict__ pooled,
    float* __restrict__ cnt){
  int colu = threadIdx.x & 63;
  int ro   = threadIdx.x >> 6;
  int base = blockIdx.x * 128;
  int g_cur = -1; float a0 = 0.f, a1 = 0.f, cacc = 0.f;
  for (int ii = 0; ii < 32; ++ii){
    int r = base + ro + ii*4;
    if (r >= N_NODES) break;
    int g = batch[r];
    if (g != g_cur){
      if (g_cur >= 0){
        atomicAdd(&pooled[g_cur*D + 2*colu],     a0);
        atomicAdd(&pooled[g_cur*D + 2*colu + 1], a1);
        if (colu == 0) atomicAdd(&cnt[g_cur], cacc);
      }
      a0 = 0.f; a1 = 0.f; cacc = 0.f; g_cur = g;
    }
    float2 v = bf2f2(h16[(size_t)r*64 + colu]);
    a0 += v.x; a1 += v.y; cacc += 1.f;
  }
  if (g_cur >= 0){
    atomicAdd(&pooled[g_cur*D + 2*colu],     a0);
    atomicAdd(&pooled[g_cur*D + 2*colu + 1], a1);
    if (colu == 0) atomicAdd(&cnt[g_cur], cacc);
  }
}

// ---------------- final FC ----------------
__global__ void k_fc(const float* __restrict__ pooled, const float* __restrict__ cnt,
    const float* __restrict__ W, const float* __restrict__ b, float* __restrict__ out){
  int idx = blockIdx.x*256 + threadIdx.x;
  if (idx >= GR*64) return;
  int g = idx >> 6, o = idx & 63;
  const float* p = pooled + g*D;
  float s = 0.f;
  for (int c2 = 0; c2 < D; ++c2) s += p[c2] * W[c2*64 + o];
  float inv = 1.f / fmaxf(cnt[g], 1.f);
  out[idx] = s*inv + b[o];
}

extern "C" void kernel_launch(void* const* d_in, const int* in_sizes, int n_in,
                              void* d_out, int out_size, void* d_ws, size_t ws_size,
                              hipStream_t stream){
  (void)in_sizes; (void)n_in; (void)out_size; (void)ws_size;
  const float* x       = (const float*)d_in[0];
  const int*   ei      = (const int*)  d_in[1];
  const int*   batch   = (const int*)  d_in[2];
  const float* gat1_W  = (const float*)d_in[3];
  const float* gat1_as = (const float*)d_in[4];
  const float* gat1_ad = (const float*)d_in[5];
  const float* gat1_b  = (const float*)d_in[6];
  const float* gat2_W  = (const float*)d_in[7];
  const float* gat2_as = (const float*)d_in[8];
  const float* gat2_ad = (const float*)d_in[9];
  const float* gat2_b  = (const float*)d_in[10];
  const float* s3_Wl   = (const float*)d_in[11];
  const float* s3_bl   = (const float*)d_in[12];
  const float* s3_Wr   = (const float*)d_in[13];
  const float* s4_Wl   = (const float*)d_in[14];
  const float* s4_bl   = (const float*)d_in[15];
  const float* s4_Wr   = (const float*)d_in[16];
  const float* s5_Wl   = (const float*)d_in[17];
  const float* s5_bl   = (const float*)d_in[18];
  const float* s5_Wr   = (const float*)d_in[19];
  const float* bn1_g = (const float*)d_in[20]; const float* bn1_b = (const float*)d_in[21];
  const float* bn2_g = (const float*)d_in[22]; const float* bn2_b = (const float*)d_in[23];
  const float* bn3_g = (const float*)d_in[24]; const float* bn3_b = (const float*)d_in[25];
  const float* bn4_g = (const float*)d_in[26]; const float* bn4_b = (const float*)d_in[27];
  const float* bn5_g = (const float*)d_in[28]; const float* bn5_b = (const float*)d_in[29];
  const float* res1_W = (const float*)d_in[30]; const float* res1_b = (const float*)d_in[31];
  const float* res2_W = (const float*)d_in[32]; const float* res2_b = (const float*)d_in[33];
  const float* fc_W   = (const float*)d_in[34]; const float* fc_b   = (const float*)d_in[35];
  float* out = (float*)d_out;

  char* ws = (char*)d_ws;
  size_t off = 0;
  auto alloc = [&](size_t bytes) -> void* {
    void* p = ws + off; off += (bytes + 255) & ~(size_t)255; return p;
  };
  const int mgrid = (N_NODES + 63) / 64;
  int*   rowStart = (int*)  alloc((N_NODES + 1) * 4);
  int*   deg      = (int*)  alloc((size_t)N_NODES * 4);
  int*   rank     = (int*)  alloc((size_t)N_EDGES * 4);
  int*   srcList  = (int*)  alloc((size_t)N_EDGES * 4);
  int*   bsum     = (int*)  alloc(256 * 4);
  float* bnsums   = (float*)alloc(5 * 256 * 4);
  float* pooled   = (float*)alloc(GR * D * 4);
  float* cnt      = (float*)alloc(64 * 4);
  float* es       = (float*)alloc((size_t)N_NODES * 4 * 4);
  float* edv      = (float*)alloc((size_t)N_NODES * 4 * 4);
  float* bnpart   = (float*)alloc((size_t)GATGRID * 256 * 4);
  unsigned short* Wt16 = (unsigned short*)alloc(10 * 16384 * 2);
  unsigned short* HX   = (unsigned short*)alloc((size_t)N_NODES * D * 2);
  unsigned short* H16a = (unsigned short*)alloc((size_t)N_NODES * D * 2);
  unsigned short* HO   = (unsigned short*)alloc((size_t)N_NODES * D * 2);
  unsigned short* HR   = (unsigned short*)alloc((size_t)N_NODES * D * 2);

  const int* srcE = ei;
  const int* dstE = ei + N_EDGES;
  const int nb = (N_NODES + 255) / 256;
  const int egrid = (N_EDGES + 255) / 256;
  const int agrid = (N_NODES + 3) / 4;
  const int bgrid = (N_NODES*32 + 255) / 256;
  const int pgrid = (N_NODES + 127) / 128;

  // CSR build
  hipMemsetAsync(deg, 0, (size_t)N_NODES*4, stream);
  hipMemsetAsync(bnsums, 0, (5*256 + GR*D + 64)*4, stream);
  k_countrank<<<egrid, 256, 0, stream>>>(dstE, deg, rank);
  k_scan1<<<nb, 256, 0, stream>>>(deg, bsum);
  k_scan2b<<<1, 256, 0, stream>>>(bsum, nb, rowStart);
  k_scan3<<<nb, 256, 0, stream>>>(deg, bsum, rowStart);
  k_scatter<<<egrid, 256, 0, stream>>>(srcE, dstE, rank, rowStart, srcList);

  // casts
  WPack wp;
  wp.w[0]=res1_W; wp.w[1]=gat1_W; wp.w[2]=res2_W; wp.w[3]=gat2_W;
  wp.w[4]=s3_Wl;  wp.w[5]=s3_Wr;  wp.w[6]=s4_Wl;  wp.w[7]=s4_Wr;
  wp.w[8]=s5_Wl;  wp.w[9]=s5_Wr;
  k_castw<<<640, 256, 0, stream>>>(wp, Wt16);
  k_cast_x<<<bgrid, 256, 0, stream>>>(x, HX);

  // ---- layer 1 (GAT) ----
  k_mgemm_dual<<<mgrid, 256, 0, stream>>>(HX, Wt16 + 0*16384, Wt16 + 1*16384,
                                          res1_b, gat1_as, gat1_ad,
                                          HR, H16a, es, edv, N_NODES);
  k_gat<<<GATGRID, 256, 0, stream>>>((const uint4*)H16a, es, edv, rowStart,
                                     srcList, gat1_b, (uint4*)HO, bnpart);
  k_bnred<<<64, 256, 0, stream>>>(bnpart, GATGRID, bnsums);
  k_bnapply<<<bgrid, 256, 0, stream>>>((const unsigned int*)HO, bnsums, bn1_g, bn1_b,
                                       (const unsigned int*)HR, (unsigned int*)H16a);

  // ---- layer 2 (GAT) ----
  k_mgemm_dual<<<mgrid, 256, 0, stream>>>(H16a, Wt16 + 2*16384, Wt16 + 3*16384,
                                          res2_b, gat2_as, gat2_ad,
                                          HR, HX, es, edv, N_NODES);
  k_gat<<<GATGRID, 256, 0, stream>>>((const uint4*)HX, es, edv, rowStart,
                                     srcList, gat2_b, (uint4*)HO, bnpart);
  k_bnred<<<64, 256, 0, stream>>>(bnpart, GATGRID, bnsums + 256);
  k_bnapply<<<bgrid, 256, 0, stream>>>((const unsigned int*)HO, bnsums + 256, bn2_g, bn2_b,
                                       (const unsigned int*)HR, (unsigned int*)H16a);

  // ---- layer 3 (SAGE) ----
  k_sage_mean<<<agrid, 256, 0, stream>>>((const uint4*)H16a, rowStart, srcList,
                                         (uint4*)HX);
  k_mgemm2<<<mgrid, 256, 0, stream>>>(HX, Wt16 + 4*16384, H16a, Wt16 + 5*16384,
                                      s3_bl, HO, N_NODES, bnpart);
  k_bnred<<<64, 256, 0, stream>>>(bnpart, mgrid, bnsums + 512);
  k_bnapply<<<bgrid, 256, 0, stream>>>((const unsigned int*)HO, bnsums + 512, bn3_g, bn3_b,
                                       nullptr, (unsigned int*)H16a);

  // ---- layer 4 (SAGE) ----
  k_sage_mean<<<agrid, 256, 0, stream>>>((const uint4*)H16a, rowStart, srcList,
                                         (uint4*)HX);
  k_mgemm2<<<mgrid, 256, 0, stream>>>(HX, Wt16 + 6*16384, H16a, Wt16 + 7*16384,
                                      s4_bl, HO, N_NODES, bnpart);
  k_bnred<<<64, 256, 0, stream>>>(bnpart, mgrid, bnsums + 768);
  k_bnapply<<<bgrid, 256, 0, stream>>>((const unsigned int*)HO, bnsums + 768, bn4_g, bn4_b,
                                       nullptr, (unsigned int*)H16a);

  // ---- layer 5 (SAGE) ----
  k_sage_mean<<<agrid, 256, 0, stream>>>((const uint4*)H16a, rowStart, srcList,
                                         (uint4*)HX);
  k_mgemm2<<<mgrid, 256, 0, stream>>>(HX, Wt16 + 8*16384, H16a, Wt16 + 9*16384,
                                      s5_bl, HO, N_NODES, bnpart);
  k_bnred<<<64, 256, 0, stream>>>(bnpart, mgrid, bnsums + 1024);
  k_bnapply<<<bgrid, 256, 0, stream>>>((const unsigned int*)HO, bnsums + 1024, bn5_g, bn5_b,
                                       nullptr, (unsigned int*)H16a);

  // ---- pool + fc ----
  k_pool<<<pgrid, 256, 0, stream>>>((const unsigned int*)H16a, batch, pooled, cnt);
  k_fc<<<(GR*64 + 255)/256, 256, 0, stream>>>(pooled, cnt, fc_W, fc_b, out);
}